// Round 7
// baseline (22929.829 us; speedup 1.0000x reference)
//
#include <hip/hip_runtime.h>
#include <cmath>

typedef long long i64;

#define NI 8192
#define NB 2048
#define CH 2048
#define H  512
#define HH 262144
#define TOT 265217
#define OFF_W1 1536
#define OFF_W2 263680
#define OFF_B0 264192
#define OFF_B1 264704
#define OFF_B2 265216
#define DAMP 1e-3f
#define DEC  0.95f
#define INNER 2
#define SOUTER 3
#define STEPS (INNER * 127)

__device__ __forceinline__ int imin(int a, int b) { return a < b ? a : b; }

// ======================= 64x64 GEMM, K-tile 32 =======================
template<int MODE, int BIAS, int TANH_, int FAST, int AUX>
__global__ __launch_bounds__(256) void gemm64_k(
    const float* __restrict__ A, const float* __restrict__ B,
    const float* __restrict__ bias, float* __restrict__ C,
    int M, int N, int K, const float* __restrict__ t0p, float* __restrict__ dst2)
{
    __shared__ float As[32][68];
    __shared__ float Bs[32][68];
    int tid = threadIdx.x;
    int tx = tid & 15, ty = tid >> 4;
    int m0 = blockIdx.x * 64, n0 = blockIdx.y * 64;
    float acc[4][4] = {};
    for (int k0 = 0; k0 < K; k0 += 32) {
        if (MODE == 0 || MODE == 1) {
            int m = tid >> 2, kq = (tid & 3) * 4;
            if (FAST) {
                const float* Ap = &A[(i64)(m0 + m) * K + k0 + kq];
                float4 v0 = *(const float4*)Ap;
                float4 v1 = *(const float4*)(Ap + 16);
                As[kq + 0][m] = v0.x; As[kq + 1][m] = v0.y;
                As[kq + 2][m] = v0.z; As[kq + 3][m] = v0.w;
                As[kq + 16][m] = v1.x; As[kq + 17][m] = v1.y;
                As[kq + 18][m] = v1.z; As[kq + 19][m] = v1.w;
            } else {
                int mm = m0 + m;
#pragma unroll
                for (int h = 0; h < 32; h += 16)
#pragma unroll
                    for (int i = 0; i < 4; i++) {
                        int kk = k0 + h + kq + i;
                        As[h + kq + i][m] = (mm < M && kk < K) ? A[(i64)mm * K + kk] : 0.f;
                    }
            }
        } else {
            int k = tid >> 4, mq = (tid & 15) * 4;
            if (FAST) {
                *(float4*)&As[k][mq]      = *(const float4*)&A[(i64)(k0 + k) * M + m0 + mq];
                *(float4*)&As[k + 16][mq] = *(const float4*)&A[(i64)(k0 + k + 16) * M + m0 + mq];
            } else {
#pragma unroll
                for (int h = 0; h < 32; h += 16) {
                    int kk = k0 + k + h;
#pragma unroll
                    for (int i = 0; i < 4; i++) {
                        int mm = m0 + mq + i;
                        As[k + h][mq + i] = (kk < K && mm < M) ? A[(i64)kk * M + mm] : 0.f;
                    }
                }
            }
        }
        if (MODE == 0) {
            int n = tid >> 2, kq = (tid & 3) * 4;
            if (FAST) {
                const float* Bp = &B[(i64)(n0 + n) * K + k0 + kq];
                float4 v0 = *(const float4*)Bp;
                float4 v1 = *(const float4*)(Bp + 16);
                Bs[kq + 0][n] = v0.x; Bs[kq + 1][n] = v0.y;
                Bs[kq + 2][n] = v0.z; Bs[kq + 3][n] = v0.w;
                Bs[kq + 16][n] = v1.x; Bs[kq + 17][n] = v1.y;
                Bs[kq + 18][n] = v1.z; Bs[kq + 19][n] = v1.w;
            } else {
                int nn = n0 + n;
#pragma unroll
                for (int h = 0; h < 32; h += 16)
#pragma unroll
                    for (int i = 0; i < 4; i++) {
                        int kk = k0 + h + kq + i;
                        Bs[h + kq + i][n] = (nn < N && kk < K) ? B[(i64)nn * K + kk] : 0.f;
                    }
            }
        } else {
            int k = tid >> 4, nq = (tid & 15) * 4;
            if (FAST) {
                *(float4*)&Bs[k][nq]      = *(const float4*)&B[(i64)(k0 + k) * N + n0 + nq];
                *(float4*)&Bs[k + 16][nq] = *(const float4*)&B[(i64)(k0 + k + 16) * N + n0 + nq];
            } else {
#pragma unroll
                for (int h = 0; h < 32; h += 16) {
                    int kk = k0 + k + h;
#pragma unroll
                    for (int i = 0; i < 4; i++) {
                        int nn = n0 + nq + i;
                        Bs[k + h][nq + i] = (kk < K && nn < N) ? B[(i64)kk * N + nn] : 0.f;
                    }
                }
            }
        }
        __syncthreads();
#pragma unroll
        for (int ks = 0; ks < 32; ks++) {
            float4 a = *(const float4*)&As[ks][ty * 4];
            float4 b = *(const float4*)&Bs[ks][tx * 4];
            float av[4] = {a.x, a.y, a.z, a.w};
            float bv[4] = {b.x, b.y, b.z, b.w};
#pragma unroll
            for (int i = 0; i < 4; i++)
#pragma unroll
                for (int j = 0; j < 4; j++) acc[i][j] += av[i] * bv[j];
        }
        __syncthreads();
    }
#pragma unroll
    for (int i = 0; i < 4; i++) {
        int m = m0 + ty * 4 + i;
        if (!FAST && m >= M) continue;
        if (FAST) {
            float4 vc, v2;
            float* pc = (float*)&vc; float* p2 = (float*)&v2;
            float4 t0v;
            if (AUX) t0v = *(const float4*)&t0p[(i64)m * N + n0 + tx * 4];
            const float* t0a = (const float*)&t0v;
#pragma unroll
            for (int j = 0; j < 4; j++) {
                float t = acc[i][j];
                if (BIAS) t += bias[n0 + tx * 4 + j];
                if (TANH_) t = tanhf(t);
                if (AUX == 1) { pc[j] = t; p2[j] = (1.f - t0a[j] * t0a[j]) * t; }
                else if (AUX == 2) { pc[j] = (1.f - t0a[j] * t0a[j]) * t; }
                else pc[j] = t;
            }
            *(float4*)&C[(i64)m * N + n0 + tx * 4] = vc;
            if (AUX == 1) *(float4*)&dst2[(i64)m * N + n0 + tx * 4] = v2;
        } else {
#pragma unroll
            for (int j = 0; j < 4; j++) {
                int n = n0 + tx * 4 + j;
                if (n >= N) continue;
                float t = acc[i][j];
                if (BIAS) t += bias[n];
                if (TANH_) t = tanhf(t);
                if (AUX) {
                    float t0v = t0p[(i64)m * N + n];
                    if (AUX == 1) { C[(i64)m * N + n] = t; dst2[(i64)m * N + n] = (1.f - t0v * t0v) * t; }
                    else C[(i64)m * N + n] = (1.f - t0v * t0v) * t;
                } else C[(i64)m * N + n] = t;
            }
        }
    }
}

// single split-K TN (slow/odd shapes)
template<int FAST>
__global__ __launch_bounds__(256) void gemm_tn_sk_k(
    const float* __restrict__ A, const float* __restrict__ B,
    float* __restrict__ P, int M, int N, int K, int Ks)
{
    __shared__ float As[32][68];
    __shared__ float Bs[32][68];
    int tid = threadIdx.x;
    int tx = tid & 15, ty = tid >> 4;
    int m0 = blockIdx.x * 64, n0 = blockIdx.y * 64, s = blockIdx.z;
    int kb = s * Ks, ke = imin(K, kb + Ks);
    float acc[4][4] = {};
    for (int k0 = kb; k0 < ke; k0 += 32) {
        int k = tid >> 4, q = (tid & 15) * 4;
        if (FAST) {
            *(float4*)&As[k][q]      = *(const float4*)&A[(i64)(k0 + k) * M + m0 + q];
            *(float4*)&As[k + 16][q] = *(const float4*)&A[(i64)(k0 + k + 16) * M + m0 + q];
            *(float4*)&Bs[k][q]      = *(const float4*)&B[(i64)(k0 + k) * N + n0 + q];
            *(float4*)&Bs[k + 16][q] = *(const float4*)&B[(i64)(k0 + k + 16) * N + n0 + q];
        } else {
#pragma unroll
            for (int h = 0; h < 32; h += 16) {
                int kk = k0 + k + h;
#pragma unroll
                for (int i = 0; i < 4; i++) {
                    int mm = m0 + q + i, nn = n0 + q + i;
                    As[k + h][q + i] = (kk < ke && mm < M) ? A[(i64)kk * M + mm] : 0.f;
                    Bs[k + h][q + i] = (kk < ke && nn < N) ? B[(i64)kk * N + nn] : 0.f;
                }
            }
        }
        __syncthreads();
#pragma unroll
        for (int ks = 0; ks < 32; ks++) {
            float4 a = *(const float4*)&As[ks][ty * 4];
            float4 b = *(const float4*)&Bs[ks][tx * 4];
            float av[4] = {a.x, a.y, a.z, a.w};
            float bv[4] = {b.x, b.y, b.z, b.w};
#pragma unroll
            for (int i = 0; i < 4; i++)
#pragma unroll
                for (int j = 0; j < 4; j++) acc[i][j] += av[i] * bv[j];
        }
        __syncthreads();
    }
    float* Po = P + (i64)s * M * N;
#pragma unroll
    for (int i = 0; i < 4; i++) {
        int m = m0 + ty * 4 + i;
        if (m >= M) continue;
#pragma unroll
        for (int j = 0; j < 4; j++) {
            int n = n0 + tx * 4 + j;
            if (n >= N) continue;
            Po[(i64)m * N + n] = acc[i][j];
        }
    }
}
__global__ void sk_red_k(float* __restrict__ dst, const float* __restrict__ P, int cnt)
{
    int e = blockIdx.x * 256 + threadIdx.x;
    if (e >= cnt) return;
    float s = 0.f;
#pragma unroll
    for (int z = 0; z < 8; z++) s += P[(i64)z * cnt + e];
    dst[e] += s;
}

// ======== batched TN Gram/grad GEMMs (M=N=512, fast path only) ========
struct SkBatch {
    const float* A[5]; const float* B[5];
    int job_of_z[8];
    int kb_of_z[8];
    int Ks;
};
__global__ __launch_bounds__(256) void skb_k(SkBatch sb, float* __restrict__ P)
{
    __shared__ float As[32][68];
    __shared__ float Bs[32][68];
    int tid = threadIdx.x;
    int tx = tid & 15, ty = tid >> 4;
    int m0 = blockIdx.x * 64, n0 = blockIdx.y * 64, z = blockIdx.z;
    int j = sb.job_of_z[z];
    const float* A = sb.A[j]; const float* B = sb.B[j];
    int kb = sb.kb_of_z[z], ke = kb + sb.Ks;
    float acc[4][4] = {};
    for (int k0 = kb; k0 < ke; k0 += 32) {
        int k = tid >> 4, q = (tid & 15) * 4;
        *(float4*)&As[k][q]      = *(const float4*)&A[(i64)(k0 + k) * H + m0 + q];
        *(float4*)&As[k + 16][q] = *(const float4*)&A[(i64)(k0 + k + 16) * H + m0 + q];
        *(float4*)&Bs[k][q]      = *(const float4*)&B[(i64)(k0 + k) * H + n0 + q];
        *(float4*)&Bs[k + 16][q] = *(const float4*)&B[(i64)(k0 + k + 16) * H + n0 + q];
        __syncthreads();
#pragma unroll
        for (int ks = 0; ks < 32; ks++) {
            float4 a = *(const float4*)&As[ks][ty * 4];
            float4 b = *(const float4*)&Bs[ks][tx * 4];
            float av[4] = {a.x, a.y, a.z, a.w};
            float bv[4] = {b.x, b.y, b.z, b.w};
#pragma unroll
            for (int i = 0; i < 4; i++)
#pragma unroll
                for (int jj = 0; jj < 4; jj++) acc[i][jj] += av[i] * bv[jj];
        }
        __syncthreads();
    }
    float* Po = P + (i64)z * HH;
#pragma unroll
    for (int i = 0; i < 4; i++) {
        int m = m0 + ty * 4 + i;
#pragma unroll
        for (int jj = 0; jj < 4; jj++)
            Po[(i64)m * H + n0 + tx * 4 + jj] = acc[i][jj];
    }
}
struct RedJ { float* dst[4]; int off[5]; };
__global__ void skred_k(RedJ rj, const float* __restrict__ P)
{
    int e = blockIdx.x * 256 + threadIdx.x;
    int j = blockIdx.y;
    if (e >= HH) return;
    float s = 0.f;
    for (int z = rj.off[j]; z < rj.off[j + 1]; z++) s += P[(i64)z * HH + e];
    rj.dst[j][e] += s;
}

// ======================= elementwise / fused =======================
__global__ void zero_k(float* p, i64 n) {
    i64 e = (i64)blockIdx.x * 256 + threadIdx.x;
    if (e < n) p[e] = 0.f;
}

// FULL: emit jacobian/laplacian channels; LSU: params = base - al*mcat
template<int FULL, int LSU>
__global__ __launch_bounds__(256) void fwd0_k(
    const float* __restrict__ X, const float* __restrict__ W0,
    const float* __restrict__ b0, int rows,
    float* __restrict__ t0c, float* __restrict__ g1c, float* __restrict__ l1c,
    const float* __restrict__ mcat, float al)
{
    int e = blockIdx.x * 256 + threadIdx.x;
    if (e >= rows * H) return;
    int n = e >> 9, j = e & 511;
    const float* x = X + (i64)n * 3;
    float w0 = W0[j * 3 + 0], w1 = W0[j * 3 + 1], w2 = W0[j * 3 + 2];
    float bb = b0[j];
    if (LSU) {
        w0 -= al * mcat[j * 3 + 0];
        w1 -= al * mcat[j * 3 + 1];
        w2 -= al * mcat[j * 3 + 2];
        bb -= al * mcat[OFF_B0 + j];
    }
    float s = x[0] * w0 + x[1] * w1 + x[2] * w2 + bb;
    float t = tanhf(s);
    t0c[e] = t;
    if (FULL) {
        float phi = 1.f - t * t;
        float u = -2.f * t * phi;
        float Q0 = w0 * w0 + w1 * w1 + w2 * w2;
        l1c[e] = u * Q0;
        i64 base = ((i64)n * 3) * H + j;
        g1c[base] = phi * w0;
        g1c[base + H] = phi * w1;
        g1c[base + 2 * H] = phi * w2;
    }
}

// fused lapfin + bwd_mid: per-row block; q kept in regs (q1c not stored)
__global__ __launch_bounds__(256) void lapbwd_k(
    const float* __restrict__ t1c, const float* __restrict__ ls1c,
    float* __restrict__ gs1c, const float* __restrict__ W2,
    const float* __restrict__ X, float invN,
    float* __restrict__ l2c, float* __restrict__ f1c, float* __restrict__ d1c,
    float* __restrict__ ri_out)
{
    __shared__ float red[4];
    __shared__ float riS;
    int n = blockIdx.x;
    int tid = threadIdx.x;
    float tv[2], phiv[2], uv[2], qv[2], lsv[2], g0v[2], g1v[2], g2v[2], w2v[2];
    float part = 0.f;
#pragma unroll
    for (int h = 0; h < 2; h++) {
        int m = tid + h * 256;
        i64 e = (i64)n * H + m;
        i64 b = ((i64)n * 3) * H + m;
        float g0 = gs1c[b], g1 = gs1c[b + H], g2 = gs1c[b + 2 * H];
        float q = g0 * g0 + g1 * g1 + g2 * g2;
        float t = t1c[e], phi = 1.f - t * t, u = -2.f * t * phi;
        float ls = ls1c[e];
        float l2 = phi * ls + u * q;
        l2c[e] = l2;
        part += l2 * W2[m];
        tv[h] = t; phiv[h] = phi; uv[h] = u; qv[h] = q; lsv[h] = ls;
        g0v[h] = g0; g1v[h] = g1; g2v[h] = g2; w2v[h] = W2[m];
    }
    for (int off = 32; off; off >>= 1) part += __shfl_down(part, off, 64);
    if ((tid & 63) == 0) red[tid >> 6] = part;
    __syncthreads();
    if (tid == 0) {
        float p = red[0] + red[1] + red[2] + red[3];
        const float* x = X + (i64)n * 3;
        float r = p - (sinf(x[0]) + sinf(x[1]) + sinf(x[2]));
        ri_out[n] = r;
        riS = r;
    }
    __syncthreads();
    float ri = riS;
#pragma unroll
    for (int h = 0; h < 2; h++) {
        int m = tid + h * 256;
        i64 e = (i64)n * H + m;
        i64 b = ((i64)n * 3) * H + m;
        float t = tv[h], phi = phiv[h], u = uv[h];
        float bl2 = ri * invN * w2v[h];
        f1c[e] = bl2 * (u * lsv[h] + (6.f * t * t - 2.f) * phi * qv[h]);
        d1c[e] = phi * bl2;
        float sc = 2.f * u * bl2;
        gs1c[b] = g0v[h] * sc; gs1c[b + H] = g1v[h] * sc; gs1c[b + 2 * H] = g2v[h] * sc;
    }
}

__global__ __launch_bounds__(256) void bnd_fin_k(
    const float* __restrict__ tb1, const float* __restrict__ W2,
    const float* __restrict__ b2, const float* __restrict__ X, int rows,
    float* __restrict__ rb_out)
{
    int wave = threadIdx.x >> 6, lane = threadIdx.x & 63;
    int n = blockIdx.x * 4 + wave;
    if (n >= rows) return;
    float p = 0.f;
    for (int m = lane; m < H; m += 64) p += tb1[(i64)n * H + m] * W2[m];
    for (int off = 32; off; off >>= 1) p += __shfl_down(p, off, 64);
    if (lane == 0) {
        const float* x = X + (i64)n * 3;
        rb_out[n] = p + b2[0] - (cosf(x[0]) + cosf(x[1]) + cosf(x[2]));
    }
}

// weighted column-sum jobs
struct WJ { const float* src[3]; const float* wgt[3]; float scale[3]; float* dst[3]; };
__global__ void wcolp_k(WJ wj, int rows, float* __restrict__ part)
{
    int m = blockIdx.x * 256 + threadIdx.x;
    int g = blockIdx.y, z = blockIdx.z;
    if (m >= H) return;
    const float* src = wj.src[z]; const float* w = wj.wgt[z];
    int per = (rows + 15) / 16;
    int n0 = g * per, n1 = imin(rows, n0 + per);
    float s = 0.f;
    for (int n = n0; n < n1; n++) {
        float ww = w ? w[n] : 1.f;
        s += ww * src[(i64)n * H + m];
    }
    part[(i64)(z * 16 + g) * H + m] = s;
}
__global__ void wcolr_k(WJ wj, const float* __restrict__ part)
{
    int m = blockIdx.x * 256 + threadIdx.x;
    int z = blockIdx.y;
    if (m >= H) return;
    float s = 0.f;
#pragma unroll
    for (int g = 0; g < 16; g++) s += part[(i64)(z * 16 + g) * H + m];
    wj.dst[z][m] += wj.scale[z] * s;
}

__global__ void dualred_k(const float* __restrict__ ri, const float* __restrict__ rb,
                          float* S_B2, float* gb2v, float* S_B2b)
{
    __shared__ float s1[256], s2[256];
    int z = blockIdx.x;
    const float* r = z ? rb : ri;
    int n = z ? NB : NI;
    float a = 0.f, b = 0.f;
    for (int i = threadIdx.x; i < n; i += 256) { float v = r[i]; a += v; b += v * v; }
    s1[threadIdx.x] = a; s2[threadIdx.x] = b; __syncthreads();
    for (int off = 128; off; off >>= 1) {
        if (threadIdx.x < off) { s1[threadIdx.x] += s1[threadIdx.x + off]; s2[threadIdx.x] += s2[threadIdx.x + off]; }
        __syncthreads();
    }
    if (threadIdx.x == 0) {
        float invN = 1.f / n;
        if (z == 0) { S_B2[0] += invN * invN * s2[0]; }
        else { gb2v[0] += invN * s1[0]; S_B2b[0] += invN * invN * s2[0]; }
    }
}

__global__ __launch_bounds__(256) void delta1_k(
    const float* __restrict__ t1c, const float* __restrict__ r,
    const float* __restrict__ W2, float invN, float* __restrict__ d1c, int rows)
{
    int e = blockIdx.x * 256 + threadIdx.x;
    if (e >= rows * H) return;
    int n = e >> 9, m = e & 511;
    float t = t1c[e];
    d1c[e] = (1.f - t * t) * (r[n] * invN) * W2[m];
}

__global__ void bwd0p_k(const float* __restrict__ X, int rows,
                        const float* __restrict__ W0,
                        const float* __restrict__ t0c, const float* __restrict__ bt0,
                        const float* __restrict__ bl1, const float* __restrict__ bg1,
                        float* __restrict__ part)
{
    int j = blockIdx.x * 256 + threadIdx.x;
    int g = blockIdx.y;
    if (j >= H) return;
    int per = (rows + 7) / 8;
    int n0 = g * per, n1 = imin(rows, n0 + per);
    float w0 = W0[j * 3], w1 = W0[j * 3 + 1], w2 = W0[j * 3 + 2];
    float Q0 = w0 * w0 + w1 * w1 + w2 * w2;
    float sW0 = 0, sW1 = 0, sW2 = 0, sUB = 0, sb = 0;
    for (int n = n0; n < n1; n++) {
        i64 e = (i64)n * H + j;
        float t = t0c[e], phi = 1.f - t * t, u = -2.f * t * phi;
        float bt = bt0[e], bl = bl1[e];
        i64 gb = ((i64)n * 3) * H + j;
        float g0 = bg1[gb], g1 = bg1[gb + H], g2 = bg1[gb + 2 * H];
        float bs = bt * phi + bl * (6.f * t * t - 2.f) * phi * Q0
                 + u * (g0 * w0 + g1 * w1 + g2 * w2);
        const float* x = X + (i64)n * 3;
        sW0 += bs * x[0] + phi * g0;
        sW1 += bs * x[1] + phi * g1;
        sW2 += bs * x[2] + phi * g2;
        sUB += u * bl;
        sb += bs;
    }
    float* pg = part + (i64)g * 2048;
    pg[j * 3 + 0] = sW0 + 2.f * w0 * sUB;
    pg[j * 3 + 1] = sW1 + 2.f * w1 * sUB;
    pg[j * 3 + 2] = sW2 + 2.f * w2 * sUB;
    pg[1536 + j] = sb;
}
__global__ void bwd0red_k(const float* __restrict__ part, float* __restrict__ gW0,
                          float* __restrict__ gb0)
{
    int e = blockIdx.x * 256 + threadIdx.x;
    if (e >= 2048) return;
    float s = 0.f;
#pragma unroll
    for (int g = 0; g < 8; g++) s += part[(i64)g * 2048 + e];
    if (e < 1536) gW0[e] += s;
    else gb0[e - 1536] += s;
}

__global__ __launch_bounds__(256) void xtx3b_k(const float* __restrict__ Xi,
                                               const float* __restrict__ Xb,
                                               float* __restrict__ S_A0,
                                               float* __restrict__ S_Ab0)
{
    __shared__ float red[256];
    int z = blockIdx.x;
    const float* X = z ? Xb : Xi;
    int rows = z ? NB : NI;
    float* dst = z ? S_Ab0 : S_A0;
    float s[9] = {};
    for (int n = threadIdx.x; n < rows; n += 256) {
        float x0 = X[(i64)n * 3], x1 = X[(i64)n * 3 + 1], x2 = X[(i64)n * 3 + 2];
        s[0] += x0 * x0; s[1] += x0 * x1; s[2] += x0 * x2;
        s[3] += x1 * x0; s[4] += x1 * x1; s[5] += x1 * x2;
        s[6] += x2 * x0; s[7] += x2 * x1; s[8] += x2 * x2;
    }
    for (int c = 0; c < 9; c++) {
        red[threadIdx.x] = s[c]; __syncthreads();
        for (int off = 128; off; off >>= 1) {
            if (threadIdx.x < off) red[threadIdx.x] += red[threadIdx.x + off];
            __syncthreads();
        }
        if (threadIdx.x == 0) dst[c] += red[0];
        __syncthreads();
    }
}

struct P8 { const float* p[8]; };
__global__ void fbuildb_k(P8 mom, const float* __restrict__ S, float* __restrict__ dst)
{
    int e = blockIdx.x * 256 + threadIdx.x;
    int z = blockIdx.y;
    if (e >= HH) return;
    float invN = (z < 4) ? (1.f / NI) : (1.f / NB);
    float v = DEC * mom.p[z][e] + (1.f - DEC) * invN * S[(i64)z * HH + e];
    if ((e >> 9) == (e & 511)) v += DAMP;
    dst[(i64)z * HH + e] = v;
}
__global__ void identv_k(float* V, i64 count) {
    i64 e = (i64)blockIdx.x * 256 + threadIdx.x;
    if (e >= count) return;
    i64 o = e % HH;
    V[e] = ((o >> 9) == (o & 511)) ? 1.f : 0.f;
}

// ======================= block Jacobi eigensolver =======================
__device__ __forceinline__ int pos7(int k, int r) { return k == 0 ? 0 : 1 + ((k - 1 + r) % 7); }
__device__ __forceinline__ int gidx(int a, int gA, int gB) {
    return (a < 64) ? gA * 64 + a : gB * 64 + (a - 64);
}

// 128x128 subproblem v4: interleaved-pair layout. Pairs are physically
// adjacent (2t,2t+1) in rows AND cols; round-robin implemented by the fixed
// shift permutation sigma applied on WRITES (ping-pong buffers). Reads are
// aligned float4; writes are stride-2 pairs (DS combiner -> ds_write2_b32).
// Logs (c,s,orig_p,orig_q) per rotation; reads A only.
__global__ __launch_bounds__(1024) void eig_sub_k(const float* __restrict__ Abase,
                                                  float* __restrict__ rlog, int r)
{
    __shared__ float Sa[128][132];
    __shared__ float Sb[128][132];
    __shared__ float2 csb[64];
    int pr = blockIdx.x, mat = blockIdx.y;
    int gA = pos7(pr, r), gB = pos7(7 - pr, r);
    int tid = threadIdx.x;
    const float* A = Abase + (i64)mat * HH;
    float4* lg = ((float4*)rlog) + (i64)(mat * 4 + pr) * (STEPS * 64);
    // load in interleaved-pair layout: phys 2t <- orig t ; phys 2t+1 <- orig 127-t
    for (int e = tid; e < 128 * 128; e += 1024) {
        int i = e >> 7, j = e & 127;
        int oi = (i & 1) ? (127 - (i >> 1)) : (i >> 1);
        int oj = (j & 1) ? (127 - (j >> 1)) : (j >> 1);
        Sa[i][j] = A[(i64)gidx(oi, gA, gB) * H + gidx(oj, gA, gB)];
    }
    int rp = tid >> 4, cg = tid & 15;
    int r0 = 2 * rp, r1 = 2 * rp + 1;
    int tr0 = (rp == 0) ? 0 : ((rp == 1) ? 1 : (2 * rp - 2));
    int tr1 = (rp == 63) ? 126 : (2 * rp + 3);
    // orig index tracking for the cs lanes (tid<64 -> pair tid)
    int ot = (tid == 0) ? 0 : tid;
    int ob = (tid == 0) ? 127 : (127 - tid);
    __syncthreads();
    for (int gst = 0; gst < STEPS; ++gst) {
        float (*Sc)[132] = (gst & 1) ? Sb : Sa;
        float (*Sn)[132] = (gst & 1) ? Sa : Sb;
        if (tid < 64) {
            int t2 = 2 * tid;
            float att = Sc[t2][t2];
            float abb = Sc[t2 + 1][t2 + 1];
            float atb = Sc[t2][t2 + 1];
            float c = 1.f, s = 0.f;
            if (fabsf(atb) > 1e-30f) {
                float tau = (abb - att) / (2.f * atb);
                float t = copysignf(1.f, tau) / (fabsf(tau) + sqrtf(1.f + tau * tau));
                c = 1.f / sqrtf(1.f + t * t); s = t * c;
            }
            csb[tid] = make_float2(c, s);
            lg[(i64)gst * 64 + tid] = make_float4(c, s, __int_as_float(ot), __int_as_float(ob));
            ot = (tid == 0) ? 0 : (ot == 127 ? 1 : ot + 1);
            ob = (ob == 127) ? 1 : ob + 1;
        }
        __syncthreads();
        float2 rcs = csb[rp];
        float cr = rcs.x, sr = rcs.y;
#pragma unroll
        for (int task = 0; task < 2; task++) {
            int cb = 8 * cg + 4 * task;
            float4 ccs = *(const float4*)&csb[cb >> 1];    // cA,sA,cB,sB
            float4 x0 = *(const float4*)&Sc[r0][cb];
            float4 x1 = *(const float4*)&Sc[r1][cb];
            float y0x = cr * x0.x - sr * x1.x, y1x = sr * x0.x + cr * x1.x;
            float y0y = cr * x0.y - sr * x1.y, y1y = sr * x0.y + cr * x1.y;
            float y0z = cr * x0.z - sr * x1.z, y1z = sr * x0.z + cr * x1.z;
            float y0w = cr * x0.w - sr * x1.w, y1w = sr * x0.w + cr * x1.w;
            float z00 = ccs.x * y0x - ccs.y * y0y, z01 = ccs.y * y0x + ccs.x * y0y;
            float z02 = ccs.z * y0z - ccs.w * y0w, z03 = ccs.w * y0z + ccs.z * y0w;
            float z10 = ccs.x * y1x - ccs.y * y1y, z11 = ccs.y * y1x + ccs.x * y1y;
            float z12 = ccs.z * y1z - ccs.w * y1w, z13 = ccs.w * y1z + ccs.z * y1w;
            // even-origin cols (cb -> sigma, cb+2 -> sigma)
            if (cb == 0) {
                float* w0p = &Sn[tr0][0]; w0p[0] = z00; w0p[1] = z02;
                float* w1p = &Sn[tr1][0]; w1p[0] = z10; w1p[1] = z12;
            } else {
                float* w0p = &Sn[tr0][cb - 2]; w0p[0] = z00; w0p[2] = z02;
                float* w1p = &Sn[tr1][cb - 2]; w1p[0] = z10; w1p[2] = z12;
            }
            // odd-origin cols (cb+1, cb+3)
            if (cb == 124) {
                float* w0p = &Sn[tr0][126]; w0p[0] = z03; w0p[1] = z01;
                float* w1p = &Sn[tr1][126]; w1p[0] = z13; w1p[1] = z11;
            } else {
                float* w0p = &Sn[tr0][cb + 3]; w0p[0] = z01; w0p[2] = z03;
                float* w1p = &Sn[tr1][cb + 3]; w1p[0] = z11; w1p[2] = z13;
            }
        }
        __syncthreads();
    }
}

__global__ __launch_bounds__(256) void ubuild_k(const float* __restrict__ rlog,
                                                float* __restrict__ Ubuf)
{
    __shared__ float U[16][132];
    __shared__ float4 lb[2][64];
    int sl = blockIdx.x, mp = blockIdx.y;
    int tid = threadIdx.x;
    const float4* lg = ((const float4*)rlog) + (i64)mp * (STEPS * 64);
    int ro0 = sl * 16;
    for (int e = tid; e < 16 * 128; e += 256) {
        int rr = e >> 7, cc = e & 127;
        U[rr][cc] = (ro0 + rr == cc) ? 1.f : 0.f;
    }
    if (tid < 64) lb[0][tid] = lg[tid];
    __syncthreads();
    for (int st = 0; st < STEPS; st++) {
        float4 e4 = lb[st & 1][tid & 63];
        if (tid < 64 && st + 1 < STEPS) lb[(st + 1) & 1][tid] = lg[(i64)(st + 1) * 64 + tid];
        float c = e4.x, s = e4.y;
        int p = __float_as_int(e4.z), q = __float_as_int(e4.w);
        int rch = tid >> 6;
#pragma unroll
        for (int j = 0; j < 4; j++) {
            int rr = rch * 4 + j;
            float x = U[rr][p], y = U[rr][q];
            U[rr][p] = c * x - s * y; U[rr][q] = s * x + c * y;
        }
        __syncthreads();
    }
    float* Uo = Ubuf + (i64)mp * 16384;
    for (int e = tid; e < 16 * 128; e += 256) Uo[(i64)ro0 * 128 + e] = U[e >> 7][e & 127];
}

// etA: z<256: Tbuf[region] = A_region rows @ UJ ; z>=256: V rows (in-place) @ U_pr
__global__ __launch_bounds__(256) void etA_k(const float* __restrict__ Abase,
                                             float* __restrict__ Vbase,
                                             const float* __restrict__ Ubuf,
                                             float* __restrict__ Tbuf, int r)
{
    __shared__ float As[64][132];
    __shared__ float Bs[32][132];
    int z = blockIdx.x, tid = threadIdx.x;
    int tx = tid & 15, ty = tid >> 4;
    bool vpath = (z >= 256);
    const float* srcA; const float* Bsrc;
    float* dstT = nullptr; float* Vw = nullptr;
    int rowbase, gAj, gBj;
    if (!vpath) {
        int region = z >> 1, rt = z & 1;
        int mat = region >> 4, pp = region & 15, pri = pp >> 2, prj = pp & 3;
        int gAi = pos7(pri, r), gBi = pos7(7 - pri, r);
        gAj = pos7(prj, r); gBj = pos7(7 - prj, r);
        rowbase = (rt ? gBi : gAi) * 64;
        srcA = Abase + (i64)mat * HH;
        Bsrc = Ubuf + (i64)(mat * 4 + prj) * 16384;
        dstT = Tbuf + (i64)region * 16384 + (i64)(rt * 64) * 128;
    } else {
        int vz = z - 256;
        int mat = vz >> 5, rest = vz & 31, pp2 = rest >> 3, tm = rest & 7;
        gAj = pos7(pp2, r); gBj = pos7(7 - pp2, r);
        rowbase = tm * 64;
        Vw = Vbase + (i64)mat * HH;
        srcA = Vw;
        Bsrc = Ubuf + (i64)(mat * 4 + pp2) * 16384;
    }
    for (int e = tid; e < 64 * 32; e += 256) {
        int i = e >> 5, k4 = (e & 31) * 4;
        int col = gidx(k4, gAj, gBj);
        *(float4*)&As[i][k4] = *(const float4*)&srcA[(i64)(rowbase + i) * H + col];
    }
    float acc[4][8] = {};
    __syncthreads();
    for (int k0 = 0; k0 < 128; k0 += 32) {
        for (int e = tid; e < 32 * 32; e += 256) {
            int ka = e >> 5, j4 = (e & 31) * 4;
            *(float4*)&Bs[ka][j4] = *(const float4*)&Bsrc[(i64)(k0 + ka) * 128 + j4];
        }
        __syncthreads();
#pragma unroll 4
        for (int kk = 0; kk < 32; kk++) {
            int k = k0 + kk;
            float av[4];
#pragma unroll
            for (int i = 0; i < 4; i++) av[i] = As[ty * 4 + i][k];
            float4 b0 = *(const float4*)&Bs[kk][tx * 8];
            float4 b1 = *(const float4*)&Bs[kk][tx * 8 + 4];
            float bv[8] = {b0.x, b0.y, b0.z, b0.w, b1.x, b1.y, b1.z, b1.w};
#pragma unroll
            for (int i = 0; i < 4; i++)
#pragma unroll
                for (int j = 0; j < 8; j++) acc[i][j] += av[i] * bv[j];
        }
        __syncthreads();
    }
    if (!vpath) {
#pragma unroll
        for (int i = 0; i < 4; i++) {
            int row = ty * 4 + i;
            float4 v0 = {acc[i][0], acc[i][1], acc[i][2], acc[i][3]};
            float4 v1 = {acc[i][4], acc[i][5], acc[i][6], acc[i][7]};
            *(float4*)&dstT[(i64)row * 128 + tx * 8] = v0;
            *(float4*)&dstT[(i64)row * 128 + tx * 8 + 4] = v1;
        }
    } else {
        int colbase = gidx(tx * 8, gAj, gBj);
#pragma unroll
        for (int i = 0; i < 4; i++) {
            int row = rowbase + ty * 4 + i;
            float4 v0 = {acc[i][0], acc[i][1], acc[i][2], acc[i][3]};
            float4 v1 = {acc[i][4], acc[i][5], acc[i][6], acc[i][7]};
            *(float4*)&Vw[(i64)row * H + colbase] = v0;
            *(float4*)&Vw[(i64)row * H + colbase + 4] = v1;
        }
    }
}

// etB: A_region = UI^T @ Tbuf[region]
__global__ __launch_bounds__(256) void etB_k(float* __restrict__ Abase,
                                             const float* __restrict__ Ubuf,
                                             const float* __restrict__ Tbuf, int r)
{
    __shared__ float As[32][68];
    __shared__ float Bs[32][132];
    int z = blockIdx.x, tid = threadIdx.x;
    int tx = tid & 15, ty = tid >> 4;
    int region = z >> 1, rt = z & 1;
    int mat = region >> 4, pp = region & 15, pri = pp >> 2, prj = pp & 3;
    int gAi = pos7(pri, r), gBi = pos7(7 - pri, r);
    int gAj = pos7(prj, r), gBj = pos7(7 - prj, r);
    const float* UI = Ubuf + (i64)(mat * 4 + pri) * 16384;
    const float* T = Tbuf + (i64)region * 16384;
    float* A = Abase + (i64)mat * HH;
    int outrowbase = (rt ? gBi : gAi) * 64;
    float acc[4][8] = {};
    for (int k0 = 0; k0 < 128; k0 += 32) {
        __syncthreads();
        for (int e = tid; e < 32 * 16; e += 256) {
            int ka = e >> 4, i4 = (e & 15) * 4;
            *(float4*)&As[ka][i4] = *(const float4*)&UI[(i64)(k0 + ka) * 128 + rt * 64 + i4];
        }
        for (int e = tid; e < 32 * 32; e += 256) {
            int ka = e >> 5, j4 = (e & 31) * 4;
            *(float4*)&Bs[ka][j4] = *(const float4*)&T[(i64)(k0 + ka) * 128 + j4];
        }
        __syncthreads();
#pragma unroll 4
        for (int kk = 0; kk < 32; kk++) {
            float4 a = *(const float4*)&As[kk][ty * 4];
            float av[4] = {a.x, a.y, a.z, a.w};
            float4 b0 = *(const float4*)&Bs[kk][tx * 8];
            float4 b1 = *(const float4*)&Bs[kk][tx * 8 + 4];
            float bv[8] = {b0.x, b0.y, b0.z, b0.w, b1.x, b1.y, b1.z, b1.w};
#pragma unroll
            for (int i = 0; i < 4; i++)
#pragma unroll
                for (int j = 0; j < 8; j++) acc[i][j] += av[i] * bv[j];
        }
    }
    int colbase = gidx(tx * 8, gAj, gBj);
#pragma unroll
    for (int i = 0; i < 4; i++) {
        int row = outrowbase + ty * 4 + i;
        float4 v0 = {acc[i][0], acc[i][1], acc[i][2], acc[i][3]};
        float4 v1 = {acc[i][4], acc[i][5], acc[i][6], acc[i][7]};
        *(float4*)&A[(i64)row * H + colbase] = v0;
        *(float4*)&A[(i64)row * H + colbase + 4] = v1;
    }
}

__global__ __launch_bounds__(512) void sort_k(const float* __restrict__ Afin,
                                              float* __restrict__ evals, int* __restrict__ rankbuf)
{
    __shared__ float d[512];
    int mat = blockIdx.x, i = threadIdx.x;
    float li = Afin[(i64)mat * HH + (i64)i * H + i];
    d[i] = li; __syncthreads();
    int cnt = 0;
    for (int j = 0; j < 512; j++) { float lj = d[j]; cnt += (lj < li) || (lj == li && j < i); }
    evals[mat * H + cnt] = li;
    if (mat < 4) rankbuf[mat * H + i] = cnt;
}
__global__ void perm_k(const float* __restrict__ Vfin, const int* __restrict__ rankbuf,
                       float* __restrict__ Vs)
{
    i64 e = (i64)blockIdx.x * 256 + threadIdx.x;
    if (e >= (i64)4 * HH) return;
    int mat = (int)(e / HH); i64 o = e % HH;
    int rrow = (int)(o >> 9), i = (int)(o & 511);
    Vs[(i64)mat * HH + (i64)rrow * H + rankbuf[mat * H + i]] = Vfin[e];
}

// ======================= small (3x3, 1x1) eigens =======================
__device__ void jacobi3(float A[3][3], float V[3][3], bool wantV) {
    if (wantV) for (int r = 0; r < 3; r++) for (int c = 0; c < 3; c++) V[r][c] = (r == c) ? 1.f : 0.f;
    const int PP[3] = {0, 0, 1}, QQ[3] = {1, 2, 2};
    for (int sw = 0; sw < 30; sw++)
        for (int e = 0; e < 3; e++) {
            int p = PP[e], q = QQ[e];
            float apq = A[p][q];
            if (fabsf(apq) < 1e-30f) continue;
            float tau = (A[q][q] - A[p][p]) / (2.f * apq);
            float t = copysignf(1.f, tau) / (fabsf(tau) + sqrtf(1.f + tau * tau));
            float c = 1.f / sqrtf(1.f + t * t), s = t * c;
            for (int k = 0; k < 3; k++) { float x = A[p][k], y = A[q][k]; A[p][k] = c * x - s * y; A[q][k] = s * x + c * y; }
            for (int k = 0; k < 3; k++) { float x = A[k][p], y = A[k][q]; A[k][p] = c * x - s * y; A[k][q] = s * x + c * y; }
            if (wantV) for (int k = 0; k < 3; k++) { float x = V[k][p], y = V[k][q]; V[k][p] = c * x - s * y; V[k][q] = s * x + c * y; }
        }
}

__global__ void small_eig_k(const float* Aom0, const float* S_A0,
                            const float* Abd0, const float* S_Ab0,
                            const float* Bom2, const float* S_B2,
                            const float* Bbd2, const float* S_B2b,
                            float* UA0, float* eA0, float* eAb0, float* eScal)
{
    if (threadIdx.x || blockIdx.x) return;
    float A[3][3], V[3][3];
    for (int r = 0; r < 3; r++) for (int c = 0; c < 3; c++) {
        A[r][c] = DEC * Aom0[r * 3 + c] + (1.f - DEC) * S_A0[r * 3 + c] / (float)NI;
        if (r == c) A[r][c] += DAMP;
    }
    jacobi3(A, V, true);
    int ord[3] = {0, 1, 2};
    for (int i = 0; i < 2; i++) for (int j = 0; j < 2 - i; j++)
        if (A[ord[j]][ord[j]] > A[ord[j + 1]][ord[j + 1]]) { int t = ord[j]; ord[j] = ord[j + 1]; ord[j + 1] = t; }
    for (int k = 0; k < 3; k++) { eA0[k] = A[ord[k]][ord[k]]; for (int r = 0; r < 3; r++) UA0[r * 3 + k] = V[r][ord[k]]; }

    for (int r = 0; r < 3; r++) for (int c = 0; c < 3; c++) {
        A[r][c] = DEC * Abd0[r * 3 + c] + (1.f - DEC) * S_Ab0[r * 3 + c] / (float)NB;
        if (r == c) A[r][c] += DAMP;
    }
    jacobi3(A, V, false);
    int ord2[3] = {0, 1, 2};
    for (int i = 0; i < 2; i++) for (int j = 0; j < 2 - i; j++)
        if (A[ord2[j]][ord2[j]] > A[ord2[j + 1]][ord2[j + 1]]) { int t = ord2[j]; ord2[j] = ord2[j + 1]; ord2[j + 1] = t; }
    for (int k = 0; k < 3; k++) eAb0[k] = A[ord2[k]][ord2[k]];

    eScal[0] = DEC * Bom2[0] + (1.f - DEC) * S_B2[0] / (float)NI + DAMP;
    eScal[1] = DEC * Bbd2[0] + (1.f - DEC) * S_B2b[0] / (float)NB + DAMP;
}

// ======================= preconditioning =======================
__global__ void div2_k(float* P, const float* eG, const float* eA,
                       const float* eGb, const float* eAb, int Mg, int Na)
{
    int e = blockIdx.x * 256 + threadIdx.x;
    if (e >= Mg * Na) return;
    int a = e / Na, b = e % Na;
    P[e] /= (eG[a] * eA[b] + eGb[a] * eAb[b]);
}
__global__ void div1_k(float* v, const float* eG, const float* eGb, int Mg)
{
    int e = blockIdx.x * 256 + threadIdx.x;
    if (e >= Mg) return;
    v[e] /= (eG[e] + eGb[e]);
}
__global__ void div2s_k(float* P, const float* eScal, const float* eA, const float* eAb, int Na)
{
    int e = blockIdx.x * 256 + threadIdx.x;
    if (e >= Na) return;
    P[e] /= (eScal[0] * eA[e] + eScal[1] * eAb[e]);
}
__global__ void scal2_k(const float* g, const float* eScal, float* out)
{
    if (threadIdx.x || blockIdx.x) return;
    out[0] = g[0] / (eScal[0] + eScal[1]);
}

// ======================= params concat helpers =======================
__device__ __forceinline__ float pick6(int e, const float* W0, const float* W1, const float* W2,
                                       const float* b0, const float* b1, const float* b2)
{
    if (e < OFF_W1) return W0[e];
    if (e < OFF_W2) return W1[e - OFF_W1];
    if (e < OFF_B0) return W2[e - OFF_W2];
    if (e < OFF_B1) return b0[e - OFF_B0];
    if (e < OFF_B2) return b1[e - OFF_B1];
    return b2[0];
}
__global__ void mom_k(const float* mw0, const float* mw1, const float* mw2,
                      const float* mb0, const float* mb1, const float* mb2,
                      const float* __restrict__ pcat, float* __restrict__ mcat)
{
    int e = blockIdx.x * 256 + threadIdx.x;
    if (e >= TOT) return;
    mcat[e] = 0.9f * pick6(e, mw0, mw1, mw2, mb0, mb1, mb2) + pcat[e];
}
__global__ void upd_k(const float* W0, const float* W1, const float* W2,
                      const float* b0, const float* b1, const float* b2,
                      const float* __restrict__ mcat, float alpha, const float* alphap,
                      float* __restrict__ out)
{
    int e = blockIdx.x * 256 + threadIdx.x;
    if (e >= TOT) return;
    float a = alphap ? alphap[0] : alpha;
    out[e] = pick6(e, W0, W1, W2, b0, b1, b2) - a * mcat[e];
}
__global__ void argmin_k(const float* lossI, const float* lossB, float* bestA)
{
    if (threadIdx.x || blockIdx.x) return;
    float best = 3.4e38f, ba = 0.01f;
    for (int k = 0; k < 5; k++) {
        float l = 0.5f * (lossI[k] / (float)NI) + 0.5f * (lossB[k] / (float)NB);
        float al = 0.01f * (1.0f / (float)(1 << k));
        if (l < best) { best = l; ba = al; }
    }
    bestA[0] = ba;
}

// ======================= line-search mega kernel =======================
// Candidate params computed inline: p_c = p - al*mcat (bitwise same as upd_k)
template<int LAP>
__global__ __launch_bounds__(256) void lsfused_k(
    const float* __restrict__ t0f, const float* __restrict__ W0,
    const float* __restrict__ W1, const float* __restrict__ b1,
    const float* __restrict__ W2, const float* __restrict__ b2,
    const float* __restrict__ mcat, float al,
    int nrows, float* __restrict__ part)
{
    __shared__ float As[32][68];
    __shared__ float Bs[32][68];
    __shared__ float wq[32][4];
    __shared__ float red[64][17];
    int tid = threadIdx.x, tx = tid & 15, ty = tid >> 4;
    int n0 = blockIdx.x * 64, m0 = blockIdx.y * 64;
    float a_t[4][4] = {}, a_g0[4][4] = {}, a_g1[4][4] = {}, a_g2[4][4] = {}, a_l[4][4] = {};
    for (int k0 = 0; k0 < 512; k0 += 32) {
        {
            int n = tid >> 2, kq = (tid & 3) * 4;
            const float* p = &t0f[(i64)(n0 + n) * 512 + k0 + kq];
            float4 v0 = *(const float4*)p, v1 = *(const float4*)(p + 16);
            As[kq + 0][n] = v0.x; As[kq + 1][n] = v0.y;
            As[kq + 2][n] = v0.z; As[kq + 3][n] = v0.w;
            As[kq + 16][n] = v1.x; As[kq + 17][n] = v1.y;
            As[kq + 18][n] = v1.z; As[kq + 19][n] = v1.w;
        }
        {
            int n = tid >> 2, kq = (tid & 3) * 4;
            const float* p = &W1[(i64)(m0 + n) * 512 + k0 + kq];
            const float* pm = &mcat[OFF_W1 + (i64)(m0 + n) * 512 + k0 + kq];
            float4 v0 = *(const float4*)p, v1 = *(const float4*)(p + 16);
            float4 m0v = *(const float4*)pm, m1v = *(const float4*)(pm + 16);
            Bs[kq + 0][n] = v0.x - al * m0v.x; Bs[kq + 1][n] = v0.y - al * m0v.y;
            Bs[kq + 2][n] = v0.z - al * m0v.z; Bs[kq + 3][n] = v0.w - al * m0v.w;
            Bs[kq + 16][n] = v1.x - al * m1v.x; Bs[kq + 17][n] = v1.y - al * m1v.y;
            Bs[kq + 18][n] = v1.z - al * m1v.z; Bs[kq + 19][n] = v1.w - al * m1v.w;
        }
        if (LAP && tid < 32) {
            int j = k0 + tid;
            float w0 = W0[j * 3] - al * mcat[j * 3];
            float w1 = W0[j * 3 + 1] - al * mcat[j * 3 + 1];
            float w2 = W0[j * 3 + 2] - al * mcat[j * 3 + 2];
            wq[tid][0] = w0; wq[tid][1] = w1; wq[tid][2] = w2;
            wq[tid][3] = w0 * w0 + w1 * w1 + w2 * w2;
        }
        __syncthreads();
#pragma unroll
        for (int ks = 0; ks < 32; ks++) {
            float4 a = *(const float4*)&As[ks][ty * 4];
            float4 b = *(const float4*)&Bs[ks][tx * 4];
            float av[4] = {a.x, a.y, a.z, a.w};
            float bv[4] = {b.x, b.y, b.z, b.w};
            if (LAP) {
                float w0 = wq[ks][0], w1 = wq[ks][1], w2 = wq[ks][2], q0 = wq[ks][3];
                float gv0[4], gv1[4], gv2[4], lv[4];
#pragma unroll
                for (int i = 0; i < 4; i++) {
                    float t = av[i], phi = 1.f - t * t, u = -2.f * t * phi;
                    gv0[i] = phi * w0; gv1[i] = phi * w1; gv2[i] = phi * w2; lv[i] = u * q0;
                }
#pragma unroll
                for (int i = 0; i < 4; i++)
#pragma unroll
                    for (int j = 0; j < 4; j++) {
                        a_t[i][j]  += av[i]  * bv[j];
                        a_g0[i][j] += gv0[i] * bv[j];
                        a_g1[i][j] += gv1[i] * bv[j];
                        a_g2[i][j] += gv2[i] * bv[j];
                        a_l[i][j]  += lv[i]  * bv[j];
                    }
            } else {
#pragma unroll
                for (int i = 0; i < 4; i++)
#pragma unroll
                    for (int j = 0; j < 4; j++) a_t[i][j] += av[i] * bv[j];
            }
        }
        __syncthreads();
    }
    float rowpart[4];
#pragma unroll
    for (int i = 0; i < 4; i++) {
        rowpart[i] = 0.f;
#pragma unroll
        for (int j = 0; j < 4; j++) {
            int m = m0 + tx * 4 + j;
            float s = a_t[i][j] + (b1[m] - al * mcat[OFF_B1 + m]);
            float t1 = tanhf(s);
            float val;
            if (LAP) {
                float phi = 1.f - t1 * t1, u = -2.f * t1 * phi;
                float q = a_g0[i][j] * a_g0[i][j] + a_g1[i][j] * a_g1[i][j] + a_g2[i][j] * a_g2[i][j];
                val = phi * a_l[i][j] + u * q;
            } else val = t1;
            rowpart[i] += val * (W2[m] - al * mcat[OFF_W2 + m]);
        }
    }
#pragma unroll
    for (int i = 0; i < 4; i++) red[ty * 4 + i][tx] = rowpart[i];
    __syncthreads();
    if (tid < 64) {
        float s = 0.f;
#pragma unroll
        for (int x = 0; x < 16; x++) s += red[tid][x];
        if (!LAP && blockIdx.y == 0) s += (b2[0] - al * mcat[OFF_B2]);
        part[(i64)blockIdx.y * nrows + n0 + tid] = s;
    }
}

__global__ __launch_bounds__(256) void lsred_k(const float* __restrict__ pI,
                                               const float* __restrict__ pB,
                                               const float* __restrict__ Xi,
                                               const float* __restrict__ Xb,
                                               float* __restrict__ lossI,
                                               float* __restrict__ lossB)
{
    __shared__ float red[256];
    int z = blockIdx.x, a = z >> 1, isB = z & 1;
    int rows = isB ? NB : NI;
    const float* src = isB ? (pB + (i64)a * 8 * NB) : (pI + (i64)a * 8 * NI);
    const float* X = isB ? Xb : Xi;
    float acc = 0.f;
    for (int n = threadIdx.x; n < rows; n += 256) {
        float s = 0.f;
#pragma unroll
        for (int t = 0; t < 8; t++) s += src[(i64)t * rows + n];
        const float* x = X + (i64)n * 3;
        float rhs = isB ? (cosf(x[0]) + cosf(x[1]) + cosf(x[2]))
                        : (sinf(x[0]) + sinf(x[1]) + sinf(x[2]));
        float r = s - rhs;
        acc += r * r;
    }
    red[threadIdx.x] = acc; __syncthreads();
    for (int off = 128; off; off >>= 1) {
        if (threadIdx.x < off) red[threadIdx.x] += red[threadIdx.x + off];
        __syncthreads();
    }
    if (threadIdx.x == 0) {
        if (isB) lossB[a] = red[0];
        else lossI[a] = red[0];
    }
}

// ======================= host helpers =======================
template<int MODE>
static inline void g64(hipStream_t st, const float* A, const float* B, float* C,
                       int M, int N, int K) {
    dim3 g((M + 63) / 64, (N + 63) / 64);
    bool fast = (M % 64 == 0) && (N % 64 == 0) && (K % 32 == 0);
    if (fast) gemm64_k<MODE, 0, 0, 1, 0><<<g, 256, 0, st>>>(A, B, nullptr, C, M, N, K, nullptr, nullptr);
    else      gemm64_k<MODE, 0, 0, 0, 0><<<g, 256, 0, st>>>(A, B, nullptr, C, M, N, K, nullptr, nullptr);
}
static inline void g64_bt(hipStream_t st, const float* A, const float* B, const float* bias,
                          float* C, int M, int N, int K) {
    dim3 g((M + 63) / 64, (N + 63) / 64);
    gemm64_k<0, 1, 1, 1, 0><<<g, 256, 0, st>>>(A, B, bias, C, M, N, K, nullptr, nullptr);
}
static inline void g64_aux1(hipStream_t st, const float* A, const float* B, float* C,
                            int M, int N, int K, const float* t0p, float* dst2) {
    dim3 g((M + 63) / 64, (N + 63) / 64);
    gemm64_k<1, 0, 0, 1, 1><<<g, 256, 0, st>>>(A, B, nullptr, C, M, N, K, t0p, dst2);
}
static inline void g64_aux2(hipStream_t st, const float* A, const float* B, float* C,
                            int M, int N, int K, const float* t0p) {
    dim3 g((M + 63) / 64, (N + 63) / 64);
    gemm64_k<1, 0, 0, 1, 2><<<g, 256, 0, st>>>(A, B, nullptr, C, M, N, K, t0p, nullptr);
}
static inline void g_sk(hipStream_t st, const float* A, const float* B, float* dst,
                        int M, int N, int K, float* skbuf) {
    int Ks = ((K / 8) + 31) / 32 * 32;
    if (Ks * 8 < K) Ks += 32;
    dim3 g((M + 63) / 64, (N + 63) / 64, 8);
    bool fast = (M % 64 == 0) && (N % 64 == 0) && (K == Ks * 8);
    if (fast) gemm_tn_sk_k<1><<<g, 256, 0, st>>>(A, B, skbuf, M, N, K, Ks);
    else      gemm_tn_sk_k<0><<<g, 256, 0, st>>>(A, B, skbuf, M, N, K, Ks);
    int cnt = M * N;
    sk_red_k<<<(cnt + 255) / 256, 256, 0, st>>>(dst, skbuf, cnt);
}

extern "C" void kernel_launch(void* const* d_in, const int* in_sizes, int n_in,
                              void* d_out, int out_size, void* d_ws, size_t ws_size,
                              hipStream_t stream)
{
    const float* Xi   = (const float*)d_in[0];
    const float* Xb   = (const float*)d_in[1];
    const float* W0   = (const float*)d_in[2];
    const float* b0   = (const float*)d_in[3];
    const float* Aom0 = (const float*)d_in[4];
    const float* Bom0 = (const float*)d_in[5];
    const float* Abd0 = (const float*)d_in[6];
    const float* Bbd0 = (const float*)d_in[7];
    const float* mw0  = (const float*)d_in[8];
    const float* mb0  = (const float*)d_in[9];
    const float* W1   = (const float*)d_in[10];
    const float* b1   = (const float*)d_in[11];
    const float* Aom1 = (const float*)d_in[12];
    const float* Bom1 = (const float*)d_in[13];
    const float* Abd1 = (const float*)d_in[14];
    const float* Bbd1 = (const float*)d_in[15];
    const float* mw1  = (const float*)d_in[16];
    const float* mb1  = (const float*)d_in[17];
    const float* W2   = (const float*)d_in[18];
    const float* b2   = (const float*)d_in[19];
    const float* Aom2 = (const float*)d_in[20];
    const float* Bom2 = (const float*)d_in[21];
    const float* Abd2 = (const float*)d_in[22];
    const float* Bbd2 = (const float*)d_in[23];
    const float* mw2  = (const float*)d_in[24];
    const float* mb2  = (const float*)d_in[25];

    float* w = (float*)d_ws;
    i64 off = 0;
    auto alloc = [&](i64 n) { float* p = w + off; off += n; return p; };

    const i64 M1 = 1048576;
    float* arena = alloc(15 * M1);
    float* t0c = arena + 0 * M1;
    float* t1c = arena + 1 * M1;
    float* l1c = arena + 2 * M1;
    float* ls1c = arena + 3 * M1;
    float* l2c = arena + 5 * M1;
    float* d1c = arena + 6 * M1;
    float* e1c = arena + 7 * M1;
    float* f1c = arena + 8 * M1;
    float* g1c = arena + 9 * M1;
    float* gs1c = arena + 12 * M1;
    float* skbuf = arena + 4 * M1;
    // eigen views
    float* Aeig = arena + 0 * M1;
    float* Veig = arena + 2 * M1;
    float* Ubuf = arena + 3 * M1;
    float* Vs   = arena + 3 * M1 + 524288;
    float* rlog = arena + 5 * M1;
    float* Tbuf = arena + 8 * M1;
    // precond / LS views
    float* P1 = arena + 8 * M1;
    float* P2 = arena + 8 * M1 + HH;
    float* t0f = arena + 0 * M1;
    float* t0b = arena + 8 * M1;
    float* pI  = arena + 9 * M1;
    float* pB  = arena + 10 * M1;

    float* ri = alloc(NI);
    float* rb = alloc(NB);
    float* zero_base = w + off;
    float* S8   = alloc(8 * (i64)HH);
    float* S_A0 = alloc(9);
    float* S_Ab0 = alloc(9);
    float* S_B2 = alloc(1);
    float* S_B2b = alloc(1);
    float* gW0 = alloc(1536);
    float* gW1 = alloc(HH);
    float* gW2 = alloc(H);
    float* gb0v = alloc(H);
    float* gb1v = alloc(H);
    float* gb2v = alloc(1);
    float* lossI = alloc(5);
    float* lossB = alloc(5);
    i64 zero_count = (w + off) - zero_base;
    float* UA0 = alloc(9);
    float* eA0 = alloc(3);
    float* eAb0 = alloc(3);
    float* eScal = alloc(2);
    float* evals = alloc(4096);
    int*   ranks = (int*)alloc(2048);
    float* pcat = alloc(TOT);
    float* mcat = alloc(TOT);
    float* ccat = alloc(TOT);
    float* bestA = alloc(1);
    float* wpart = alloc(3 * 16 * H);
    float* b0part = alloc(8 * 2048);
    if (ws_size < (size_t)off * sizeof(float)) return;

    hipStream_t st = stream;
    zero_k<<<(int)((zero_count + 255) / 256), 256, 0, st>>>(zero_base, zero_count);

    const int EW = (CH * H + 255) / 256;

    // ---------------- interior chunks ----------------
    for (int c = 0; c < 4; c++) {
        const float* Xc = Xi + (i64)c * CH * 3;
        float* ric = ri + (i64)c * CH;
        fwd0_k<1, 0><<<EW, 256, 0, st>>>(Xc, W0, b0, CH, t0c, g1c, l1c, nullptr, 0.f);
        g64_bt(st, t0c, W1, b1, t1c, CH, H, H);
        g64<0>(st, g1c, W1, gs1c, 3 * CH, H, H);
        g64<0>(st, l1c, W1, ls1c, CH, H, H);
        lapbwd_k<<<CH, 256, 0, st>>>(t1c, ls1c, gs1c, W2, Xc, 1.f / NI, l2c, f1c, d1c, ric);
        g64_aux1(st, d1c, W1, ls1c, CH, H, H, t0c, e1c);        // bar_l1 + delta0
        {
            WJ wj = {};
            wj.src[0] = l2c; wj.wgt[0] = ric; wj.scale[0] = 1.f / NI; wj.dst[0] = gW2;
            wj.src[1] = f1c; wj.wgt[1] = nullptr; wj.scale[1] = 1.f; wj.dst[1] = gb1v;
            wcolp_k<<<dim3(2, 16, 2), 256, 0, st>>>(wj, CH, wpart);
            wcolr_k<<<dim3(2, 2), 256, 0, st>>>(wj, wpart);
        }
        {   // batched Gram: Bo1, Bo0, Ao1, Ao2
            SkBatch sb = {};
            sb.A[0] = d1c; sb.B[0] = d1c;
            sb.A[1] = e1c; sb.B[1] = e1c;
            sb.A[2] = t0c; sb.B[2] = t0c;
            sb.A[3] = t1c; sb.B[3] = t1c;
            sb.Ks = 1024;
            for (int z = 0; z < 8; z++) { sb.job_of_z[z] = z >> 1; sb.kb_of_z[z] = (z & 1) * 1024; }
            skb_k<<<dim3(8, 8, 8), 256, 0, st>>>(sb, skbuf);
            RedJ rj = {};
            rj.dst[0] = S8 + 2 * (i64)HH; rj.dst[1] = S8 + 0 * (i64)HH;
            rj.dst[2] = S8 + 1 * (i64)HH; rj.dst[3] = S8 + 3 * (i64)HH;
            rj.off[0] = 0; rj.off[1] = 2; rj.off[2] = 4; rj.off[3] = 6; rj.off[4] = 8;
            skred_k<<<dim3(1024, 4), 256, 0, st>>>(rj, skbuf);
        }
        {   // batched gW1
            SkBatch sb = {};
            sb.A[0] = f1c;  sb.B[0] = t0c;
            sb.A[1] = gs1c; sb.B[1] = g1c;
            sb.A[2] = d1c;  sb.B[2] = l1c;
            sb.Ks = 2048;
            int jo[5] = {0, 1, 1, 1, 2};
            int kb[5] = {0, 0, 2048, 4096, 0};
            for (int z = 0; z < 5; z++) { sb.job_of_z[z] = jo[z]; sb.kb_of_z[z] = kb[z]; }
            skb_k<<<dim3(8, 8, 5), 256, 0, st>>>(sb, skbuf);
            RedJ rj = {};
            rj.dst[0] = gW1;
            rj.off[0] = 0; rj.off[1] = 5;
            skred_k<<<dim3(1024, 1), 256, 0, st>>>(rj, skbuf);
        }
        g64<1>(st, f1c, W1, l2c, CH, H, H);                     // bar_t0
        g64<1>(st, gs1c, W1, g1c, 3 * CH, H, H);                // bar_g1
        bwd0p_k<<<dim3(2, 8), 256, 0, st>>>(Xc, CH, W0, t0c, l2c, ls1c, g1c, b0part);
        bwd0red_k<<<8, 256, 0, st>>>(b0part, gW0, gb0v);
    }

    // ---------------- boundary ----------------
    fwd0_k<0, 0><<<(NB * H + 255) / 256, 256, 0, st>>>(Xb, W0, b0, NB, t0c, nullptr, nullptr, nullptr, 0.f);
    g64_bt(st, t0c, W1, b1, t1c, NB, H, H);
    bnd_fin_k<<<NB / 4, 256, 0, st>>>(t1c, W2, b2, Xb, NB, rb);
    dualred_k<<<2, 256, 0, st>>>(ri, rb, S_B2, gb2v, S_B2b);
    delta1_k<<<(NB * H + 255) / 256, 256, 0, st>>>(t1c, rb, W2, 1.f / NB, d1c, NB);
    {
        SkBatch sb = {};
        sb.A[0] = d1c; sb.B[0] = d1c;
        sb.A[1] = t0c; sb.B[1] = t0c;
        sb.A[2] = t1c; sb.B[2] = t1c;
        sb.Ks = 1024;
        for (int z = 0; z < 6; z++) { sb.job_of_z[z] = z >> 1; sb.kb_of_z[z] = (z & 1) * 1024; }
        skb_k<<<dim3(8, 8, 6), 256, 0, st>>>(sb, skbuf);
        RedJ rj = {};
        rj.dst[0] = S8 + 6 * (i64)HH; rj.dst[1] = S8 + 5 * (i64)HH; rj.dst[2] = S8 + 7 * (i64)HH;
        rj.off[0] = 0; rj.off[1] = 2; rj.off[2] = 4; rj.off[3] = 6;
        skred_k<<<dim3(1024, 3), 256, 0, st>>>(rj, skbuf);
    }
    g_sk(st, d1c, t0c, gW1, H, H, NB, skbuf);
    g64_aux2(st, d1c, W1, e1c, NB, H, H, t0c);
    {
        WJ wj = {};
        wj.src[0] = t1c; wj.wgt[0] = rb; wj.scale[0] = 1.f / NB; wj.dst[0] = gW2;
        wj.src[1] = d1c; wj.wgt[1] = nullptr; wj.scale[1] = 1.f; wj.dst[1] = gb1v;
        wj.src[2] = e1c; wj.wgt[2] = nullptr; wj.scale[2] = 1.f; wj.dst[2] = gb0v;
        wcolp_k<<<dim3(2, 16, 3), 256, 0, st>>>(wj, NB, wpart);
        wcolr_k<<<dim3(2, 3), 256, 0, st>>>(wj, wpart);
    }
    g_sk(st, e1c, e1c, S8 + 4 * (i64)HH, H, H, NB, skbuf);
    g_sk(st, e1c, Xb, gW0, H, 3, NB, skbuf);
    xtx3b_k<<<2, 256, 0, st>>>(Xi, Xb, S_A0, S_Ab0);

    // ---------------- factor build + eigensolve ----------------
    {
        P8 mom = {};
        mom.p[0] = Bom0; mom.p[1] = Aom1; mom.p[2] = Bom1; mom.p[3] = Aom2;
        mom.p[4] = Bbd0; mom.p[5] = Abd1; mom.p[6] = Bbd1; mom.p[7] = Abd2;
        fbuildb_k<<<dim3(1024, 8), 256, 0, st>>>(mom, S8, Aeig);
    }
    identv_k<<<(int)((4 * (i64)HH + 255) / 256), 256, 0, st>>>(Veig, 4 * (i64)HH);
    small_eig_k<<<1, 1, 0, st>>>(Aom0, S_A0, Abd0, S_Ab0, Bom2, S_B2, Bbd2, S_B2b,
                                 UA0, eA0, eAb0, eScal);

    for (int sw = 0; sw < SOUTER; sw++)
        for (int r = 0; r < 7; r++) {
            eig_sub_k<<<dim3(4, 8), 1024, 0, st>>>(Aeig, rlog, r);
            ubuild_k<<<dim3(8, 32), 256, 0, st>>>(rlog, Ubuf);
            etA_k<<<384, 256, 0, st>>>(Aeig, Veig, Ubuf, Tbuf, r);
            etB_k<<<256, 256, 0, st>>>(Aeig, Ubuf, Tbuf, r);
        }
    sort_k<<<8, 512, 0, st>>>(Aeig, evals, ranks);
    perm_k<<<(int)((4 * (i64)HH + 255) / 256), 256, 0, st>>>(Veig, ranks, Vs);

    // ---------------- preconditioning ----------------
    g64<2>(st, Vs + 0 * (i64)HH, gW0, P1, H, 3, H);
    g64<1>(st, P1, UA0, P2, H, 3, 3);
    div2_k<<<6, 256, 0, st>>>(P2, evals + 0 * H, eA0, evals + 4 * H, eAb0, H, 3);
    g64<1>(st, Vs + 0 * (i64)HH, P2, P1, H, 3, H);
    g64<0>(st, P1, UA0, pcat + 0, H, 3, 3);
    g64<2>(st, Vs + 0 * (i64)HH, gb0v, P2, H, 1, H);
    div1_k<<<2, 256, 0, st>>>(P2, evals + 0 * H, evals + 4 * H, H);
    g64<1>(st, Vs + 0 * (i64)HH, P2, pcat + OFF_B0, H, 1, H);

    g64<2>(st, Vs + 2 * (i64)HH, gW1, P1, H, H, H);
    g64<1>(st, P1, Vs + 1 * (i64)HH, P2, H, H, H);
    div2_k<<<1024, 256, 0, st>>>(P2, evals + 2 * H, evals + 1 * H, evals + 6 * H, evals + 5 * H, H, H);
    g64<1>(st, Vs + 2 * (i64)HH, P2, P1, H, H, H);
    g64<0>(st, P1, Vs + 1 * (i64)HH, pcat + OFF_W1, H, H, H);
    g64<2>(st, Vs + 2 * (i64)HH, gb1v, P2, H, 1, H);
    div1_k<<<2, 256, 0, st>>>(P2, evals + 2 * H, evals + 6 * H, H);
    g64<1>(st, Vs + 2 * (i64)HH, P2, pcat + OFF_B1, H, 1, H);

    g64<1>(st, gW2, Vs + 3 * (i64)HH, P2, 1, H, H);
    div2s_k<<<2, 256, 0, st>>>(P2, eScal, evals + 3 * H, evals + 7 * H, H);
    g64<0>(st, P2, Vs + 3 * (i64)HH, pcat + OFF_W2, 1, H, H);
    scal2_k<<<1, 1, 0, st>>>(gb2v, eScal, pcat + OFF_B2);

    // ---------------- momentum ----------------
    mom_k<<<(TOT + 255) / 256, 256, 0, st>>>(mw0, mw1, mw2, mb0, mb1, mb2, pcat, mcat);

    // ---------------- line search (candidate params computed inline) ----------------
    for (int a = 0; a < 5; a++) {
        float al = 0.01f * (1.0f / (float)(1 << a));
        fwd0_k<0, 1><<<(NI * H + 255) / 256, 256, 0, st>>>(Xi, W0, b0, NI, t0f,
                                                           nullptr, nullptr, mcat, al);
        lsfused_k<1><<<dim3(NI / 64, 8), 256, 0, st>>>(t0f, W0, W1, b1, W2, b2, mcat, al,
                                                       NI, pI + (i64)a * 8 * NI);
        fwd0_k<0, 1><<<(NB * H + 255) / 256, 256, 0, st>>>(Xb, W0, b0, NB, t0b,
                                                           nullptr, nullptr, mcat, al);
        lsfused_k<0><<<dim3(NB / 64, 8), 256, 0, st>>>(t0b, W0, W1, b1, W2, b2, mcat, al,
                                                       NB, pB + (i64)a * 8 * NB);
    }
    lsred_k<<<10, 256, 0, st>>>(pI, pB, Xi, Xb, lossI, lossB);
    argmin_k<<<1, 1, 0, st>>>(lossI, lossB, bestA);
    upd_k<<<(TOT + 255) / 256, 256, 0, st>>>(W0, W1, W2, b0, b1, b2, mcat, 0.f, bestA,
                                             (float*)d_out);
}

// Round 8
// 18295.479 us; speedup vs baseline: 1.2533x; 1.2533x over previous
//
#include <hip/hip_runtime.h>
#include <cmath>

typedef long long i64;

#define NI 8192
#define NB 2048
#define CH 2048
#define H  512
#define HH 262144
#define TOT 265217
#define OFF_W1 1536
#define OFF_W2 263680
#define OFF_B0 264192
#define OFF_B1 264704
#define OFF_B2 265216
#define DAMP 1e-3f
#define DEC  0.95f
#define INNER 3
#define SOUTER 2
#define STEPS (INNER * 127)

__device__ __forceinline__ int imin(int a, int b) { return a < b ? a : b; }

// ======================= 64x64 GEMM, K-tile 32 =======================
template<int MODE, int BIAS, int TANH_, int FAST, int AUX>
__global__ __launch_bounds__(256) void gemm64_k(
    const float* __restrict__ A, const float* __restrict__ B,
    const float* __restrict__ bias, float* __restrict__ C,
    int M, int N, int K, const float* __restrict__ t0p, float* __restrict__ dst2)
{
    __shared__ float As[32][68];
    __shared__ float Bs[32][68];
    int tid = threadIdx.x;
    int tx = tid & 15, ty = tid >> 4;
    int m0 = blockIdx.x * 64, n0 = blockIdx.y * 64;
    float acc[4][4] = {};
    for (int k0 = 0; k0 < K; k0 += 32) {
        if (MODE == 0 || MODE == 1) {
            int m = tid >> 2, kq = (tid & 3) * 4;
            if (FAST) {
                const float* Ap = &A[(i64)(m0 + m) * K + k0 + kq];
                float4 v0 = *(const float4*)Ap;
                float4 v1 = *(const float4*)(Ap + 16);
                As[kq + 0][m] = v0.x; As[kq + 1][m] = v0.y;
                As[kq + 2][m] = v0.z; As[kq + 3][m] = v0.w;
                As[kq + 16][m] = v1.x; As[kq + 17][m] = v1.y;
                As[kq + 18][m] = v1.z; As[kq + 19][m] = v1.w;
            } else {
                int mm = m0 + m;
#pragma unroll
                for (int h = 0; h < 32; h += 16)
#pragma unroll
                    for (int i = 0; i < 4; i++) {
                        int kk = k0 + h + kq + i;
                        As[h + kq + i][m] = (mm < M && kk < K) ? A[(i64)mm * K + kk] : 0.f;
                    }
            }
        } else {
            int k = tid >> 4, mq = (tid & 15) * 4;
            if (FAST) {
                *(float4*)&As[k][mq]      = *(const float4*)&A[(i64)(k0 + k) * M + m0 + mq];
                *(float4*)&As[k + 16][mq] = *(const float4*)&A[(i64)(k0 + k + 16) * M + m0 + mq];
            } else {
#pragma unroll
                for (int h = 0; h < 32; h += 16) {
                    int kk = k0 + k + h;
#pragma unroll
                    for (int i = 0; i < 4; i++) {
                        int mm = m0 + mq + i;
                        As[k + h][mq + i] = (kk < K && mm < M) ? A[(i64)kk * M + mm] : 0.f;
                    }
                }
            }
        }
        if (MODE == 0) {
            int n = tid >> 2, kq = (tid & 3) * 4;
            if (FAST) {
                const float* Bp = &B[(i64)(n0 + n) * K + k0 + kq];
                float4 v0 = *(const float4*)Bp;
                float4 v1 = *(const float4*)(Bp + 16);
                Bs[kq + 0][n] = v0.x; Bs[kq + 1][n] = v0.y;
                Bs[kq + 2][n] = v0.z; Bs[kq + 3][n] = v0.w;
                Bs[kq + 16][n] = v1.x; Bs[kq + 17][n] = v1.y;
                Bs[kq + 18][n] = v1.z; Bs[kq + 19][n] = v1.w;
            } else {
                int nn = n0 + n;
#pragma unroll
                for (int h = 0; h < 32; h += 16)
#pragma unroll
                    for (int i = 0; i < 4; i++) {
                        int kk = k0 + h + kq + i;
                        Bs[h + kq + i][n] = (nn < N && kk < K) ? B[(i64)nn * K + kk] : 0.f;
                    }
            }
        } else {
            int k = tid >> 4, nq = (tid & 15) * 4;
            if (FAST) {
                *(float4*)&Bs[k][nq]      = *(const float4*)&B[(i64)(k0 + k) * N + n0 + nq];
                *(float4*)&Bs[k + 16][nq] = *(const float4*)&B[(i64)(k0 + k + 16) * N + n0 + nq];
            } else {
#pragma unroll
                for (int h = 0; h < 32; h += 16) {
                    int kk = k0 + k + h;
#pragma unroll
                    for (int i = 0; i < 4; i++) {
                        int nn = n0 + nq + i;
                        Bs[k + h][nq + i] = (kk < K && nn < N) ? B[(i64)kk * N + nn] : 0.f;
                    }
                }
            }
        }
        __syncthreads();
#pragma unroll
        for (int ks = 0; ks < 32; ks++) {
            float4 a = *(const float4*)&As[ks][ty * 4];
            float4 b = *(const float4*)&Bs[ks][tx * 4];
            float av[4] = {a.x, a.y, a.z, a.w};
            float bv[4] = {b.x, b.y, b.z, b.w};
#pragma unroll
            for (int i = 0; i < 4; i++)
#pragma unroll
                for (int j = 0; j < 4; j++) acc[i][j] += av[i] * bv[j];
        }
        __syncthreads();
    }
#pragma unroll
    for (int i = 0; i < 4; i++) {
        int m = m0 + ty * 4 + i;
        if (!FAST && m >= M) continue;
        if (FAST) {
            float4 vc, v2;
            float* pc = (float*)&vc; float* p2 = (float*)&v2;
            float4 t0v;
            if (AUX) t0v = *(const float4*)&t0p[(i64)m * N + n0 + tx * 4];
            const float* t0a = (const float*)&t0v;
#pragma unroll
            for (int j = 0; j < 4; j++) {
                float t = acc[i][j];
                if (BIAS) t += bias[n0 + tx * 4 + j];
                if (TANH_) t = tanhf(t);
                if (AUX == 1) { pc[j] = t; p2[j] = (1.f - t0a[j] * t0a[j]) * t; }
                else if (AUX == 2) { pc[j] = (1.f - t0a[j] * t0a[j]) * t; }
                else pc[j] = t;
            }
            *(float4*)&C[(i64)m * N + n0 + tx * 4] = vc;
            if (AUX == 1) *(float4*)&dst2[(i64)m * N + n0 + tx * 4] = v2;
        } else {
#pragma unroll
            for (int j = 0; j < 4; j++) {
                int n = n0 + tx * 4 + j;
                if (n >= N) continue;
                float t = acc[i][j];
                if (BIAS) t += bias[n];
                if (TANH_) t = tanhf(t);
                if (AUX) {
                    float t0v = t0p[(i64)m * N + n];
                    if (AUX == 1) { C[(i64)m * N + n] = t; dst2[(i64)m * N + n] = (1.f - t0v * t0v) * t; }
                    else C[(i64)m * N + n] = (1.f - t0v * t0v) * t;
                } else C[(i64)m * N + n] = t;
            }
        }
    }
}

// single split-K TN (slow/odd shapes)
template<int FAST>
__global__ __launch_bounds__(256) void gemm_tn_sk_k(
    const float* __restrict__ A, const float* __restrict__ B,
    float* __restrict__ P, int M, int N, int K, int Ks)
{
    __shared__ float As[32][68];
    __shared__ float Bs[32][68];
    int tid = threadIdx.x;
    int tx = tid & 15, ty = tid >> 4;
    int m0 = blockIdx.x * 64, n0 = blockIdx.y * 64, s = blockIdx.z;
    int kb = s * Ks, ke = imin(K, kb + Ks);
    float acc[4][4] = {};
    for (int k0 = kb; k0 < ke; k0 += 32) {
        int k = tid >> 4, q = (tid & 15) * 4;
        if (FAST) {
            *(float4*)&As[k][q]      = *(const float4*)&A[(i64)(k0 + k) * M + m0 + q];
            *(float4*)&As[k + 16][q] = *(const float4*)&A[(i64)(k0 + k + 16) * M + m0 + q];
            *(float4*)&Bs[k][q]      = *(const float4*)&B[(i64)(k0 + k) * N + n0 + q];
            *(float4*)&Bs[k + 16][q] = *(const float4*)&B[(i64)(k0 + k + 16) * N + n0 + q];
        } else {
#pragma unroll
            for (int h = 0; h < 32; h += 16) {
                int kk = k0 + k + h;
#pragma unroll
                for (int i = 0; i < 4; i++) {
                    int mm = m0 + q + i, nn = n0 + q + i;
                    As[k + h][q + i] = (kk < ke && mm < M) ? A[(i64)kk * M + mm] : 0.f;
                    Bs[k + h][q + i] = (kk < ke && nn < N) ? B[(i64)kk * N + nn] : 0.f;
                }
            }
        }
        __syncthreads();
#pragma unroll
        for (int ks = 0; ks < 32; ks++) {
            float4 a = *(const float4*)&As[ks][ty * 4];
            float4 b = *(const float4*)&Bs[ks][tx * 4];
            float av[4] = {a.x, a.y, a.z, a.w};
            float bv[4] = {b.x, b.y, b.z, b.w};
#pragma unroll
            for (int i = 0; i < 4; i++)
#pragma unroll
                for (int j = 0; j < 4; j++) acc[i][j] += av[i] * bv[j];
        }
        __syncthreads();
    }
    float* Po = P + (i64)s * M * N;
#pragma unroll
    for (int i = 0; i < 4; i++) {
        int m = m0 + ty * 4 + i;
        if (m >= M) continue;
#pragma unroll
        for (int j = 0; j < 4; j++) {
            int n = n0 + tx * 4 + j;
            if (n >= N) continue;
            Po[(i64)m * N + n] = acc[i][j];
        }
    }
}
__global__ void sk_red_k(float* __restrict__ dst, const float* __restrict__ P, int cnt)
{
    int e = blockIdx.x * 256 + threadIdx.x;
    if (e >= cnt) return;
    float s = 0.f;
#pragma unroll
    for (int z = 0; z < 8; z++) s += P[(i64)z * cnt + e];
    dst[e] += s;
}

// ======== batched TN Gram/grad GEMMs (M=N=512, fast path only) ========
struct SkBatch {
    const float* A[5]; const float* B[5];
    int job_of_z[8];
    int kb_of_z[8];
    int Ks;
};
__global__ __launch_bounds__(256) void skb_k(SkBatch sb, float* __restrict__ P)
{
    __shared__ float As[32][68];
    __shared__ float Bs[32][68];
    int tid = threadIdx.x;
    int tx = tid & 15, ty = tid >> 4;
    int m0 = blockIdx.x * 64, n0 = blockIdx.y * 64, z = blockIdx.z;
    int j = sb.job_of_z[z];
    const float* A = sb.A[j]; const float* B = sb.B[j];
    int kb = sb.kb_of_z[z], ke = kb + sb.Ks;
    float acc[4][4] = {};
    for (int k0 = kb; k0 < ke; k0 += 32) {
        int k = tid >> 4, q = (tid & 15) * 4;
        *(float4*)&As[k][q]      = *(const float4*)&A[(i64)(k0 + k) * H + m0 + q];
        *(float4*)&As[k + 16][q] = *(const float4*)&A[(i64)(k0 + k + 16) * H + m0 + q];
        *(float4*)&Bs[k][q]      = *(const float4*)&B[(i64)(k0 + k) * H + n0 + q];
        *(float4*)&Bs[k + 16][q] = *(const float4*)&B[(i64)(k0 + k + 16) * H + n0 + q];
        __syncthreads();
#pragma unroll
        for (int ks = 0; ks < 32; ks++) {
            float4 a = *(const float4*)&As[ks][ty * 4];
            float4 b = *(const float4*)&Bs[ks][tx * 4];
            float av[4] = {a.x, a.y, a.z, a.w};
            float bv[4] = {b.x, b.y, b.z, b.w};
#pragma unroll
            for (int i = 0; i < 4; i++)
#pragma unroll
                for (int jj = 0; jj < 4; jj++) acc[i][jj] += av[i] * bv[jj];
        }
        __syncthreads();
    }
    float* Po = P + (i64)z * HH;
#pragma unroll
    for (int i = 0; i < 4; i++) {
        int m = m0 + ty * 4 + i;
#pragma unroll
        for (int jj = 0; jj < 4; jj++)
            Po[(i64)m * H + n0 + tx * 4 + jj] = acc[i][jj];
    }
}
struct RedJ { float* dst[4]; int off[5]; };
__global__ void skred_k(RedJ rj, const float* __restrict__ P)
{
    int e = blockIdx.x * 256 + threadIdx.x;
    int j = blockIdx.y;
    if (e >= HH) return;
    float s = 0.f;
    for (int z = rj.off[j]; z < rj.off[j + 1]; z++) s += P[(i64)z * HH + e];
    rj.dst[j][e] += s;
}

// ======================= elementwise / fused =======================
__global__ void zero_k(float* p, i64 n) {
    i64 e = (i64)blockIdx.x * 256 + threadIdx.x;
    if (e < n) p[e] = 0.f;
}

template<int FULL>
__global__ __launch_bounds__(256) void fwd0_k(
    const float* __restrict__ X, const float* __restrict__ W0,
    const float* __restrict__ b0, int rows,
    float* __restrict__ t0c, float* __restrict__ g1c, float* __restrict__ l1c)
{
    int e = blockIdx.x * 256 + threadIdx.x;
    if (e >= rows * H) return;
    int n = e >> 9, j = e & 511;
    const float* x = X + (i64)n * 3;
    float w0 = W0[j * 3 + 0], w1 = W0[j * 3 + 1], w2 = W0[j * 3 + 2];
    float s = x[0] * w0 + x[1] * w1 + x[2] * w2 + b0[j];
    float t = tanhf(s);
    t0c[e] = t;
    if (FULL) {
        float phi = 1.f - t * t;
        float u = -2.f * t * phi;
        float Q0 = w0 * w0 + w1 * w1 + w2 * w2;
        l1c[e] = u * Q0;
        i64 base = ((i64)n * 3) * H + j;
        g1c[base] = phi * w0;
        g1c[base + H] = phi * w1;
        g1c[base + 2 * H] = phi * w2;
    }
}

// fused lapfin + bwd_mid: per-row block; q kept in regs
__global__ __launch_bounds__(256) void lapbwd_k(
    const float* __restrict__ t1c, const float* __restrict__ ls1c,
    float* __restrict__ gs1c, const float* __restrict__ W2,
    const float* __restrict__ X, float invN,
    float* __restrict__ l2c, float* __restrict__ f1c, float* __restrict__ d1c,
    float* __restrict__ ri_out)
{
    __shared__ float red[4];
    __shared__ float riS;
    int n = blockIdx.x;
    int tid = threadIdx.x;
    float tv[2], phiv[2], uv[2], qv[2], lsv[2], g0v[2], g1v[2], g2v[2], w2v[2];
    float part = 0.f;
#pragma unroll
    for (int h = 0; h < 2; h++) {
        int m = tid + h * 256;
        i64 e = (i64)n * H + m;
        i64 b = ((i64)n * 3) * H + m;
        float g0 = gs1c[b], g1 = gs1c[b + H], g2 = gs1c[b + 2 * H];
        float q = g0 * g0 + g1 * g1 + g2 * g2;
        float t = t1c[e], phi = 1.f - t * t, u = -2.f * t * phi;
        float ls = ls1c[e];
        float l2 = phi * ls + u * q;
        l2c[e] = l2;
        part += l2 * W2[m];
        tv[h] = t; phiv[h] = phi; uv[h] = u; qv[h] = q; lsv[h] = ls;
        g0v[h] = g0; g1v[h] = g1; g2v[h] = g2; w2v[h] = W2[m];
    }
    for (int off = 32; off; off >>= 1) part += __shfl_down(part, off, 64);
    if ((tid & 63) == 0) red[tid >> 6] = part;
    __syncthreads();
    if (tid == 0) {
        float p = red[0] + red[1] + red[2] + red[3];
        const float* x = X + (i64)n * 3;
        float r = p - (sinf(x[0]) + sinf(x[1]) + sinf(x[2]));
        ri_out[n] = r;
        riS = r;
    }
    __syncthreads();
    float ri = riS;
#pragma unroll
    for (int h = 0; h < 2; h++) {
        int m = tid + h * 256;
        i64 e = (i64)n * H + m;
        i64 b = ((i64)n * 3) * H + m;
        float t = tv[h], phi = phiv[h], u = uv[h];
        float bl2 = ri * invN * w2v[h];
        f1c[e] = bl2 * (u * lsv[h] + (6.f * t * t - 2.f) * phi * qv[h]);
        d1c[e] = phi * bl2;
        float sc = 2.f * u * bl2;
        gs1c[b] = g0v[h] * sc; gs1c[b + H] = g1v[h] * sc; gs1c[b + 2 * H] = g2v[h] * sc;
    }
}

__global__ __launch_bounds__(256) void bnd_fin_k(
    const float* __restrict__ tb1, const float* __restrict__ W2,
    const float* __restrict__ b2, const float* __restrict__ X, int rows,
    float* __restrict__ rb_out)
{
    int wave = threadIdx.x >> 6, lane = threadIdx.x & 63;
    int n = blockIdx.x * 4 + wave;
    if (n >= rows) return;
    float p = 0.f;
    for (int m = lane; m < H; m += 64) p += tb1[(i64)n * H + m] * W2[m];
    for (int off = 32; off; off >>= 1) p += __shfl_down(p, off, 64);
    if (lane == 0) {
        const float* x = X + (i64)n * 3;
        rb_out[n] = p + b2[0] - (cosf(x[0]) + cosf(x[1]) + cosf(x[2]));
    }
}

// weighted column-sum jobs
struct WJ { const float* src[3]; const float* wgt[3]; float scale[3]; float* dst[3]; };
__global__ void wcolp_k(WJ wj, int rows, float* __restrict__ part)
{
    int m = blockIdx.x * 256 + threadIdx.x;
    int g = blockIdx.y, z = blockIdx.z;
    if (m >= H) return;
    const float* src = wj.src[z]; const float* w = wj.wgt[z];
    int per = (rows + 15) / 16;
    int n0 = g * per, n1 = imin(rows, n0 + per);
    float s = 0.f;
    for (int n = n0; n < n1; n++) {
        float ww = w ? w[n] : 1.f;
        s += ww * src[(i64)n * H + m];
    }
    part[(i64)(z * 16 + g) * H + m] = s;
}
__global__ void wcolr_k(WJ wj, const float* __restrict__ part)
{
    int m = blockIdx.x * 256 + threadIdx.x;
    int z = blockIdx.y;
    if (m >= H) return;
    float s = 0.f;
#pragma unroll
    for (int g = 0; g < 16; g++) s += part[(i64)(z * 16 + g) * H + m];
    wj.dst[z][m] += wj.scale[z] * s;
}

__global__ void dualred_k(const float* __restrict__ ri, const float* __restrict__ rb,
                          float* S_B2, float* gb2v, float* S_B2b)
{
    __shared__ float s1[256], s2[256];
    int z = blockIdx.x;
    const float* r = z ? rb : ri;
    int n = z ? NB : NI;
    float a = 0.f, b = 0.f;
    for (int i = threadIdx.x; i < n; i += 256) { float v = r[i]; a += v; b += v * v; }
    s1[threadIdx.x] = a; s2[threadIdx.x] = b; __syncthreads();
    for (int off = 128; off; off >>= 1) {
        if (threadIdx.x < off) { s1[threadIdx.x] += s1[threadIdx.x + off]; s2[threadIdx.x] += s2[threadIdx.x + off]; }
        __syncthreads();
    }
    if (threadIdx.x == 0) {
        float invN = 1.f / n;
        if (z == 0) { S_B2[0] += invN * invN * s2[0]; }
        else { gb2v[0] += invN * s1[0]; S_B2b[0] += invN * invN * s2[0]; }
    }
}

__global__ __launch_bounds__(256) void delta1_k(
    const float* __restrict__ t1c, const float* __restrict__ r,
    const float* __restrict__ W2, float invN, float* __restrict__ d1c, int rows)
{
    int e = blockIdx.x * 256 + threadIdx.x;
    if (e >= rows * H) return;
    int n = e >> 9, m = e & 511;
    float t = t1c[e];
    d1c[e] = (1.f - t * t) * (r[n] * invN) * W2[m];
}

__global__ void bwd0p_k(const float* __restrict__ X, int rows,
                        const float* __restrict__ W0,
                        const float* __restrict__ t0c, const float* __restrict__ bt0,
                        const float* __restrict__ bl1, const float* __restrict__ bg1,
                        float* __restrict__ part)
{
    int j = blockIdx.x * 256 + threadIdx.x;
    int g = blockIdx.y;
    if (j >= H) return;
    int per = (rows + 7) / 8;
    int n0 = g * per, n1 = imin(rows, n0 + per);
    float w0 = W0[j * 3], w1 = W0[j * 3 + 1], w2 = W0[j * 3 + 2];
    float Q0 = w0 * w0 + w1 * w1 + w2 * w2;
    float sW0 = 0, sW1 = 0, sW2 = 0, sUB = 0, sb = 0;
    for (int n = n0; n < n1; n++) {
        i64 e = (i64)n * H + j;
        float t = t0c[e], phi = 1.f - t * t, u = -2.f * t * phi;
        float bt = bt0[e], bl = bl1[e];
        i64 gb = ((i64)n * 3) * H + j;
        float g0 = bg1[gb], g1 = bg1[gb + H], g2 = bg1[gb + 2 * H];
        float bs = bt * phi + bl * (6.f * t * t - 2.f) * phi * Q0
                 + u * (g0 * w0 + g1 * w1 + g2 * w2);
        const float* x = X + (i64)n * 3;
        sW0 += bs * x[0] + phi * g0;
        sW1 += bs * x[1] + phi * g1;
        sW2 += bs * x[2] + phi * g2;
        sUB += u * bl;
        sb += bs;
    }
    float* pg = part + (i64)g * 2048;
    pg[j * 3 + 0] = sW0 + 2.f * w0 * sUB;
    pg[j * 3 + 1] = sW1 + 2.f * w1 * sUB;
    pg[j * 3 + 2] = sW2 + 2.f * w2 * sUB;
    pg[1536 + j] = sb;
}
__global__ void bwd0red_k(const float* __restrict__ part, float* __restrict__ gW0,
                          float* __restrict__ gb0)
{
    int e = blockIdx.x * 256 + threadIdx.x;
    if (e >= 2048) return;
    float s = 0.f;
#pragma unroll
    for (int g = 0; g < 8; g++) s += part[(i64)g * 2048 + e];
    if (e < 1536) gW0[e] += s;
    else gb0[e - 1536] += s;
}

__global__ __launch_bounds__(256) void xtx3b_k(const float* __restrict__ Xi,
                                               const float* __restrict__ Xb,
                                               float* __restrict__ S_A0,
                                               float* __restrict__ S_Ab0)
{
    __shared__ float red[256];
    int z = blockIdx.x;
    const float* X = z ? Xb : Xi;
    int rows = z ? NB : NI;
    float* dst = z ? S_Ab0 : S_A0;
    float s[9] = {};
    for (int n = threadIdx.x; n < rows; n += 256) {
        float x0 = X[(i64)n * 3], x1 = X[(i64)n * 3 + 1], x2 = X[(i64)n * 3 + 2];
        s[0] += x0 * x0; s[1] += x0 * x1; s[2] += x0 * x2;
        s[3] += x1 * x0; s[4] += x1 * x1; s[5] += x1 * x2;
        s[6] += x2 * x0; s[7] += x2 * x1; s[8] += x2 * x2;
    }
    for (int c = 0; c < 9; c++) {
        red[threadIdx.x] = s[c]; __syncthreads();
        for (int off = 128; off; off >>= 1) {
            if (threadIdx.x < off) red[threadIdx.x] += red[threadIdx.x + off];
            __syncthreads();
        }
        if (threadIdx.x == 0) dst[c] += red[0];
        __syncthreads();
    }
}

struct P8 { const float* p[8]; };
__global__ void fbuildb_k(P8 mom, const float* __restrict__ S, float* __restrict__ dst)
{
    int e = blockIdx.x * 256 + threadIdx.x;
    int z = blockIdx.y;
    if (e >= HH) return;
    float invN = (z < 4) ? (1.f / NI) : (1.f / NB);
    float v = DEC * mom.p[z][e] + (1.f - DEC) * invN * S[(i64)z * HH + e];
    if ((e >> 9) == (e & 511)) v += DAMP;
    dst[(i64)z * HH + e] = v;
}
__global__ void identv_k(float* V, i64 count) {
    i64 e = (i64)blockIdx.x * 256 + threadIdx.x;
    if (e >= count) return;
    i64 o = e % HH;
    V[e] = ((o >> 9) == (o & 511)) ? 1.f : 0.f;
}

// ======================= block Jacobi eigensolver =======================
__device__ __forceinline__ int pos7(int k, int r) { return k == 0 ? 0 : 1 + ((k - 1 + r) % 7); }
__device__ __forceinline__ int pos127s(int k, int s) {
    if (k == 0) return 0;
    int v = k - 1 + s;
    return 1 + (v < 127 ? v : v - 127);
}
__device__ __forceinline__ int gidx(int a, int gA, int gB) {
    return (a < 64) ? gA * 64 + a : gB * 64 + (a - 64);
}

// 128x128 subproblem (round-6 v3): 1024 threads, incremental pair tracking,
// fused 2x2 transform, 1 barrier/step. Logs (c,s,p,q); reads A only.
__global__ __launch_bounds__(1024) void eig_sub_k(const float* __restrict__ Abase,
                                                  float* __restrict__ rlog, int r)
{
    __shared__ float Sa[128][129];
    __shared__ float Sb[128][129];
    int pr = blockIdx.x, mat = blockIdx.y;
    int gA = pos7(pr, r), gB = pos7(7 - pr, r);
    int tid = threadIdx.x, lane = tid & 63, wv = tid >> 6;  // wv 0..15
    const float* A = Abase + (i64)mat * HH;
    float4* lg = ((float4*)rlog) + (i64)(mat * 4 + pr) * (STEPS * 64);
    for (int e = tid; e < 128 * 128; e += 1024) {
        int a = e >> 7, b = e & 127;
        Sa[a][b] = A[(i64)gidx(a, gA, gB) * H + gidx(b, gA, gB)];
    }
    int pa = pos127s(lane, 0), qa = pos127s(127 - lane, 0);
    int pb[4], qb[4];
    bool pbz[4];
#pragma unroll
    for (int it = 0; it < 4; it++) {
        int bj = wv * 4 + it;
        pb[it] = pos127s(bj, 0);
        qb[it] = pos127s(127 - bj, 0);
        pbz[it] = (bj == 0);
    }
    bool paz = (lane == 0);
    __syncthreads();
    for (int gst = 0; gst < STEPS; ++gst) {
        float (*Scur)[129] = (gst & 1) ? Sb : Sa;
        float (*Snew)[129] = (gst & 1) ? Sa : Sb;
        float app = Scur[pa][pa], aqq = Scur[qa][qa], apq = Scur[pa][qa];
        float c = 1.f, s = 0.f;
        if (fabsf(apq) > 1e-30f) {
            float tau = (aqq - app) / (2.f * apq);
            float t = copysignf(1.f, tau) / (fabsf(tau) + sqrtf(1.f + tau * tau));
            c = 1.f / sqrtf(1.f + t * t); s = t * c;
        }
        if (tid < 64) lg[(i64)gst * 64 + lane] =
            make_float4(c, s, __int_as_float(pa), __int_as_float(qa));
        const float* rowp = &Scur[pa][0];
        const float* rowq = &Scur[qa][0];
        float* nrowp = &Snew[pa][0];
        float* nrowq = &Snew[qa][0];
#pragma unroll
        for (int it = 0; it < 4; it++) {
            int cb = pb[it], db = qb[it];
            float cj = __shfl(c, wv * 4 + it, 64);
            float sj = __shfl(s, wv * 4 + it, 64);
            float m00 = rowp[cb], m01 = rowp[db];
            float m10 = rowq[cb], m11 = rowq[db];
            float t0 = c * m00 - s * m10;
            float t1 = c * m01 - s * m11;
            float t2 = s * m00 + c * m10;
            float t3 = s * m01 + c * m11;
            nrowp[cb] = cj * t0 - sj * t1;
            nrowp[db] = sj * t0 + cj * t1;
            nrowq[cb] = cj * t2 - sj * t3;
            nrowq[db] = sj * t2 + cj * t3;
        }
        pa = paz ? 0 : (pa == 127 ? 1 : pa + 1);
        qa = (qa == 127 ? 1 : qa + 1);
#pragma unroll
        for (int it = 0; it < 4; it++) {
            pb[it] = pbz[it] ? 0 : (pb[it] == 127 ? 1 : pb[it] + 1);
            qb[it] = (qb[it] == 127 ? 1 : qb[it] + 1);
        }
        __syncthreads();
    }
}

__global__ __launch_bounds__(256) void ubuild_k(const float* __restrict__ rlog,
                                                float* __restrict__ Ubuf)
{
    __shared__ float U[16][132];
    __shared__ float4 lb[2][64];
    int sl = blockIdx.x, mp = blockIdx.y;
    int tid = threadIdx.x;
    const float4* lg = ((const float4*)rlog) + (i64)mp * (STEPS * 64);
    int ro0 = sl * 16;
    for (int e = tid; e < 16 * 128; e += 256) {
        int rr = e >> 7, cc = e & 127;
        U[rr][cc] = (ro0 + rr == cc) ? 1.f : 0.f;
    }
    if (tid < 64) lb[0][tid] = lg[tid];
    __syncthreads();
    for (int st = 0; st < STEPS; st++) {
        float4 e4 = lb[st & 1][tid & 63];
        if (tid < 64 && st + 1 < STEPS) lb[(st + 1) & 1][tid] = lg[(i64)(st + 1) * 64 + tid];
        float c = e4.x, s = e4.y;
        int p = __float_as_int(e4.z), q = __float_as_int(e4.w);
        int rch = tid >> 6;
#pragma unroll
        for (int j = 0; j < 4; j++) {
            int rr = rch * 4 + j;
            float x = U[rr][p], y = U[rr][q];
            U[rr][p] = c * x - s * y; U[rr][q] = s * x + c * y;
        }
        __syncthreads();
    }
    float* Uo = Ubuf + (i64)mp * 16384;
    for (int e = tid; e < 16 * 128; e += 256) Uo[(i64)ro0 * 128 + e] = U[e >> 7][e & 127];
}

// etA: z<256: Tbuf[region] = A_region rows @ UJ ; z>=256: V rows (in-place) @ U_pr
__global__ __launch_bounds__(256) void etA_k(const float* __restrict__ Abase,
                                             float* __restrict__ Vbase,
                                             const float* __restrict__ Ubuf,
                                             float* __restrict__ Tbuf, int r)
{
    __shared__ float As[64][132];
    __shared__ float Bs[32][132];
    int z = blockIdx.x, tid = threadIdx.x;
    int tx = tid & 15, ty = tid >> 4;
    bool vpath = (z >= 256);
    const float* srcA; const float* Bsrc;
    float* dstT = nullptr; float* Vw = nullptr;
    int rowbase, gAj, gBj;
    if (!vpath) {
        int region = z >> 1, rt = z & 1;
        int mat = region >> 4, pp = region & 15, pri = pp >> 2, prj = pp & 3;
        int gAi = pos7(pri, r), gBi = pos7(7 - pri, r);
        gAj = pos7(prj, r); gBj = pos7(7 - prj, r);
        rowbase = (rt ? gBi : gAi) * 64;
        srcA = Abase + (i64)mat * HH;
        Bsrc = Ubuf + (i64)(mat * 4 + prj) * 16384;
        dstT = Tbuf + (i64)region * 16384 + (i64)(rt * 64) * 128;
    } else {
        int vz = z - 256;
        int mat = vz >> 5, rest = vz & 31, pp2 = rest >> 3, tm = rest & 7;
        gAj = pos7(pp2, r); gBj = pos7(7 - pp2, r);
        rowbase = tm * 64;
        Vw = Vbase + (i64)mat * HH;
        srcA = Vw;
        Bsrc = Ubuf + (i64)(mat * 4 + pp2) * 16384;
    }
    for (int e = tid; e < 64 * 32; e += 256) {
        int i = e >> 5, k4 = (e & 31) * 4;
        int col = gidx(k4, gAj, gBj);
        *(float4*)&As[i][k4] = *(const float4*)&srcA[(i64)(rowbase + i) * H + col];
    }
    float acc[4][8] = {};
    __syncthreads();
    for (int k0 = 0; k0 < 128; k0 += 32) {
        for (int e = tid; e < 32 * 32; e += 256) {
            int ka = e >> 5, j4 = (e & 31) * 4;
            *(float4*)&Bs[ka][j4] = *(const float4*)&Bsrc[(i64)(k0 + ka) * 128 + j4];
        }
        __syncthreads();
#pragma unroll 4
        for (int kk = 0; kk < 32; kk++) {
            int k = k0 + kk;
            float av[4];
#pragma unroll
            for (int i = 0; i < 4; i++) av[i] = As[ty * 4 + i][k];
            float4 b0 = *(const float4*)&Bs[kk][tx * 8];
            float4 b1 = *(const float4*)&Bs[kk][tx * 8 + 4];
            float bv[8] = {b0.x, b0.y, b0.z, b0.w, b1.x, b1.y, b1.z, b1.w};
#pragma unroll
            for (int i = 0; i < 4; i++)
#pragma unroll
                for (int j = 0; j < 8; j++) acc[i][j] += av[i] * bv[j];
        }
        __syncthreads();
    }
    if (!vpath) {
#pragma unroll
        for (int i = 0; i < 4; i++) {
            int row = ty * 4 + i;
            float4 v0 = {acc[i][0], acc[i][1], acc[i][2], acc[i][3]};
            float4 v1 = {acc[i][4], acc[i][5], acc[i][6], acc[i][7]};
            *(float4*)&dstT[(i64)row * 128 + tx * 8] = v0;
            *(float4*)&dstT[(i64)row * 128 + tx * 8 + 4] = v1;
        }
    } else {
        int colbase = gidx(tx * 8, gAj, gBj);
#pragma unroll
        for (int i = 0; i < 4; i++) {
            int row = rowbase + ty * 4 + i;
            float4 v0 = {acc[i][0], acc[i][1], acc[i][2], acc[i][3]};
            float4 v1 = {acc[i][4], acc[i][5], acc[i][6], acc[i][7]};
            *(float4*)&Vw[(i64)row * H + colbase] = v0;
            *(float4*)&Vw[(i64)row * H + colbase + 4] = v1;
        }
    }
}

// etB: A_region = UI^T @ Tbuf[region]
__global__ __launch_bounds__(256) void etB_k(float* __restrict__ Abase,
                                             const float* __restrict__ Ubuf,
                                             const float* __restrict__ Tbuf, int r)
{
    __shared__ float As[32][68];
    __shared__ float Bs[32][132];
    int z = blockIdx.x, tid = threadIdx.x;
    int tx = tid & 15, ty = tid >> 4;
    int region = z >> 1, rt = z & 1;
    int mat = region >> 4, pp = region & 15, pri = pp >> 2, prj = pp & 3;
    int gAi = pos7(pri, r), gBi = pos7(7 - pri, r);
    int gAj = pos7(prj, r), gBj = pos7(7 - prj, r);
    const float* UI = Ubuf + (i64)(mat * 4 + pri) * 16384;
    const float* T = Tbuf + (i64)region * 16384;
    float* A = Abase + (i64)mat * HH;
    int outrowbase = (rt ? gBi : gAi) * 64;
    float acc[4][8] = {};
    for (int k0 = 0; k0 < 128; k0 += 32) {
        __syncthreads();
        for (int e = tid; e < 32 * 16; e += 256) {
            int ka = e >> 4, i4 = (e & 15) * 4;
            *(float4*)&As[ka][i4] = *(const float4*)&UI[(i64)(k0 + ka) * 128 + rt * 64 + i4];
        }
        for (int e = tid; e < 32 * 32; e += 256) {
            int ka = e >> 5, j4 = (e & 31) * 4;
            *(float4*)&Bs[ka][j4] = *(const float4*)&T[(i64)(k0 + ka) * 128 + j4];
        }
        __syncthreads();
#pragma unroll 4
        for (int kk = 0; kk < 32; kk++) {
            float4 a = *(const float4*)&As[kk][ty * 4];
            float av[4] = {a.x, a.y, a.z, a.w};
            float4 b0 = *(const float4*)&Bs[kk][tx * 8];
            float4 b1 = *(const float4*)&Bs[kk][tx * 8 + 4];
            float bv[8] = {b0.x, b0.y, b0.z, b0.w, b1.x, b1.y, b1.z, b1.w};
#pragma unroll
            for (int i = 0; i < 4; i++)
#pragma unroll
                for (int j = 0; j < 8; j++) acc[i][j] += av[i] * bv[j];
        }
    }
    int colbase = gidx(tx * 8, gAj, gBj);
#pragma unroll
    for (int i = 0; i < 4; i++) {
        int row = outrowbase + ty * 4 + i;
        float4 v0 = {acc[i][0], acc[i][1], acc[i][2], acc[i][3]};
        float4 v1 = {acc[i][4], acc[i][5], acc[i][6], acc[i][7]};
        *(float4*)&A[(i64)row * H + colbase] = v0;
        *(float4*)&A[(i64)row * H + colbase + 4] = v1;
    }
}

__global__ __launch_bounds__(512) void sort_k(const float* __restrict__ Afin,
                                              float* __restrict__ evals, int* __restrict__ rankbuf)
{
    __shared__ float d[512];
    int mat = blockIdx.x, i = threadIdx.x;
    float li = Afin[(i64)mat * HH + (i64)i * H + i];
    d[i] = li; __syncthreads();
    int cnt = 0;
    for (int j = 0; j < 512; j++) { float lj = d[j]; cnt += (lj < li) || (lj == li && j < i); }
    evals[mat * H + cnt] = li;
    if (mat < 4) rankbuf[mat * H + i] = cnt;
}
__global__ void perm_k(const float* __restrict__ Vfin, const int* __restrict__ rankbuf,
                       float* __restrict__ Vs)
{
    i64 e = (i64)blockIdx.x * 256 + threadIdx.x;
    if (e >= (i64)4 * HH) return;
    int mat = (int)(e / HH); i64 o = e % HH;
    int rrow = (int)(o >> 9), i = (int)(o & 511);
    Vs[(i64)mat * HH + (i64)rrow * H + rankbuf[mat * H + i]] = Vfin[e];
}

// ======================= small (3x3, 1x1) eigens =======================
__device__ void jacobi3(float A[3][3], float V[3][3], bool wantV) {
    if (wantV) for (int r = 0; r < 3; r++) for (int c = 0; c < 3; c++) V[r][c] = (r == c) ? 1.f : 0.f;
    const int PP[3] = {0, 0, 1}, QQ[3] = {1, 2, 2};
    for (int sw = 0; sw < 30; sw++)
        for (int e = 0; e < 3; e++) {
            int p = PP[e], q = QQ[e];
            float apq = A[p][q];
            if (fabsf(apq) < 1e-30f) continue;
            float tau = (A[q][q] - A[p][p]) / (2.f * apq);
            float t = copysignf(1.f, tau) / (fabsf(tau) + sqrtf(1.f + tau * tau));
            float c = 1.f / sqrtf(1.f + t * t), s = t * c;
            for (int k = 0; k < 3; k++) { float x = A[p][k], y = A[q][k]; A[p][k] = c * x - s * y; A[q][k] = s * x + c * y; }
            for (int k = 0; k < 3; k++) { float x = A[k][p], y = A[k][q]; A[k][p] = c * x - s * y; A[k][q] = s * x + c * y; }
            if (wantV) for (int k = 0; k < 3; k++) { float x = V[k][p], y = V[k][q]; V[k][p] = c * x - s * y; V[k][q] = s * x + c * y; }
        }
}

__global__ void small_eig_k(const float* Aom0, const float* S_A0,
                            const float* Abd0, const float* S_Ab0,
                            const float* Bom2, const float* S_B2,
                            const float* Bbd2, const float* S_B2b,
                            float* UA0, float* eA0, float* eAb0, float* eScal)
{
    if (threadIdx.x || blockIdx.x) return;
    float A[3][3], V[3][3];
    for (int r = 0; r < 3; r++) for (int c = 0; c < 3; c++) {
        A[r][c] = DEC * Aom0[r * 3 + c] + (1.f - DEC) * S_A0[r * 3 + c] / (float)NI;
        if (r == c) A[r][c] += DAMP;
    }
    jacobi3(A, V, true);
    int ord[3] = {0, 1, 2};
    for (int i = 0; i < 2; i++) for (int j = 0; j < 2 - i; j++)
        if (A[ord[j]][ord[j]] > A[ord[j + 1]][ord[j + 1]]) { int t = ord[j]; ord[j] = ord[j + 1]; ord[j + 1] = t; }
    for (int k = 0; k < 3; k++) { eA0[k] = A[ord[k]][ord[k]]; for (int r = 0; r < 3; r++) UA0[r * 3 + k] = V[r][ord[k]]; }

    for (int r = 0; r < 3; r++) for (int c = 0; c < 3; c++) {
        A[r][c] = DEC * Abd0[r * 3 + c] + (1.f - DEC) * S_Ab0[r * 3 + c] / (float)NB;
        if (r == c) A[r][c] += DAMP;
    }
    jacobi3(A, V, false);
    int ord2[3] = {0, 1, 2};
    for (int i = 0; i < 2; i++) for (int j = 0; j < 2 - i; j++)
        if (A[ord2[j]][ord2[j]] > A[ord2[j + 1]][ord2[j + 1]]) { int t = ord2[j]; ord2[j] = ord2[j + 1]; ord2[j + 1] = t; }
    for (int k = 0; k < 3; k++) eAb0[k] = A[ord2[k]][ord2[k]];

    eScal[0] = DEC * Bom2[0] + (1.f - DEC) * S_B2[0] / (float)NI + DAMP;
    eScal[1] = DEC * Bbd2[0] + (1.f - DEC) * S_B2b[0] / (float)NB + DAMP;
}

// ======================= preconditioning =======================
__global__ void div2_k(float* P, const float* eG, const float* eA,
                       const float* eGb, const float* eAb, int Mg, int Na)
{
    int e = blockIdx.x * 256 + threadIdx.x;
    if (e >= Mg * Na) return;
    int a = e / Na, b = e % Na;
    P[e] /= (eG[a] * eA[b] + eGb[a] * eAb[b]);
}
__global__ void div1_k(float* v, const float* eG, const float* eGb, int Mg)
{
    int e = blockIdx.x * 256 + threadIdx.x;
    if (e >= Mg) return;
    v[e] /= (eG[e] + eGb[e]);
}
__global__ void div2s_k(float* P, const float* eScal, const float* eA, const float* eAb, int Na)
{
    int e = blockIdx.x * 256 + threadIdx.x;
    if (e >= Na) return;
    P[e] /= (eScal[0] * eA[e] + eScal[1] * eAb[e]);
}
__global__ void scal2_k(const float* g, const float* eScal, float* out)
{
    if (threadIdx.x || blockIdx.x) return;
    out[0] = g[0] / (eScal[0] + eScal[1]);
}

// ======================= params concat helpers =======================
__device__ __forceinline__ float pick6(int e, const float* W0, const float* W1, const float* W2,
                                       const float* b0, const float* b1, const float* b2)
{
    if (e < OFF_W1) return W0[e];
    if (e < OFF_W2) return W1[e - OFF_W1];
    if (e < OFF_B0) return W2[e - OFF_W2];
    if (e < OFF_B1) return b0[e - OFF_B0];
    if (e < OFF_B2) return b1[e - OFF_B1];
    return b2[0];
}
__global__ void mom_k(const float* mw0, const float* mw1, const float* mw2,
                      const float* mb0, const float* mb1, const float* mb2,
                      const float* __restrict__ pcat, float* __restrict__ mcat)
{
    int e = blockIdx.x * 256 + threadIdx.x;
    if (e >= TOT) return;
    mcat[e] = 0.9f * pick6(e, mw0, mw1, mw2, mb0, mb1, mb2) + pcat[e];
}
__global__ void upd_k(const float* W0, const float* W1, const float* W2,
                      const float* b0, const float* b1, const float* b2,
                      const float* __restrict__ mcat, float alpha, const float* alphap,
                      float* __restrict__ out)
{
    int e = blockIdx.x * 256 + threadIdx.x;
    if (e >= TOT) return;
    float a = alphap ? alphap[0] : alpha;
    out[e] = pick6(e, W0, W1, W2, b0, b1, b2) - a * mcat[e];
}
__global__ void argmin_k(const float* lossI, const float* lossB, float* bestA)
{
    if (threadIdx.x || blockIdx.x) return;
    float best = 3.4e38f, ba = 0.01f;
    for (int k = 0; k < 5; k++) {
        float l = 0.5f * (lossI[k] / (float)NI) + 0.5f * (lossB[k] / (float)NB);
        float al = 0.01f * (1.0f / (float)(1 << k));
        if (l < best) { best = l; ba = al; }
    }
    bestA[0] = ba;
}

// ============ line-search mega kernel v2: fused t0, z = alpha ============
template<int LAP>
__global__ __launch_bounds__(256) void lsf2_k(
    const float* __restrict__ X,
    const float* __restrict__ W0, const float* __restrict__ b0,
    const float* __restrict__ W1, const float* __restrict__ b1,
    const float* __restrict__ W2, const float* __restrict__ b2,
    const float* __restrict__ mcat, int nrows, float* __restrict__ part)
{
    __shared__ float As[32][68];
    __shared__ float Bs[32][68];
    __shared__ float wq[32][8];
    __shared__ float Xs[64][4];
    __shared__ float red[64][17];
    int tid = threadIdx.x, tx = tid & 15, ty = tid >> 4;
    int n0 = blockIdx.x * 64, m0 = blockIdx.y * 64;
    float al = 0.01f * (1.0f / (float)(1 << blockIdx.z));
    if (tid < 192) { int n = tid / 3, d = tid - n * 3; Xs[n][d] = X[(i64)(n0 + n) * 3 + d]; }
    float a_t[4][4] = {}, a_g0[4][4] = {}, a_g1[4][4] = {}, a_g2[4][4] = {}, a_l[4][4] = {};
    __syncthreads();
    for (int k0 = 0; k0 < 512; k0 += 32) {
        {   // stage candidate W1 tile
            int n = tid >> 2, kq = (tid & 3) * 4;
            const float* p = &W1[(i64)(m0 + n) * 512 + k0 + kq];
            const float* pm = &mcat[OFF_W1 + (i64)(m0 + n) * 512 + k0 + kq];
            float4 v0 = *(const float4*)p, v1 = *(const float4*)(p + 16);
            float4 m0v = *(const float4*)pm, m1v = *(const float4*)(pm + 16);
            Bs[kq + 0][n] = v0.x - al * m0v.x; Bs[kq + 1][n] = v0.y - al * m0v.y;
            Bs[kq + 2][n] = v0.z - al * m0v.z; Bs[kq + 3][n] = v0.w - al * m0v.w;
            Bs[kq + 16][n] = v1.x - al * m1v.x; Bs[kq + 17][n] = v1.y - al * m1v.y;
            Bs[kq + 18][n] = v1.z - al * m1v.z; Bs[kq + 19][n] = v1.w - al * m1v.w;
        }
        if (tid < 32) {   // stage candidate layer-0 params
            int j = k0 + tid;
            float w0 = W0[j * 3]     - al * mcat[j * 3];
            float w1 = W0[j * 3 + 1] - al * mcat[j * 3 + 1];
            float w2 = W0[j * 3 + 2] - al * mcat[j * 3 + 2];
            float bb = b0[j] - al * mcat[OFF_B0 + j];
            wq[tid][0] = w0; wq[tid][1] = w1; wq[tid][2] = w2; wq[tid][3] = bb;
            wq[tid][4] = w0 * w0 + w1 * w1 + w2 * w2;
        }
        __syncthreads();
        {   // compute t0 on the fly into As
            int n = tid >> 2, a = tid & 3;
            float x0 = Xs[n][0], x1 = Xs[n][1], x2 = Xs[n][2];
#pragma unroll
            for (int i = 0; i < 8; i++) {
                int k = a + 4 * i;
                float s = x0 * wq[k][0] + x1 * wq[k][1] + x2 * wq[k][2] + wq[k][3];
                As[k][n] = tanhf(s);
            }
        }
        __syncthreads();
#pragma unroll
        for (int ks = 0; ks < 32; ks++) {
            float4 a = *(const float4*)&As[ks][ty * 4];
            float4 b = *(const float4*)&Bs[ks][tx * 4];
            float av[4] = {a.x, a.y, a.z, a.w};
            float bv[4] = {b.x, b.y, b.z, b.w};
            if (LAP) {
                float w0 = wq[ks][0], w1 = wq[ks][1], w2 = wq[ks][2], q0 = wq[ks][4];
                float gv0[4], gv1[4], gv2[4], lv[4];
#pragma unroll
                for (int i = 0; i < 4; i++) {
                    float t = av[i], phi = 1.f - t * t, u = -2.f * t * phi;
                    gv0[i] = phi * w0; gv1[i] = phi * w1; gv2[i] = phi * w2; lv[i] = u * q0;
                }
#pragma unroll
                for (int i = 0; i < 4; i++)
#pragma unroll
                    for (int j = 0; j < 4; j++) {
                        a_t[i][j]  += av[i]  * bv[j];
                        a_g0[i][j] += gv0[i] * bv[j];
                        a_g1[i][j] += gv1[i] * bv[j];
                        a_g2[i][j] += gv2[i] * bv[j];
                        a_l[i][j]  += lv[i]  * bv[j];
                    }
            } else {
#pragma unroll
                for (int i = 0; i < 4; i++)
#pragma unroll
                    for (int j = 0; j < 4; j++) a_t[i][j] += av[i] * bv[j];
            }
        }
        __syncthreads();
    }
    float rowpart[4];
#pragma unroll
    for (int i = 0; i < 4; i++) {
        rowpart[i] = 0.f;
#pragma unroll
        for (int j = 0; j < 4; j++) {
            int m = m0 + tx * 4 + j;
            float s = a_t[i][j] + (b1[m] - al * mcat[OFF_B1 + m]);
            float t1 = tanhf(s);
            float val;
            if (LAP) {
                float phi = 1.f - t1 * t1, u = -2.f * t1 * phi;
                float q = a_g0[i][j] * a_g0[i][j] + a_g1[i][j] * a_g1[i][j] + a_g2[i][j] * a_g2[i][j];
                val = phi * a_l[i][j] + u * q;
            } else val = t1;
            rowpart[i] += val * (W2[m] - al * mcat[OFF_W2 + m]);
        }
    }
#pragma unroll
    for (int i = 0; i < 4; i++) red[ty * 4 + i][tx] = rowpart[i];
    __syncthreads();
    if (tid < 64) {
        float s = 0.f;
#pragma unroll
        for (int x = 0; x < 16; x++) s += red[tid][x];
        if (!LAP && blockIdx.y == 0) s += (b2[0] - al * mcat[OFF_B2]);
        part[((i64)blockIdx.z * 8 + blockIdx.y) * nrows + n0 + tid] = s;
    }
}

__global__ __launch_bounds__(256) void lsred_k(const float* __restrict__ pI,
                                               const float* __restrict__ pB,
                                               const float* __restrict__ Xi,
                                               const float* __restrict__ Xb,
                                               float* __restrict__ lossI,
                                               float* __restrict__ lossB)
{
    __shared__ float red[256];
    int z = blockIdx.x, a = z >> 1, isB = z & 1;
    int rows = isB ? NB : NI;
    const float* src = isB ? (pB + (i64)a * 8 * NB) : (pI + (i64)a * 8 * NI);
    const float* X = isB ? Xb : Xi;
    float acc = 0.f;
    for (int n = threadIdx.x; n < rows; n += 256) {
        float s = 0.f;
#pragma unroll
        for (int t = 0; t < 8; t++) s += src[(i64)t * rows + n];
        const float* x = X + (i64)n * 3;
        float rhs = isB ? (cosf(x[0]) + cosf(x[1]) + cosf(x[2]))
                        : (sinf(x[0]) + sinf(x[1]) + sinf(x[2]));
        float r = s - rhs;
        acc += r * r;
    }
    red[threadIdx.x] = acc; __syncthreads();
    for (int off = 128; off; off >>= 1) {
        if (threadIdx.x < off) red[threadIdx.x] += red[threadIdx.x + off];
        __syncthreads();
    }
    if (threadIdx.x == 0) {
        if (isB) lossB[a] = red[0];
        else lossI[a] = red[0];
    }
}

// ======================= host helpers =======================
template<int MODE>
static inline void g64(hipStream_t st, const float* A, const float* B, float* C,
                       int M, int N, int K) {
    dim3 g((M + 63) / 64, (N + 63) / 64);
    bool fast = (M % 64 == 0) && (N % 64 == 0) && (K % 32 == 0);
    if (fast) gemm64_k<MODE, 0, 0, 1, 0><<<g, 256, 0, st>>>(A, B, nullptr, C, M, N, K, nullptr, nullptr);
    else      gemm64_k<MODE, 0, 0, 0, 0><<<g, 256, 0, st>>>(A, B, nullptr, C, M, N, K, nullptr, nullptr);
}
static inline void g64_bt(hipStream_t st, const float* A, const float* B, const float* bias,
                          float* C, int M, int N, int K) {
    dim3 g((M + 63) / 64, (N + 63) / 64);
    gemm64_k<0, 1, 1, 1, 0><<<g, 256, 0, st>>>(A, B, bias, C, M, N, K, nullptr, nullptr);
}
static inline void g64_aux1(hipStream_t st, const float* A, const float* B, float* C,
                            int M, int N, int K, const float* t0p, float* dst2) {
    dim3 g((M + 63) / 64, (N + 63) / 64);
    gemm64_k<1, 0, 0, 1, 1><<<g, 256, 0, st>>>(A, B, nullptr, C, M, N, K, t0p, dst2);
}
static inline void g64_aux2(hipStream_t st, const float* A, const float* B, float* C,
                            int M, int N, int K, const float* t0p) {
    dim3 g((M + 63) / 64, (N + 63) / 64);
    gemm64_k<1, 0, 0, 1, 2><<<g, 256, 0, st>>>(A, B, nullptr, C, M, N, K, t0p, nullptr);
}
static inline void g_sk(hipStream_t st, const float* A, const float* B, float* dst,
                        int M, int N, int K, float* skbuf) {
    int Ks = ((K / 8) + 31) / 32 * 32;
    if (Ks * 8 < K) Ks += 32;
    dim3 g((M + 63) / 64, (N + 63) / 64, 8);
    bool fast = (M % 64 == 0) && (N % 64 == 0) && (K == Ks * 8);
    if (fast) gemm_tn_sk_k<1><<<g, 256, 0, st>>>(A, B, skbuf, M, N, K, Ks);
    else      gemm_tn_sk_k<0><<<g, 256, 0, st>>>(A, B, skbuf, M, N, K, Ks);
    int cnt = M * N;
    sk_red_k<<<(cnt + 255) / 256, 256, 0, st>>>(dst, skbuf, cnt);
}

extern "C" void kernel_launch(void* const* d_in, const int* in_sizes, int n_in,
                              void* d_out, int out_size, void* d_ws, size_t ws_size,
                              hipStream_t stream)
{
    const float* Xi   = (const float*)d_in[0];
    const float* Xb   = (const float*)d_in[1];
    const float* W0   = (const float*)d_in[2];
    const float* b0   = (const float*)d_in[3];
    const float* Aom0 = (const float*)d_in[4];
    const float* Bom0 = (const float*)d_in[5];
    const float* Abd0 = (const float*)d_in[6];
    const float* Bbd0 = (const float*)d_in[7];
    const float* mw0  = (const float*)d_in[8];
    const float* mb0  = (const float*)d_in[9];
    const float* W1   = (const float*)d_in[10];
    const float* b1   = (const float*)d_in[11];
    const float* Aom1 = (const float*)d_in[12];
    const float* Bom1 = (const float*)d_in[13];
    const float* Abd1 = (const float*)d_in[14];
    const float* Bbd1 = (const float*)d_in[15];
    const float* mw1  = (const float*)d_in[16];
    const float* mb1  = (const float*)d_in[17];
    const float* W2   = (const float*)d_in[18];
    const float* b2   = (const float*)d_in[19];
    const float* Aom2 = (const float*)d_in[20];
    const float* Bom2 = (const float*)d_in[21];
    const float* Abd2 = (const float*)d_in[22];
    const float* Bbd2 = (const float*)d_in[23];
    const float* mw2  = (const float*)d_in[24];
    const float* mb2  = (const float*)d_in[25];

    float* w = (float*)d_ws;
    i64 off = 0;
    auto alloc = [&](i64 n) { float* p = w + off; off += n; return p; };

    const i64 M1 = 1048576;
    float* arena = alloc(15 * M1);
    float* t0c = arena + 0 * M1;
    float* t1c = arena + 1 * M1;
    float* l1c = arena + 2 * M1;
    float* ls1c = arena + 3 * M1;
    float* l2c = arena + 5 * M1;
    float* d1c = arena + 6 * M1;
    float* e1c = arena + 7 * M1;
    float* f1c = arena + 8 * M1;
    float* g1c = arena + 9 * M1;
    float* gs1c = arena + 12 * M1;
    float* skbuf = arena + 4 * M1;
    // eigen views
    float* Aeig = arena + 0 * M1;              // 8*HH (slots 0-1)
    float* Veig = arena + 2 * M1;              // 4*HH (slot 2)
    float* Ubuf = arena + 3 * M1;              // 32*16384
    float* Vs   = arena + 3 * M1 + 524288;     // 4*HH
    float* rlog = arena + 5 * M1;              // 32*STEPS*64*4 floats (~3 M1, slots 5-7)
    float* Tbuf = arena + 8 * M1;              // 128*16384 (slots 8-9)
    // precond / LS views
    float* P1 = arena + 8 * M1;
    float* P2 = arena + 8 * M1 + HH;
    float* pI  = arena + 9 * M1;               // 5*8*NI
    float* pB  = arena + 10 * M1;              // 5*8*NB

    float* ri = alloc(NI);
    float* rb = alloc(NB);
    float* zero_base = w + off;
    float* S8   = alloc(8 * (i64)HH);
    float* S_A0 = alloc(9);
    float* S_Ab0 = alloc(9);
    float* S_B2 = alloc(1);
    float* S_B2b = alloc(1);
    float* gW0 = alloc(1536);
    float* gW1 = alloc(HH);
    float* gW2 = alloc(H);
    float* gb0v = alloc(H);
    float* gb1v = alloc(H);
    float* gb2v = alloc(1);
    float* lossI = alloc(5);
    float* lossB = alloc(5);
    i64 zero_count = (w + off) - zero_base;
    float* UA0 = alloc(9);
    float* eA0 = alloc(3);
    float* eAb0 = alloc(3);
    float* eScal = alloc(2);
    float* evals = alloc(4096);
    int*   ranks = (int*)alloc(2048);
    float* pcat = alloc(TOT);
    float* mcat = alloc(TOT);
    float* bestA = alloc(1);
    float* wpart = alloc(3 * 16 * H);
    float* b0part = alloc(8 * 2048);
    if (ws_size < (size_t)off * sizeof(float)) return;

    hipStream_t st = stream;
    zero_k<<<(int)((zero_count + 255) / 256), 256, 0, st>>>(zero_base, zero_count);

    const int EW = (CH * H + 255) / 256;

    // ---------------- interior chunks ----------------
    for (int c = 0; c < 4; c++) {
        const float* Xc = Xi + (i64)c * CH * 3;
        float* ric = ri + (i64)c * CH;
        fwd0_k<1><<<EW, 256, 0, st>>>(Xc, W0, b0, CH, t0c, g1c, l1c);
        g64_bt(st, t0c, W1, b1, t1c, CH, H, H);
        g64<0>(st, g1c, W1, gs1c, 3 * CH, H, H);
        g64<0>(st, l1c, W1, ls1c, CH, H, H);
        lapbwd_k<<<CH, 256, 0, st>>>(t1c, ls1c, gs1c, W2, Xc, 1.f / NI, l2c, f1c, d1c, ric);
        g64_aux1(st, d1c, W1, ls1c, CH, H, H, t0c, e1c);        // bar_l1 + delta0
        {
            WJ wj = {};
            wj.src[0] = l2c; wj.wgt[0] = ric; wj.scale[0] = 1.f / NI; wj.dst[0] = gW2;
            wj.src[1] = f1c; wj.wgt[1] = nullptr; wj.scale[1] = 1.f; wj.dst[1] = gb1v;
            wcolp_k<<<dim3(2, 16, 2), 256, 0, st>>>(wj, CH, wpart);
            wcolr_k<<<dim3(2, 2), 256, 0, st>>>(wj, wpart);
        }
        {   // batched Gram: Bo1, Bo0, Ao1, Ao2
            SkBatch sb = {};
            sb.A[0] = d1c; sb.B[0] = d1c;
            sb.A[1] = e1c; sb.B[1] = e1c;
            sb.A[2] = t0c; sb.B[2] = t0c;
            sb.A[3] = t1c; sb.B[3] = t1c;
            sb.Ks = 1024;
            for (int z = 0; z < 8; z++) { sb.job_of_z[z] = z >> 1; sb.kb_of_z[z] = (z & 1) * 1024; }
            skb_k<<<dim3(8, 8, 8), 256, 0, st>>>(sb, skbuf);
            RedJ rj = {};
            rj.dst[0] = S8 + 2 * (i64)HH; rj.dst[1] = S8 + 0 * (i64)HH;
            rj.dst[2] = S8 + 1 * (i64)HH; rj.dst[3] = S8 + 3 * (i64)HH;
            rj.off[0] = 0; rj.off[1] = 2; rj.off[2] = 4; rj.off[3] = 6; rj.off[4] = 8;
            skred_k<<<dim3(1024, 4), 256, 0, st>>>(rj, skbuf);
        }
        {   // batched gW1
            SkBatch sb = {};
            sb.A[0] = f1c;  sb.B[0] = t0c;
            sb.A[1] = gs1c; sb.B[1] = g1c;
            sb.A[2] = d1c;  sb.B[2] = l1c;
            sb.Ks = 2048;
            int jo[5] = {0, 1, 1, 1, 2};
            int kb[5] = {0, 0, 2048, 4096, 0};
            for (int z = 0; z < 5; z++) { sb.job_of_z[z] = jo[z]; sb.kb_of_z[z] = kb[z]; }
            skb_k<<<dim3(8, 8, 5), 256, 0, st>>>(sb, skbuf);
            RedJ rj = {};
            rj.dst[0] = gW1;
            rj.off[0] = 0; rj.off[1] = 5;
            skred_k<<<dim3(1024, 1), 256, 0, st>>>(rj, skbuf);
        }
        g64<1>(st, f1c, W1, l2c, CH, H, H);                     // bar_t0
        g64<1>(st, gs1c, W1, g1c, 3 * CH, H, H);                // bar_g1
        bwd0p_k<<<dim3(2, 8), 256, 0, st>>>(Xc, CH, W0, t0c, l2c, ls1c, g1c, b0part);
        bwd0red_k<<<8, 256, 0, st>>>(b0part, gW0, gb0v);
    }

    // ---------------- boundary ----------------
    fwd0_k<0><<<(NB * H + 255) / 256, 256, 0, st>>>(Xb, W0, b0, NB, t0c, nullptr, nullptr);
    g64_bt(st, t0c, W1, b1, t1c, NB, H, H);
    bnd_fin_k<<<NB / 4, 256, 0, st>>>(t1c, W2, b2, Xb, NB, rb);
    dualred_k<<<2, 256, 0, st>>>(ri, rb, S_B2, gb2v, S_B2b);
    delta1_k<<<(NB * H + 255) / 256, 256, 0, st>>>(t1c, rb, W2, 1.f / NB, d1c, NB);
    {
        SkBatch sb = {};
        sb.A[0] = d1c; sb.B[0] = d1c;
        sb.A[1] = t0c; sb.B[1] = t0c;
        sb.A[2] = t1c; sb.B[2] = t1c;
        sb.Ks = 1024;
        for (int z = 0; z < 6; z++) { sb.job_of_z[z] = z >> 1; sb.kb_of_z[z] = (z & 1) * 1024; }
        skb_k<<<dim3(8, 8, 6), 256, 0, st>>>(sb, skbuf);
        RedJ rj = {};
        rj.dst[0] = S8 + 6 * (i64)HH; rj.dst[1] = S8 + 5 * (i64)HH; rj.dst[2] = S8 + 7 * (i64)HH;
        rj.off[0] = 0; rj.off[1] = 2; rj.off[2] = 4; rj.off[3] = 6;
        skred_k<<<dim3(1024, 3), 256, 0, st>>>(rj, skbuf);
    }
    g_sk(st, d1c, t0c, gW1, H, H, NB, skbuf);
    g64_aux2(st, d1c, W1, e1c, NB, H, H, t0c);
    {
        WJ wj = {};
        wj.src[0] = t1c; wj.wgt[0] = rb; wj.scale[0] = 1.f / NB; wj.dst[0] = gW2;
        wj.src[1] = d1c; wj.wgt[1] = nullptr; wj.scale[1] = 1.f; wj.dst[1] = gb1v;
        wj.src[2] = e1c; wj.wgt[2] = nullptr; wj.scale[2] = 1.f; wj.dst[2] = gb0v;
        wcolp_k<<<dim3(2, 16, 3), 256, 0, st>>>(wj, NB, wpart);
        wcolr_k<<<dim3(2, 3), 256, 0, st>>>(wj, wpart);
    }
    g_sk(st, e1c, e1c, S8 + 4 * (i64)HH, H, H, NB, skbuf);
    g_sk(st, e1c, Xb, gW0, H, 3, NB, skbuf);
    xtx3b_k<<<2, 256, 0, st>>>(Xi, Xb, S_A0, S_Ab0);

    // ---------------- factor build + eigensolve ----------------
    {
        P8 mom = {};
        mom.p[0] = Bom0; mom.p[1] = Aom1; mom.p[2] = Bom1; mom.p[3] = Aom2;
        mom.p[4] = Bbd0; mom.p[5] = Abd1; mom.p[6] = Bbd1; mom.p[7] = Abd2;
        fbuildb_k<<<dim3(1024, 8), 256, 0, st>>>(mom, S8, Aeig);
    }
    identv_k<<<(int)((4 * (i64)HH + 255) / 256), 256, 0, st>>>(Veig, 4 * (i64)HH);
    small_eig_k<<<1, 1, 0, st>>>(Aom0, S_A0, Abd0, S_Ab0, Bom2, S_B2, Bbd2, S_B2b,
                                 UA0, eA0, eAb0, eScal);

    for (int sw = 0; sw < SOUTER; sw++)
        for (int r = 0; r < 7; r++) {
            eig_sub_k<<<dim3(4, 8), 1024, 0, st>>>(Aeig, rlog, r);
            ubuild_k<<<dim3(8, 32), 256, 0, st>>>(rlog, Ubuf);
            etA_k<<<384, 256, 0, st>>>(Aeig, Veig, Ubuf, Tbuf, r);
            etB_k<<<256, 256, 0, st>>>(Aeig, Ubuf, Tbuf, r);
        }
    sort_k<<<8, 512, 0, st>>>(Aeig, evals, ranks);
    perm_k<<<(int)((4 * (i64)HH + 255) / 256), 256, 0, st>>>(Veig, ranks, Vs);

    // ---------------- preconditioning ----------------
    g64<2>(st, Vs + 0 * (i64)HH, gW0, P1, H, 3, H);
    g64<1>(st, P1, UA0, P2, H, 3, 3);
    div2_k<<<6, 256, 0, st>>>(P2, evals + 0 * H, eA0, evals + 4 * H, eAb0, H, 3);
    g64<1>(st, Vs + 0 * (i64)HH, P2, P1, H, 3, H);
    g64<0>(st, P1, UA0, pcat + 0, H, 3, 3);
    g64<2>(st, Vs + 0 * (i64)HH, gb0v, P2, H, 1, H);
    div1_k<<<2, 256, 0, st>>>(P2, evals + 0 * H, evals + 4 * H, H);
    g64<1>(st, Vs + 0 * (i64)HH, P2, pcat + OFF_B0, H, 1, H);

    g64<2>(st, Vs + 2 * (i64)HH, gW1, P1, H, H, H);
    g64<1>(st, P1, Vs + 1 * (i64)HH, P2, H, H, H);
    div2_k<<<1024, 256, 0, st>>>(P2, evals + 2 * H, evals + 1 * H, evals + 6 * H, evals + 5 * H, H, H);
    g64<1>(st, Vs + 2 * (i64)HH, P2, P1, H, H, H);
    g64<0>(st, P1, Vs + 1 * (i64)HH, pcat + OFF_W1, H, H, H);
    g64<2>(st, Vs + 2 * (i64)HH, gb1v, P2, H, 1, H);
    div1_k<<<2, 256, 0, st>>>(P2, evals + 2 * H, evals + 6 * H, H);
    g64<1>(st, Vs + 2 * (i64)HH, P2, pcat + OFF_B1, H, 1, H);

    g64<1>(st, gW2, Vs + 3 * (i64)HH, P2, 1, H, H);
    div2s_k<<<2, 256, 0, st>>>(P2, eScal, evals + 3 * H, evals + 7 * H, H);
    g64<0>(st, P2, Vs + 3 * (i64)HH, pcat + OFF_W2, 1, H, H);
    scal2_k<<<1, 1, 0, st>>>(gb2v, eScal, pcat + OFF_B2);

    // ---------------- momentum ----------------
    mom_k<<<(TOT + 255) / 256, 256, 0, st>>>(mw0, mw1, mw2, mb0, mb1, mb2, pcat, mcat);

    // ---------------- line search: 2 z-batched launches ----------------
    lsf2_k<1><<<dim3(NI / 64, 8, 5), 256, 0, st>>>(Xi, W0, b0, W1, b1, W2, b2, mcat, NI, pI);
    lsf2_k<0><<<dim3(NB / 64, 8, 5), 256, 0, st>>>(Xb, W0, b0, W1, b1, W2, b2, mcat, NB, pB);
    lsred_k<<<10, 256, 0, st>>>(pI, pB, Xi, Xb, lossI, lossB);
    argmin_k<<<1, 1, 0, st>>>(lossI, lossB, bestA);
    upd_k<<<(TOT + 255) / 256, 256, 0, st>>>(W0, W1, W2, b0, b1, b2, mcat, 0.f, bestA,
                                             (float*)d_out);
}

// Round 9
// 14163.834 us; speedup vs baseline: 1.6189x; 1.2917x over previous
//
#include <hip/hip_runtime.h>
#include <cmath>

typedef long long i64;

#define NI 8192
#define NB 2048
#define CH 2048
#define H  512
#define HH 262144
#define TOT 265217
#define OFF_W1 1536
#define OFF_W2 263680
#define OFF_B0 264192
#define OFF_B1 264704
#define OFF_B2 265216
#define DAMP 1e-3f
#define DEC  0.95f
#define INNER 2
#define SOUTER 2
#define STEPS (INNER * 127)

__device__ __forceinline__ int imin(int a, int b) { return a < b ? a : b; }

// ======================= 64x64 GEMM, K-tile 32 =======================
template<int MODE, int BIAS, int TANH_, int FAST, int AUX>
__global__ __launch_bounds__(256) void gemm64_k(
    const float* __restrict__ A, const float* __restrict__ B,
    const float* __restrict__ bias, float* __restrict__ C,
    int M, int N, int K, const float* __restrict__ t0p, float* __restrict__ dst2)
{
    __shared__ float As[32][68];
    __shared__ float Bs[32][68];
    int tid = threadIdx.x;
    int tx = tid & 15, ty = tid >> 4;
    int m0 = blockIdx.x * 64, n0 = blockIdx.y * 64;
    float acc[4][4] = {};
    for (int k0 = 0; k0 < K; k0 += 32) {
        if (MODE == 0 || MODE == 1) {
            int m = tid >> 2, kq = (tid & 3) * 4;
            if (FAST) {
                const float* Ap = &A[(i64)(m0 + m) * K + k0 + kq];
                float4 v0 = *(const float4*)Ap;
                float4 v1 = *(const float4*)(Ap + 16);
                As[kq + 0][m] = v0.x; As[kq + 1][m] = v0.y;
                As[kq + 2][m] = v0.z; As[kq + 3][m] = v0.w;
                As[kq + 16][m] = v1.x; As[kq + 17][m] = v1.y;
                As[kq + 18][m] = v1.z; As[kq + 19][m] = v1.w;
            } else {
                int mm = m0 + m;
#pragma unroll
                for (int h = 0; h < 32; h += 16)
#pragma unroll
                    for (int i = 0; i < 4; i++) {
                        int kk = k0 + h + kq + i;
                        As[h + kq + i][m] = (mm < M && kk < K) ? A[(i64)mm * K + kk] : 0.f;
                    }
            }
        } else {
            int k = tid >> 4, mq = (tid & 15) * 4;
            if (FAST) {
                *(float4*)&As[k][mq]      = *(const float4*)&A[(i64)(k0 + k) * M + m0 + mq];
                *(float4*)&As[k + 16][mq] = *(const float4*)&A[(i64)(k0 + k + 16) * M + m0 + mq];
            } else {
#pragma unroll
                for (int h = 0; h < 32; h += 16) {
                    int kk = k0 + k + h;
#pragma unroll
                    for (int i = 0; i < 4; i++) {
                        int mm = m0 + mq + i;
                        As[k + h][mq + i] = (kk < K && mm < M) ? A[(i64)kk * M + mm] : 0.f;
                    }
                }
            }
        }
        if (MODE == 0) {
            int n = tid >> 2, kq = (tid & 3) * 4;
            if (FAST) {
                const float* Bp = &B[(i64)(n0 + n) * K + k0 + kq];
                float4 v0 = *(const float4*)Bp;
                float4 v1 = *(const float4*)(Bp + 16);
                Bs[kq + 0][n] = v0.x; Bs[kq + 1][n] = v0.y;
                Bs[kq + 2][n] = v0.z; Bs[kq + 3][n] = v0.w;
                Bs[kq + 16][n] = v1.x; Bs[kq + 17][n] = v1.y;
                Bs[kq + 18][n] = v1.z; Bs[kq + 19][n] = v1.w;
            } else {
                int nn = n0 + n;
#pragma unroll
                for (int h = 0; h < 32; h += 16)
#pragma unroll
                    for (int i = 0; i < 4; i++) {
                        int kk = k0 + h + kq + i;
                        Bs[h + kq + i][n] = (nn < N && kk < K) ? B[(i64)nn * K + kk] : 0.f;
                    }
            }
        } else {
            int k = tid >> 4, nq = (tid & 15) * 4;
            if (FAST) {
                *(float4*)&Bs[k][nq]      = *(const float4*)&B[(i64)(k0 + k) * N + n0 + nq];
                *(float4*)&Bs[k + 16][nq] = *(const float4*)&B[(i64)(k0 + k + 16) * N + n0 + nq];
            } else {
#pragma unroll
                for (int h = 0; h < 32; h += 16) {
                    int kk = k0 + k + h;
#pragma unroll
                    for (int i = 0; i < 4; i++) {
                        int nn = n0 + nq + i;
                        Bs[k + h][nq + i] = (kk < K && nn < N) ? B[(i64)kk * N + nn] : 0.f;
                    }
                }
            }
        }
        __syncthreads();
#pragma unroll
        for (int ks = 0; ks < 32; ks++) {
            float4 a = *(const float4*)&As[ks][ty * 4];
            float4 b = *(const float4*)&Bs[ks][tx * 4];
            float av[4] = {a.x, a.y, a.z, a.w};
            float bv[4] = {b.x, b.y, b.z, b.w};
#pragma unroll
            for (int i = 0; i < 4; i++)
#pragma unroll
                for (int j = 0; j < 4; j++) acc[i][j] += av[i] * bv[j];
        }
        __syncthreads();
    }
#pragma unroll
    for (int i = 0; i < 4; i++) {
        int m = m0 + ty * 4 + i;
        if (!FAST && m >= M) continue;
        if (FAST) {
            float4 vc, v2;
            float* pc = (float*)&vc; float* p2 = (float*)&v2;
            float4 t0v;
            if (AUX) t0v = *(const float4*)&t0p[(i64)m * N + n0 + tx * 4];
            const float* t0a = (const float*)&t0v;
#pragma unroll
            for (int j = 0; j < 4; j++) {
                float t = acc[i][j];
                if (BIAS) t += bias[n0 + tx * 4 + j];
                if (TANH_) t = tanhf(t);
                if (AUX == 1) { pc[j] = t; p2[j] = (1.f - t0a[j] * t0a[j]) * t; }
                else if (AUX == 2) { pc[j] = (1.f - t0a[j] * t0a[j]) * t; }
                else pc[j] = t;
            }
            *(float4*)&C[(i64)m * N + n0 + tx * 4] = vc;
            if (AUX == 1) *(float4*)&dst2[(i64)m * N + n0 + tx * 4] = v2;
        } else {
#pragma unroll
            for (int j = 0; j < 4; j++) {
                int n = n0 + tx * 4 + j;
                if (n >= N) continue;
                float t = acc[i][j];
                if (BIAS) t += bias[n];
                if (TANH_) t = tanhf(t);
                if (AUX) {
                    float t0v = t0p[(i64)m * N + n];
                    if (AUX == 1) { C[(i64)m * N + n] = t; dst2[(i64)m * N + n] = (1.f - t0v * t0v) * t; }
                    else C[(i64)m * N + n] = (1.f - t0v * t0v) * t;
                } else C[(i64)m * N + n] = t;
            }
        }
    }
}

// single split-K TN (slow/odd shapes)
template<int FAST>
__global__ __launch_bounds__(256) void gemm_tn_sk_k(
    const float* __restrict__ A, const float* __restrict__ B,
    float* __restrict__ P, int M, int N, int K, int Ks)
{
    __shared__ float As[32][68];
    __shared__ float Bs[32][68];
    int tid = threadIdx.x;
    int tx = tid & 15, ty = tid >> 4;
    int m0 = blockIdx.x * 64, n0 = blockIdx.y * 64, s = blockIdx.z;
    int kb = s * Ks, ke = imin(K, kb + Ks);
    float acc[4][4] = {};
    for (int k0 = kb; k0 < ke; k0 += 32) {
        int k = tid >> 4, q = (tid & 15) * 4;
        if (FAST) {
            *(float4*)&As[k][q]      = *(const float4*)&A[(i64)(k0 + k) * M + m0 + q];
            *(float4*)&As[k + 16][q] = *(const float4*)&A[(i64)(k0 + k + 16) * M + m0 + q];
            *(float4*)&Bs[k][q]      = *(const float4*)&B[(i64)(k0 + k) * N + n0 + q];
            *(float4*)&Bs[k + 16][q] = *(const float4*)&B[(i64)(k0 + k + 16) * N + n0 + q];
        } else {
#pragma unroll
            for (int h = 0; h < 32; h += 16) {
                int kk = k0 + k + h;
#pragma unroll
                for (int i = 0; i < 4; i++) {
                    int mm = m0 + q + i, nn = n0 + q + i;
                    As[k + h][q + i] = (kk < ke && mm < M) ? A[(i64)kk * M + mm] : 0.f;
                    Bs[k + h][q + i] = (kk < ke && nn < N) ? B[(i64)kk * N + nn] : 0.f;
                }
            }
        }
        __syncthreads();
#pragma unroll
        for (int ks = 0; ks < 32; ks++) {
            float4 a = *(const float4*)&As[ks][ty * 4];
            float4 b = *(const float4*)&Bs[ks][tx * 4];
            float av[4] = {a.x, a.y, a.z, a.w};
            float bv[4] = {b.x, b.y, b.z, b.w};
#pragma unroll
            for (int i = 0; i < 4; i++)
#pragma unroll
                for (int j = 0; j < 4; j++) acc[i][j] += av[i] * bv[j];
        }
        __syncthreads();
    }
    float* Po = P + (i64)s * M * N;
#pragma unroll
    for (int i = 0; i < 4; i++) {
        int m = m0 + ty * 4 + i;
        if (m >= M) continue;
#pragma unroll
        for (int j = 0; j < 4; j++) {
            int n = n0 + tx * 4 + j;
            if (n >= N) continue;
            Po[(i64)m * N + n] = acc[i][j];
        }
    }
}
__global__ void sk_red_k(float* __restrict__ dst, const float* __restrict__ P, int cnt)
{
    int e = blockIdx.x * 256 + threadIdx.x;
    if (e >= cnt) return;
    float s = 0.f;
#pragma unroll
    for (int z = 0; z < 8; z++) s += P[(i64)z * cnt + e];
    dst[e] += s;
}

// ======== batched TN Gram/grad GEMMs (M=N=512, fast path only) ========
struct SkBatch {
    const float* A[5]; const float* B[5];
    int job_of_z[8];
    int kb_of_z[8];
    int Ks;
};
__global__ __launch_bounds__(256) void skb_k(SkBatch sb, float* __restrict__ P)
{
    __shared__ float As[32][68];
    __shared__ float Bs[32][68];
    int tid = threadIdx.x;
    int tx = tid & 15, ty = tid >> 4;
    int m0 = blockIdx.x * 64, n0 = blockIdx.y * 64, z = blockIdx.z;
    int j = sb.job_of_z[z];
    const float* A = sb.A[j]; const float* B = sb.B[j];
    int kb = sb.kb_of_z[z], ke = kb + sb.Ks;
    float acc[4][4] = {};
    for (int k0 = kb; k0 < ke; k0 += 32) {
        int k = tid >> 4, q = (tid & 15) * 4;
        *(float4*)&As[k][q]      = *(const float4*)&A[(i64)(k0 + k) * H + m0 + q];
        *(float4*)&As[k + 16][q] = *(const float4*)&A[(i64)(k0 + k + 16) * H + m0 + q];
        *(float4*)&Bs[k][q]      = *(const float4*)&B[(i64)(k0 + k) * H + n0 + q];
        *(float4*)&Bs[k + 16][q] = *(const float4*)&B[(i64)(k0 + k + 16) * H + n0 + q];
        __syncthreads();
#pragma unroll
        for (int ks = 0; ks < 32; ks++) {
            float4 a = *(const float4*)&As[ks][ty * 4];
            float4 b = *(const float4*)&Bs[ks][tx * 4];
            float av[4] = {a.x, a.y, a.z, a.w};
            float bv[4] = {b.x, b.y, b.z, b.w};
#pragma unroll
            for (int i = 0; i < 4; i++)
#pragma unroll
                for (int jj = 0; jj < 4; jj++) acc[i][jj] += av[i] * bv[jj];
        }
        __syncthreads();
    }
    float* Po = P + (i64)z * HH;
#pragma unroll
    for (int i = 0; i < 4; i++) {
        int m = m0 + ty * 4 + i;
#pragma unroll
        for (int jj = 0; jj < 4; jj++)
            Po[(i64)m * H + n0 + tx * 4 + jj] = acc[i][jj];
    }
}
struct RedJ { float* dst[4]; int off[5]; };
__global__ void skred_k(RedJ rj, const float* __restrict__ P)
{
    int e = blockIdx.x * 256 + threadIdx.x;
    int j = blockIdx.y;
    if (e >= HH) return;
    float s = 0.f;
    for (int z = rj.off[j]; z < rj.off[j + 1]; z++) s += P[(i64)z * HH + e];
    rj.dst[j][e] += s;
}

// ======================= elementwise / fused =======================
__global__ void zero_k(float* p, i64 n) {
    i64 e = (i64)blockIdx.x * 256 + threadIdx.x;
    if (e < n) p[e] = 0.f;
}

template<int FULL>
__global__ __launch_bounds__(256) void fwd0_k(
    const float* __restrict__ X, const float* __restrict__ W0,
    const float* __restrict__ b0, int rows,
    float* __restrict__ t0c, float* __restrict__ g1c, float* __restrict__ l1c)
{
    int e = blockIdx.x * 256 + threadIdx.x;
    if (e >= rows * H) return;
    int n = e >> 9, j = e & 511;
    const float* x = X + (i64)n * 3;
    float w0 = W0[j * 3 + 0], w1 = W0[j * 3 + 1], w2 = W0[j * 3 + 2];
    float s = x[0] * w0 + x[1] * w1 + x[2] * w2 + b0[j];
    float t = tanhf(s);
    t0c[e] = t;
    if (FULL) {
        float phi = 1.f - t * t;
        float u = -2.f * t * phi;
        float Q0 = w0 * w0 + w1 * w1 + w2 * w2;
        l1c[e] = u * Q0;
        i64 base = ((i64)n * 3) * H + j;
        g1c[base] = phi * w0;
        g1c[base + H] = phi * w1;
        g1c[base + 2 * H] = phi * w2;
    }
}

// fused lapfin + bwd_mid: per-row block; q kept in regs
__global__ __launch_bounds__(256) void lapbwd_k(
    const float* __restrict__ t1c, const float* __restrict__ ls1c,
    float* __restrict__ gs1c, const float* __restrict__ W2,
    const float* __restrict__ X, float invN,
    float* __restrict__ l2c, float* __restrict__ f1c, float* __restrict__ d1c,
    float* __restrict__ ri_out)
{
    __shared__ float red[4];
    __shared__ float riS;
    int n = blockIdx.x;
    int tid = threadIdx.x;
    float tv[2], phiv[2], uv[2], qv[2], lsv[2], g0v[2], g1v[2], g2v[2], w2v[2];
    float part = 0.f;
#pragma unroll
    for (int h = 0; h < 2; h++) {
        int m = tid + h * 256;
        i64 e = (i64)n * H + m;
        i64 b = ((i64)n * 3) * H + m;
        float g0 = gs1c[b], g1 = gs1c[b + H], g2 = gs1c[b + 2 * H];
        float q = g0 * g0 + g1 * g1 + g2 * g2;
        float t = t1c[e], phi = 1.f - t * t, u = -2.f * t * phi;
        float ls = ls1c[e];
        float l2 = phi * ls + u * q;
        l2c[e] = l2;
        part += l2 * W2[m];
        tv[h] = t; phiv[h] = phi; uv[h] = u; qv[h] = q; lsv[h] = ls;
        g0v[h] = g0; g1v[h] = g1; g2v[h] = g2; w2v[h] = W2[m];
    }
    for (int off = 32; off; off >>= 1) part += __shfl_down(part, off, 64);
    if ((tid & 63) == 0) red[tid >> 6] = part;
    __syncthreads();
    if (tid == 0) {
        float p = red[0] + red[1] + red[2] + red[3];
        const float* x = X + (i64)n * 3;
        float r = p - (sinf(x[0]) + sinf(x[1]) + sinf(x[2]));
        ri_out[n] = r;
        riS = r;
    }
    __syncthreads();
    float ri = riS;
#pragma unroll
    for (int h = 0; h < 2; h++) {
        int m = tid + h * 256;
        i64 e = (i64)n * H + m;
        i64 b = ((i64)n * 3) * H + m;
        float t = tv[h], phi = phiv[h], u = uv[h];
        float bl2 = ri * invN * w2v[h];
        f1c[e] = bl2 * (u * lsv[h] + (6.f * t * t - 2.f) * phi * qv[h]);
        d1c[e] = phi * bl2;
        float sc = 2.f * u * bl2;
        gs1c[b] = g0v[h] * sc; gs1c[b + H] = g1v[h] * sc; gs1c[b + 2 * H] = g2v[h] * sc;
    }
}

__global__ __launch_bounds__(256) void bnd_fin_k(
    const float* __restrict__ tb1, const float* __restrict__ W2,
    const float* __restrict__ b2, const float* __restrict__ X, int rows,
    float* __restrict__ rb_out)
{
    int wave = threadIdx.x >> 6, lane = threadIdx.x & 63;
    int n = blockIdx.x * 4 + wave;
    if (n >= rows) return;
    float p = 0.f;
    for (int m = lane; m < H; m += 64) p += tb1[(i64)n * H + m] * W2[m];
    for (int off = 32; off; off >>= 1) p += __shfl_down(p, off, 64);
    if (lane == 0) {
        const float* x = X + (i64)n * 3;
        rb_out[n] = p + b2[0] - (cosf(x[0]) + cosf(x[1]) + cosf(x[2]));
    }
}

// weighted column-sum jobs
struct WJ { const float* src[3]; const float* wgt[3]; float scale[3]; float* dst[3]; };
__global__ void wcolp_k(WJ wj, int rows, float* __restrict__ part)
{
    int m = blockIdx.x * 256 + threadIdx.x;
    int g = blockIdx.y, z = blockIdx.z;
    if (m >= H) return;
    const float* src = wj.src[z]; const float* w = wj.wgt[z];
    int per = (rows + 15) / 16;
    int n0 = g * per, n1 = imin(rows, n0 + per);
    float s = 0.f;
    for (int n = n0; n < n1; n++) {
        float ww = w ? w[n] : 1.f;
        s += ww * src[(i64)n * H + m];
    }
    part[(i64)(z * 16 + g) * H + m] = s;
}
__global__ void wcolr_k(WJ wj, const float* __restrict__ part)
{
    int m = blockIdx.x * 256 + threadIdx.x;
    int z = blockIdx.y;
    if (m >= H) return;
    float s = 0.f;
#pragma unroll
    for (int g = 0; g < 16; g++) s += part[(i64)(z * 16 + g) * H + m];
    wj.dst[z][m] += wj.scale[z] * s;
}

__global__ void dualred_k(const float* __restrict__ ri, const float* __restrict__ rb,
                          float* S_B2, float* gb2v, float* S_B2b)
{
    __shared__ float s1[256], s2[256];
    int z = blockIdx.x;
    const float* r = z ? rb : ri;
    int n = z ? NB : NI;
    float a = 0.f, b = 0.f;
    for (int i = threadIdx.x; i < n; i += 256) { float v = r[i]; a += v; b += v * v; }
    s1[threadIdx.x] = a; s2[threadIdx.x] = b; __syncthreads();
    for (int off = 128; off; off >>= 1) {
        if (threadIdx.x < off) { s1[threadIdx.x] += s1[threadIdx.x + off]; s2[threadIdx.x] += s2[threadIdx.x + off]; }
        __syncthreads();
    }
    if (threadIdx.x == 0) {
        float invN = 1.f / n;
        if (z == 0) { S_B2[0] += invN * invN * s2[0]; }
        else { gb2v[0] += invN * s1[0]; S_B2b[0] += invN * invN * s2[0]; }
    }
}

__global__ __launch_bounds__(256) void delta1_k(
    const float* __restrict__ t1c, const float* __restrict__ r,
    const float* __restrict__ W2, float invN, float* __restrict__ d1c, int rows)
{
    int e = blockIdx.x * 256 + threadIdx.x;
    if (e >= rows * H) return;
    int n = e >> 9, m = e & 511;
    float t = t1c[e];
    d1c[e] = (1.f - t * t) * (r[n] * invN) * W2[m];
}

__global__ void bwd0p_k(const float* __restrict__ X, int rows,
                        const float* __restrict__ W0,
                        const float* __restrict__ t0c, const float* __restrict__ bt0,
                        const float* __restrict__ bl1, const float* __restrict__ bg1,
                        float* __restrict__ part)
{
    int j = blockIdx.x * 256 + threadIdx.x;
    int g = blockIdx.y;
    if (j >= H) return;
    int per = (rows + 7) / 8;
    int n0 = g * per, n1 = imin(rows, n0 + per);
    float w0 = W0[j * 3], w1 = W0[j * 3 + 1], w2 = W0[j * 3 + 2];
    float Q0 = w0 * w0 + w1 * w1 + w2 * w2;
    float sW0 = 0, sW1 = 0, sW2 = 0, sUB = 0, sb = 0;
    for (int n = n0; n < n1; n++) {
        i64 e = (i64)n * H + j;
        float t = t0c[e], phi = 1.f - t * t, u = -2.f * t * phi;
        float bt = bt0[e], bl = bl1[e];
        i64 gb = ((i64)n * 3) * H + j;
        float g0 = bg1[gb], g1 = bg1[gb + H], g2 = bg1[gb + 2 * H];
        float bs = bt * phi + bl * (6.f * t * t - 2.f) * phi * Q0
                 + u * (g0 * w0 + g1 * w1 + g2 * w2);
        const float* x = X + (i64)n * 3;
        sW0 += bs * x[0] + phi * g0;
        sW1 += bs * x[1] + phi * g1;
        sW2 += bs * x[2] + phi * g2;
        sUB += u * bl;
        sb += bs;
    }
    float* pg = part + (i64)g * 2048;
    pg[j * 3 + 0] = sW0 + 2.f * w0 * sUB;
    pg[j * 3 + 1] = sW1 + 2.f * w1 * sUB;
    pg[j * 3 + 2] = sW2 + 2.f * w2 * sUB;
    pg[1536 + j] = sb;
}
__global__ void bwd0red_k(const float* __restrict__ part, float* __restrict__ gW0,
                          float* __restrict__ gb0)
{
    int e = blockIdx.x * 256 + threadIdx.x;
    if (e >= 2048) return;
    float s = 0.f;
#pragma unroll
    for (int g = 0; g < 8; g++) s += part[(i64)g * 2048 + e];
    if (e < 1536) gW0[e] += s;
    else gb0[e - 1536] += s;
}

__global__ __launch_bounds__(256) void xtx3b_k(const float* __restrict__ Xi,
                                               const float* __restrict__ Xb,
                                               float* __restrict__ S_A0,
                                               float* __restrict__ S_Ab0)
{
    __shared__ float red[256];
    int z = blockIdx.x;
    const float* X = z ? Xb : Xi;
    int rows = z ? NB : NI;
    float* dst = z ? S_Ab0 : S_A0;
    float s[9] = {};
    for (int n = threadIdx.x; n < rows; n += 256) {
        float x0 = X[(i64)n * 3], x1 = X[(i64)n * 3 + 1], x2 = X[(i64)n * 3 + 2];
        s[0] += x0 * x0; s[1] += x0 * x1; s[2] += x0 * x2;
        s[3] += x1 * x0; s[4] += x1 * x1; s[5] += x1 * x2;
        s[6] += x2 * x0; s[7] += x2 * x1; s[8] += x2 * x2;
    }
    for (int c = 0; c < 9; c++) {
        red[threadIdx.x] = s[c]; __syncthreads();
        for (int off = 128; off; off >>= 1) {
            if (threadIdx.x < off) red[threadIdx.x] += red[threadIdx.x + off];
            __syncthreads();
        }
        if (threadIdx.x == 0) dst[c] += red[0];
        __syncthreads();
    }
}

struct P8 { const float* p[8]; };
__global__ void fbuildb_k(P8 mom, const float* __restrict__ S, float* __restrict__ dst)
{
    int e = blockIdx.x * 256 + threadIdx.x;
    int z = blockIdx.y;
    if (e >= HH) return;
    float invN = (z < 4) ? (1.f / NI) : (1.f / NB);
    float v = DEC * mom.p[z][e] + (1.f - DEC) * invN * S[(i64)z * HH + e];
    if ((e >> 9) == (e & 511)) v += DAMP;
    dst[(i64)z * HH + e] = v;
}
__global__ void identv_k(float* V, i64 count) {
    i64 e = (i64)blockIdx.x * 256 + threadIdx.x;
    if (e >= count) return;
    i64 o = e % HH;
    V[e] = ((o >> 9) == (o & 511)) ? 1.f : 0.f;
}

// ======================= block Jacobi eigensolver =======================
__device__ __forceinline__ int pos7(int k, int r) { return k == 0 ? 0 : 1 + ((k - 1 + r) % 7); }
__device__ __forceinline__ int pos127s(int k, int s) {
    if (k == 0) return 0;
    int v = k - 1 + s;
    return 1 + (v < 127 ? v : v - 127);
}
__device__ __forceinline__ int gidx(int a, int gA, int gB) {
    return (a < 64) ? gA * 64 + a : gB * 64 + (a - 64);
}

// 128x128 subproblem: 1024 threads, incremental pair tracking,
// fused 2x2 transform, 1 barrier/step. Logs (c,s,p,q); reads A only.
__global__ __launch_bounds__(1024) void eig_sub_k(const float* __restrict__ Abase,
                                                  float* __restrict__ rlog, int r)
{
    __shared__ float Sa[128][129];
    __shared__ float Sb[128][129];
    int pr = blockIdx.x, mat = blockIdx.y;
    int gA = pos7(pr, r), gB = pos7(7 - pr, r);
    int tid = threadIdx.x, lane = tid & 63, wv = tid >> 6;  // wv 0..15
    const float* A = Abase + (i64)mat * HH;
    float4* lg = ((float4*)rlog) + (i64)(mat * 4 + pr) * (STEPS * 64);
    for (int e = tid; e < 128 * 128; e += 1024) {
        int a = e >> 7, b = e & 127;
        Sa[a][b] = A[(i64)gidx(a, gA, gB) * H + gidx(b, gA, gB)];
    }
    int pa = pos127s(lane, 0), qa = pos127s(127 - lane, 0);
    int pb[4], qb[4];
    bool pbz[4];
#pragma unroll
    for (int it = 0; it < 4; it++) {
        int bj = wv * 4 + it;
        pb[it] = pos127s(bj, 0);
        qb[it] = pos127s(127 - bj, 0);
        pbz[it] = (bj == 0);
    }
    bool paz = (lane == 0);
    __syncthreads();
    for (int gst = 0; gst < STEPS; ++gst) {
        float (*Scur)[129] = (gst & 1) ? Sb : Sa;
        float (*Snew)[129] = (gst & 1) ? Sa : Sb;
        float app = Scur[pa][pa], aqq = Scur[qa][qa], apq = Scur[pa][qa];
        float c = 1.f, s = 0.f;
        if (fabsf(apq) > 1e-30f) {
            float tau = (aqq - app) / (2.f * apq);
            float t = copysignf(1.f, tau) / (fabsf(tau) + sqrtf(1.f + tau * tau));
            c = 1.f / sqrtf(1.f + t * t); s = t * c;
        }
        if (tid < 64) lg[(i64)gst * 64 + lane] =
            make_float4(c, s, __int_as_float(pa), __int_as_float(qa));
        const float* rowp = &Scur[pa][0];
        const float* rowq = &Scur[qa][0];
        float* nrowp = &Snew[pa][0];
        float* nrowq = &Snew[qa][0];
#pragma unroll
        for (int it = 0; it < 4; it++) {
            int cb = pb[it], db = qb[it];
            float cj = __shfl(c, wv * 4 + it, 64);
            float sj = __shfl(s, wv * 4 + it, 64);
            float m00 = rowp[cb], m01 = rowp[db];
            float m10 = rowq[cb], m11 = rowq[db];
            float t0 = c * m00 - s * m10;
            float t1 = c * m01 - s * m11;
            float t2 = s * m00 + c * m10;
            float t3 = s * m01 + c * m11;
            nrowp[cb] = cj * t0 - sj * t1;
            nrowp[db] = sj * t0 + cj * t1;
            nrowq[cb] = cj * t2 - sj * t3;
            nrowq[db] = sj * t2 + cj * t3;
        }
        pa = paz ? 0 : (pa == 127 ? 1 : pa + 1);
        qa = (qa == 127 ? 1 : qa + 1);
#pragma unroll
        for (int it = 0; it < 4; it++) {
            pb[it] = pbz[it] ? 0 : (pb[it] == 127 ? 1 : pb[it] + 1);
            qb[it] = (qb[it] == 127 ? 1 : qb[it] + 1);
        }
        __syncthreads();
    }
}

__global__ __launch_bounds__(256) void ubuild_k(const float* __restrict__ rlog,
                                                float* __restrict__ Ubuf)
{
    __shared__ float U[16][132];
    __shared__ float4 lb[2][64];
    int sl = blockIdx.x, mp = blockIdx.y;
    int tid = threadIdx.x;
    const float4* lg = ((const float4*)rlog) + (i64)mp * (STEPS * 64);
    int ro0 = sl * 16;
    for (int e = tid; e < 16 * 128; e += 256) {
        int rr = e >> 7, cc = e & 127;
        U[rr][cc] = (ro0 + rr == cc) ? 1.f : 0.f;
    }
    if (tid < 64) lb[0][tid] = lg[tid];
    __syncthreads();
    for (int st = 0; st < STEPS; st++) {
        float4 e4 = lb[st & 1][tid & 63];
        if (tid < 64 && st + 1 < STEPS) lb[(st + 1) & 1][tid] = lg[(i64)(st + 1) * 64 + tid];
        float c = e4.x, s = e4.y;
        int p = __float_as_int(e4.z), q = __float_as_int(e4.w);
        int rch = tid >> 6;
#pragma unroll
        for (int j = 0; j < 4; j++) {
            int rr = rch * 4 + j;
            float x = U[rr][p], y = U[rr][q];
            U[rr][p] = c * x - s * y; U[rr][q] = s * x + c * y;
        }
        __syncthreads();
    }
    float* Uo = Ubuf + (i64)mp * 16384;
    for (int e = tid; e < 16 * 128; e += 256) Uo[(i64)ro0 * 128 + e] = U[e >> 7][e & 127];
}

// etA: z<256: Tbuf[region] = A_region rows @ UJ ; z>=256: V rows (in-place) @ U_pr
__global__ __launch_bounds__(256) void etA_k(const float* __restrict__ Abase,
                                             float* __restrict__ Vbase,
                                             const float* __restrict__ Ubuf,
                                             float* __restrict__ Tbuf, int r)
{
    __shared__ float As[64][132];
    __shared__ float Bs[32][132];
    int z = blockIdx.x, tid = threadIdx.x;
    int tx = tid & 15, ty = tid >> 4;
    bool vpath = (z >= 256);
    const float* srcA; const float* Bsrc;
    float* dstT = nullptr; float* Vw = nullptr;
    int rowbase, gAj, gBj;
    if (!vpath) {
        int region = z >> 1, rt = z & 1;
        int mat = region >> 4, pp = region & 15, pri = pp >> 2, prj = pp & 3;
        int gAi = pos7(pri, r), gBi = pos7(7 - pri, r);
        gAj = pos7(prj, r); gBj = pos7(7 - prj, r);
        rowbase = (rt ? gBi : gAi) * 64;
        srcA = Abase + (i64)mat * HH;
        Bsrc = Ubuf + (i64)(mat * 4 + prj) * 16384;
        dstT = Tbuf + (i64)region * 16384 + (i64)(rt * 64) * 128;
    } else {
        int vz = z - 256;
        int mat = vz >> 5, rest = vz & 31, pp2 = rest >> 3, tm = rest & 7;
        gAj = pos7(pp2, r); gBj = pos7(7 - pp2, r);
        rowbase = tm * 64;
        Vw = Vbase + (i64)mat * HH;
        srcA = Vw;
        Bsrc = Ubuf + (i64)(mat * 4 + pp2) * 16384;
    }
    for (int e = tid; e < 64 * 32; e += 256) {
        int i = e >> 5, k4 = (e & 31) * 4;
        int col = gidx(k4, gAj, gBj);
        *(float4*)&As[i][k4] = *(const float4*)&srcA[(i64)(rowbase + i) * H + col];
    }
    float acc[4][8] = {};
    __syncthreads();
    for (int k0 = 0; k0 < 128; k0 += 32) {
        for (int e = tid; e < 32 * 32; e += 256) {
            int ka = e >> 5, j4 = (e & 31) * 4;
            *(float4*)&Bs[ka][j4] = *(const float4*)&Bsrc[(i64)(k0 + ka) * 128 + j4];
        }
        __syncthreads();
#pragma unroll 4
        for (int kk = 0; kk < 32; kk++) {
            int k = k0 + kk;
            float av[4];
#pragma unroll
            for (int i = 0; i < 4; i++) av[i] = As[ty * 4 + i][k];
            float4 b0 = *(const float4*)&Bs[kk][tx * 8];
            float4 b1 = *(const float4*)&Bs[kk][tx * 8 + 4];
            float bv[8] = {b0.x, b0.y, b0.z, b0.w, b1.x, b1.y, b1.z, b1.w};
#pragma unroll
            for (int i = 0; i < 4; i++)
#pragma unroll
                for (int j = 0; j < 8; j++) acc[i][j] += av[i] * bv[j];
        }
        __syncthreads();
    }
    if (!vpath) {
#pragma unroll
        for (int i = 0; i < 4; i++) {
            int row = ty * 4 + i;
            float4 v0 = {acc[i][0], acc[i][1], acc[i][2], acc[i][3]};
            float4 v1 = {acc[i][4], acc[i][5], acc[i][6], acc[i][7]};
            *(float4*)&dstT[(i64)row * 128 + tx * 8] = v0;
            *(float4*)&dstT[(i64)row * 128 + tx * 8 + 4] = v1;
        }
    } else {
        int colbase = gidx(tx * 8, gAj, gBj);
#pragma unroll
        for (int i = 0; i < 4; i++) {
            int row = rowbase + ty * 4 + i;
            float4 v0 = {acc[i][0], acc[i][1], acc[i][2], acc[i][3]};
            float4 v1 = {acc[i][4], acc[i][5], acc[i][6], acc[i][7]};
            *(float4*)&Vw[(i64)row * H + colbase] = v0;
            *(float4*)&Vw[(i64)row * H + colbase + 4] = v1;
        }
    }
}

// etB: A_region = UI^T @ Tbuf[region]
__global__ __launch_bounds__(256) void etB_k(float* __restrict__ Abase,
                                             const float* __restrict__ Ubuf,
                                             const float* __restrict__ Tbuf, int r)
{
    __shared__ float As[32][68];
    __shared__ float Bs[32][132];
    int z = blockIdx.x, tid = threadIdx.x;
    int tx = tid & 15, ty = tid >> 4;
    int region = z >> 1, rt = z & 1;
    int mat = region >> 4, pp = region & 15, pri = pp >> 2, prj = pp & 3;
    int gAi = pos7(pri, r), gBi = pos7(7 - pri, r);
    int gAj = pos7(prj, r), gBj = pos7(7 - prj, r);
    const float* UI = Ubuf + (i64)(mat * 4 + pri) * 16384;
    const float* T = Tbuf + (i64)region * 16384;
    float* A = Abase + (i64)mat * HH;
    int outrowbase = (rt ? gBi : gAi) * 64;
    float acc[4][8] = {};
    for (int k0 = 0; k0 < 128; k0 += 32) {
        __syncthreads();
        for (int e = tid; e < 32 * 16; e += 256) {
            int ka = e >> 4, i4 = (e & 15) * 4;
            *(float4*)&As[ka][i4] = *(const float4*)&UI[(i64)(k0 + ka) * 128 + rt * 64 + i4];
        }
        for (int e = tid; e < 32 * 32; e += 256) {
            int ka = e >> 5, j4 = (e & 31) * 4;
            *(float4*)&Bs[ka][j4] = *(const float4*)&T[(i64)(k0 + ka) * 128 + j4];
        }
        __syncthreads();
#pragma unroll 4
        for (int kk = 0; kk < 32; kk++) {
            float4 a = *(const float4*)&As[kk][ty * 4];
            float av[4] = {a.x, a.y, a.z, a.w};
            float4 b0 = *(const float4*)&Bs[kk][tx * 8];
            float4 b1 = *(const float4*)&Bs[kk][tx * 8 + 4];
            float bv[8] = {b0.x, b0.y, b0.z, b0.w, b1.x, b1.y, b1.z, b1.w};
#pragma unroll
            for (int i = 0; i < 4; i++)
#pragma unroll
                for (int j = 0; j < 8; j++) acc[i][j] += av[i] * bv[j];
        }
    }
    int colbase = gidx(tx * 8, gAj, gBj);
#pragma unroll
    for (int i = 0; i < 4; i++) {
        int row = outrowbase + ty * 4 + i;
        float4 v0 = {acc[i][0], acc[i][1], acc[i][2], acc[i][3]};
        float4 v1 = {acc[i][4], acc[i][5], acc[i][6], acc[i][7]};
        *(float4*)&A[(i64)row * H + colbase] = v0;
        *(float4*)&A[(i64)row * H + colbase + 4] = v1;
    }
}

__global__ __launch_bounds__(512) void sort_k(const float* __restrict__ Afin,
                                              float* __restrict__ evals, int* __restrict__ rankbuf)
{
    __shared__ float d[512];
    int mat = blockIdx.x, i = threadIdx.x;
    float li = Afin[(i64)mat * HH + (i64)i * H + i];
    d[i] = li; __syncthreads();
    int cnt = 0;
    for (int j = 0; j < 512; j++) { float lj = d[j]; cnt += (lj < li) || (lj == li && j < i); }
    evals[mat * H + cnt] = li;
    if (mat < 4) rankbuf[mat * H + i] = cnt;
}
__global__ void perm_k(const float* __restrict__ Vfin, const int* __restrict__ rankbuf,
                       float* __restrict__ Vs)
{
    i64 e = (i64)blockIdx.x * 256 + threadIdx.x;
    if (e >= (i64)4 * HH) return;
    int mat = (int)(e / HH); i64 o = e % HH;
    int rrow = (int)(o >> 9), i = (int)(o & 511);
    Vs[(i64)mat * HH + (i64)rrow * H + rankbuf[mat * H + i]] = Vfin[e];
}

// ======================= small (3x3, 1x1) eigens =======================
__device__ void jacobi3(float A[3][3], float V[3][3], bool wantV) {
    if (wantV) for (int r = 0; r < 3; r++) for (int c = 0; c < 3; c++) V[r][c] = (r == c) ? 1.f : 0.f;
    const int PP[3] = {0, 0, 1}, QQ[3] = {1, 2, 2};
    for (int sw = 0; sw < 30; sw++)
        for (int e = 0; e < 3; e++) {
            int p = PP[e], q = QQ[e];
            float apq = A[p][q];
            if (fabsf(apq) < 1e-30f) continue;
            float tau = (A[q][q] - A[p][p]) / (2.f * apq);
            float t = copysignf(1.f, tau) / (fabsf(tau) + sqrtf(1.f + tau * tau));
            float c = 1.f / sqrtf(1.f + t * t), s = t * c;
            for (int k = 0; k < 3; k++) { float x = A[p][k], y = A[q][k]; A[p][k] = c * x - s * y; A[q][k] = s * x + c * y; }
            for (int k = 0; k < 3; k++) { float x = A[k][p], y = A[k][q]; A[k][p] = c * x - s * y; A[k][q] = s * x + c * y; }
            if (wantV) for (int k = 0; k < 3; k++) { float x = V[k][p], y = V[k][q]; V[k][p] = c * x - s * y; V[k][q] = s * x + c * y; }
        }
}

__global__ void small_eig_k(const float* Aom0, const float* S_A0,
                            const float* Abd0, const float* S_Ab0,
                            const float* Bom2, const float* S_B2,
                            const float* Bbd2, const float* S_B2b,
                            float* UA0, float* eA0, float* eAb0, float* eScal)
{
    if (threadIdx.x || blockIdx.x) return;
    float A[3][3], V[3][3];
    for (int r = 0; r < 3; r++) for (int c = 0; c < 3; c++) {
        A[r][c] = DEC * Aom0[r * 3 + c] + (1.f - DEC) * S_A0[r * 3 + c] / (float)NI;
        if (r == c) A[r][c] += DAMP;
    }
    jacobi3(A, V, true);
    int ord[3] = {0, 1, 2};
    for (int i = 0; i < 2; i++) for (int j = 0; j < 2 - i; j++)
        if (A[ord[j]][ord[j]] > A[ord[j + 1]][ord[j + 1]]) { int t = ord[j]; ord[j] = ord[j + 1]; ord[j + 1] = t; }
    for (int k = 0; k < 3; k++) { eA0[k] = A[ord[k]][ord[k]]; for (int r = 0; r < 3; r++) UA0[r * 3 + k] = V[r][ord[k]]; }

    for (int r = 0; r < 3; r++) for (int c = 0; c < 3; c++) {
        A[r][c] = DEC * Abd0[r * 3 + c] + (1.f - DEC) * S_Ab0[r * 3 + c] / (float)NB;
        if (r == c) A[r][c] += DAMP;
    }
    jacobi3(A, V, false);
    int ord2[3] = {0, 1, 2};
    for (int i = 0; i < 2; i++) for (int j = 0; j < 2 - i; j++)
        if (A[ord2[j]][ord2[j]] > A[ord2[j + 1]][ord2[j + 1]]) { int t = ord2[j]; ord2[j] = ord2[j + 1]; ord2[j + 1] = t; }
    for (int k = 0; k < 3; k++) eAb0[k] = A[ord2[k]][ord2[k]];

    eScal[0] = DEC * Bom2[0] + (1.f - DEC) * S_B2[0] / (float)NI + DAMP;
    eScal[1] = DEC * Bbd2[0] + (1.f - DEC) * S_B2b[0] / (float)NB + DAMP;
}

// ======================= preconditioning =======================
__global__ void div2_k(float* P, const float* eG, const float* eA,
                       const float* eGb, const float* eAb, int Mg, int Na)
{
    int e = blockIdx.x * 256 + threadIdx.x;
    if (e >= Mg * Na) return;
    int a = e / Na, b = e % Na;
    P[e] /= (eG[a] * eA[b] + eGb[a] * eAb[b]);
}
__global__ void div1_k(float* v, const float* eG, const float* eGb, int Mg)
{
    int e = blockIdx.x * 256 + threadIdx.x;
    if (e >= Mg) return;
    v[e] /= (eG[e] + eGb[e]);
}
__global__ void div2s_k(float* P, const float* eScal, const float* eA, const float* eAb, int Na)
{
    int e = blockIdx.x * 256 + threadIdx.x;
    if (e >= Na) return;
    P[e] /= (eScal[0] * eA[e] + eScal[1] * eAb[e]);
}
__global__ void scal2_k(const float* g, const float* eScal, float* out)
{
    if (threadIdx.x || blockIdx.x) return;
    out[0] = g[0] / (eScal[0] + eScal[1]);
}

// ======================= params concat helpers =======================
__device__ __forceinline__ float pick6(int e, const float* W0, const float* W1, const float* W2,
                                       const float* b0, const float* b1, const float* b2)
{
    if (e < OFF_W1) return W0[e];
    if (e < OFF_W2) return W1[e - OFF_W1];
    if (e < OFF_B0) return W2[e - OFF_W2];
    if (e < OFF_B1) return b0[e - OFF_B0];
    if (e < OFF_B2) return b1[e - OFF_B1];
    return b2[0];
}
__global__ void mom_k(const float* mw0, const float* mw1, const float* mw2,
                      const float* mb0, const float* mb1, const float* mb2,
                      const float* __restrict__ pcat, float* __restrict__ mcat)
{
    int e = blockIdx.x * 256 + threadIdx.x;
    if (e >= TOT) return;
    mcat[e] = 0.9f * pick6(e, mw0, mw1, mw2, mb0, mb1, mb2) + pcat[e];
}
__global__ void upd_k(const float* W0, const float* W1, const float* W2,
                      const float* b0, const float* b1, const float* b2,
                      const float* __restrict__ mcat, float alpha, const float* alphap,
                      float* __restrict__ out)
{
    int e = blockIdx.x * 256 + threadIdx.x;
    if (e >= TOT) return;
    float a = alphap ? alphap[0] : alpha;
    out[e] = pick6(e, W0, W1, W2, b0, b1, b2) - a * mcat[e];
}
__global__ void argmin_k(const float* lossI, const float* lossB, float* bestA)
{
    if (threadIdx.x || blockIdx.x) return;
    float best = 3.4e38f, ba = 0.01f;
    for (int k = 0; k < 5; k++) {
        float l = 0.5f * (lossI[k] / (float)NI) + 0.5f * (lossB[k] / (float)NB);
        float al = 0.01f * (1.0f / (float)(1 << k));
        if (l < best) { best = l; ba = al; }
    }
    bestA[0] = ba;
}

// ============ line-search mega kernel v2: fused t0, z = alpha ============
template<int LAP>
__global__ __launch_bounds__(256) void lsf2_k(
    const float* __restrict__ X,
    const float* __restrict__ W0, const float* __restrict__ b0,
    const float* __restrict__ W1, const float* __restrict__ b1,
    const float* __restrict__ W2, const float* __restrict__ b2,
    const float* __restrict__ mcat, int nrows, float* __restrict__ part)
{
    __shared__ float As[32][68];
    __shared__ float Bs[32][68];
    __shared__ float wq[32][8];
    __shared__ float Xs[64][4];
    __shared__ float red[64][17];
    int tid = threadIdx.x, tx = tid & 15, ty = tid >> 4;
    int n0 = blockIdx.x * 64, m0 = blockIdx.y * 64;
    float al = 0.01f * (1.0f / (float)(1 << blockIdx.z));
    if (tid < 192) { int n = tid / 3, d = tid - n * 3; Xs[n][d] = X[(i64)(n0 + n) * 3 + d]; }
    float a_t[4][4] = {}, a_g0[4][4] = {}, a_g1[4][4] = {}, a_g2[4][4] = {}, a_l[4][4] = {};
    __syncthreads();
    for (int k0 = 0; k0 < 512; k0 += 32) {
        {
            int n = tid >> 2, kq = (tid & 3) * 4;
            const float* p = &W1[(i64)(m0 + n) * 512 + k0 + kq];
            const float* pm = &mcat[OFF_W1 + (i64)(m0 + n) * 512 + k0 + kq];
            float4 v0 = *(const float4*)p, v1 = *(const float4*)(p + 16);
            float4 m0v = *(const float4*)pm, m1v = *(const float4*)(pm + 16);
            Bs[kq + 0][n] = v0.x - al * m0v.x; Bs[kq + 1][n] = v0.y - al * m0v.y;
            Bs[kq + 2][n] = v0.z - al * m0v.z; Bs[kq + 3][n] = v0.w - al * m0v.w;
            Bs[kq + 16][n] = v1.x - al * m1v.x; Bs[kq + 17][n] = v1.y - al * m1v.y;
            Bs[kq + 18][n] = v1.z - al * m1v.z; Bs[kq + 19][n] = v1.w - al * m1v.w;
        }
        if (tid < 32) {
            int j = k0 + tid;
            float w0 = W0[j * 3]     - al * mcat[j * 3];
            float w1 = W0[j * 3 + 1] - al * mcat[j * 3 + 1];
            float w2 = W0[j * 3 + 2] - al * mcat[j * 3 + 2];
            float bb = b0[j] - al * mcat[OFF_B0 + j];
            wq[tid][0] = w0; wq[tid][1] = w1; wq[tid][2] = w2; wq[tid][3] = bb;
            wq[tid][4] = w0 * w0 + w1 * w1 + w2 * w2;
        }
        __syncthreads();
        {
            int n = tid >> 2, a = tid & 3;
            float x0 = Xs[n][0], x1 = Xs[n][1], x2 = Xs[n][2];
#pragma unroll
            for (int i = 0; i < 8; i++) {
                int k = a + 4 * i;
                float s = x0 * wq[k][0] + x1 * wq[k][1] + x2 * wq[k][2] + wq[k][3];
                As[k][n] = tanhf(s);
            }
        }
        __syncthreads();
#pragma unroll
        for (int ks = 0; ks < 32; ks++) {
            float4 a = *(const float4*)&As[ks][ty * 4];
            float4 b = *(const float4*)&Bs[ks][tx * 4];
            float av[4] = {a.x, a.y, a.z, a.w};
            float bv[4] = {b.x, b.y, b.z, b.w};
            if (LAP) {
                float w0 = wq[ks][0], w1 = wq[ks][1], w2 = wq[ks][2], q0 = wq[ks][4];
                float gv0[4], gv1[4], gv2[4], lv[4];
#pragma unroll
                for (int i = 0; i < 4; i++) {
                    float t = av[i], phi = 1.f - t * t, u = -2.f * t * phi;
                    gv0[i] = phi * w0; gv1[i] = phi * w1; gv2[i] = phi * w2; lv[i] = u * q0;
                }
#pragma unroll
                for (int i = 0; i < 4; i++)
#pragma unroll
                    for (int j = 0; j < 4; j++) {
                        a_t[i][j]  += av[i]  * bv[j];
                        a_g0[i][j] += gv0[i] * bv[j];
                        a_g1[i][j] += gv1[i] * bv[j];
                        a_g2[i][j] += gv2[i] * bv[j];
                        a_l[i][j]  += lv[i]  * bv[j];
                    }
            } else {
#pragma unroll
                for (int i = 0; i < 4; i++)
#pragma unroll
                    for (int j = 0; j < 4; j++) a_t[i][j] += av[i] * bv[j];
            }
        }
        __syncthreads();
    }
    float rowpart[4];
#pragma unroll
    for (int i = 0; i < 4; i++) {
        rowpart[i] = 0.f;
#pragma unroll
        for (int j = 0; j < 4; j++) {
            int m = m0 + tx * 4 + j;
            float s = a_t[i][j] + (b1[m] - al * mcat[OFF_B1 + m]);
            float t1 = tanhf(s);
            float val;
            if (LAP) {
                float phi = 1.f - t1 * t1, u = -2.f * t1 * phi;
                float q = a_g0[i][j] * a_g0[i][j] + a_g1[i][j] * a_g1[i][j] + a_g2[i][j] * a_g2[i][j];
                val = phi * a_l[i][j] + u * q;
            } else val = t1;
            rowpart[i] += val * (W2[m] - al * mcat[OFF_W2 + m]);
        }
    }
#pragma unroll
    for (int i = 0; i < 4; i++) red[ty * 4 + i][tx] = rowpart[i];
    __syncthreads();
    if (tid < 64) {
        float s = 0.f;
#pragma unroll
        for (int x = 0; x < 16; x++) s += red[tid][x];
        if (!LAP && blockIdx.y == 0) s += (b2[0] - al * mcat[OFF_B2]);
        part[((i64)blockIdx.z * 8 + blockIdx.y) * nrows + n0 + tid] = s;
    }
}

__global__ __launch_bounds__(256) void lsred_k(const float* __restrict__ pI,
                                               const float* __restrict__ pB,
                                               const float* __restrict__ Xi,
                                               const float* __restrict__ Xb,
                                               float* __restrict__ lossI,
                                               float* __restrict__ lossB)
{
    __shared__ float red[256];
    int z = blockIdx.x, a = z >> 1, isB = z & 1;
    int rows = isB ? NB : NI;
    const float* src = isB ? (pB + (i64)a * 8 * NB) : (pI + (i64)a * 8 * NI);
    const float* X = isB ? Xb : Xi;
    float acc = 0.f;
    for (int n = threadIdx.x; n < rows; n += 256) {
        float s = 0.f;
#pragma unroll
        for (int t = 0; t < 8; t++) s += src[(i64)t * rows + n];
        const float* x = X + (i64)n * 3;
        float rhs = isB ? (cosf(x[0]) + cosf(x[1]) + cosf(x[2]))
                        : (sinf(x[0]) + sinf(x[1]) + sinf(x[2]));
        float r = s - rhs;
        acc += r * r;
    }
    red[threadIdx.x] = acc; __syncthreads();
    for (int off = 128; off; off >>= 1) {
        if (threadIdx.x < off) red[threadIdx.x] += red[threadIdx.x + off];
        __syncthreads();
    }
    if (threadIdx.x == 0) {
        if (isB) lossB[a] = red[0];
        else lossI[a] = red[0];
    }
}

// ======================= host helpers =======================
template<int MODE>
static inline void g64(hipStream_t st, const float* A, const float* B, float* C,
                       int M, int N, int K) {
    dim3 g((M + 63) / 64, (N + 63) / 64);
    bool fast = (M % 64 == 0) && (N % 64 == 0) && (K % 32 == 0);
    if (fast) gemm64_k<MODE, 0, 0, 1, 0><<<g, 256, 0, st>>>(A, B, nullptr, C, M, N, K, nullptr, nullptr);
    else      gemm64_k<MODE, 0, 0, 0, 0><<<g, 256, 0, st>>>(A, B, nullptr, C, M, N, K, nullptr, nullptr);
}
static inline void g64_bt(hipStream_t st, const float* A, const float* B, const float* bias,
                          float* C, int M, int N, int K) {
    dim3 g((M + 63) / 64, (N + 63) / 64);
    gemm64_k<0, 1, 1, 1, 0><<<g, 256, 0, st>>>(A, B, bias, C, M, N, K, nullptr, nullptr);
}
static inline void g64_aux1(hipStream_t st, const float* A, const float* B, float* C,
                            int M, int N, int K, const float* t0p, float* dst2) {
    dim3 g((M + 63) / 64, (N + 63) / 64);
    gemm64_k<1, 0, 0, 1, 1><<<g, 256, 0, st>>>(A, B, nullptr, C, M, N, K, t0p, dst2);
}
static inline void g64_aux2(hipStream_t st, const float* A, const float* B, float* C,
                            int M, int N, int K, const float* t0p) {
    dim3 g((M + 63) / 64, (N + 63) / 64);
    gemm64_k<1, 0, 0, 1, 2><<<g, 256, 0, st>>>(A, B, nullptr, C, M, N, K, t0p, nullptr);
}
static inline void g_sk(hipStream_t st, const float* A, const float* B, float* dst,
                        int M, int N, int K, float* skbuf) {
    int Ks = ((K / 8) + 31) / 32 * 32;
    if (Ks * 8 < K) Ks += 32;
    dim3 g((M + 63) / 64, (N + 63) / 64, 8);
    bool fast = (M % 64 == 0) && (N % 64 == 0) && (K == Ks * 8);
    if (fast) gemm_tn_sk_k<1><<<g, 256, 0, st>>>(A, B, skbuf, M, N, K, Ks);
    else      gemm_tn_sk_k<0><<<g, 256, 0, st>>>(A, B, skbuf, M, N, K, Ks);
    int cnt = M * N;
    sk_red_k<<<(cnt + 255) / 256, 256, 0, st>>>(dst, skbuf, cnt);
}

extern "C" void kernel_launch(void* const* d_in, const int* in_sizes, int n_in,
                              void* d_out, int out_size, void* d_ws, size_t ws_size,
                              hipStream_t stream)
{
    const float* Xi   = (const float*)d_in[0];
    const float* Xb   = (const float*)d_in[1];
    const float* W0   = (const float*)d_in[2];
    const float* b0   = (const float*)d_in[3];
    const float* Aom0 = (const float*)d_in[4];
    const float* Bom0 = (const float*)d_in[5];
    const float* Abd0 = (const float*)d_in[6];
    const float* Bbd0 = (const float*)d_in[7];
    const float* mw0  = (const float*)d_in[8];
    const float* mb0  = (const float*)d_in[9];
    const float* W1   = (const float*)d_in[10];
    const float* b1   = (const float*)d_in[11];
    const float* Aom1 = (const float*)d_in[12];
    const float* Bom1 = (const float*)d_in[13];
    const float* Abd1 = (const float*)d_in[14];
    const float* Bbd1 = (const float*)d_in[15];
    const float* mw1  = (const float*)d_in[16];
    const float* mb1  = (const float*)d_in[17];
    const float* W2   = (const float*)d_in[18];
    const float* b2   = (const float*)d_in[19];
    const float* Aom2 = (const float*)d_in[20];
    const float* Bom2 = (const float*)d_in[21];
    const float* Abd2 = (const float*)d_in[22];
    const float* Bbd2 = (const float*)d_in[23];
    const float* mw2  = (const float*)d_in[24];
    const float* mb2  = (const float*)d_in[25];

    float* w = (float*)d_ws;
    i64 off = 0;
    auto alloc = [&](i64 n) { float* p = w + off; off += n; return p; };

    const i64 M1 = 1048576;
    float* arena = alloc(15 * M1);
    float* t0c = arena + 0 * M1;
    float* t1c = arena + 1 * M1;
    float* l1c = arena + 2 * M1;
    float* ls1c = arena + 3 * M1;
    float* l2c = arena + 5 * M1;
    float* d1c = arena + 6 * M1;
    float* e1c = arena + 7 * M1;
    float* f1c = arena + 8 * M1;
    float* g1c = arena + 9 * M1;
    float* gs1c = arena + 12 * M1;
    float* skbuf = arena + 4 * M1;
    // eigen views (phase-disjoint: rlog [eig_sub->ubuild], Tbuf [etA->etB])
    float* Aeig = arena + 0 * M1;
    float* Veig = arena + 2 * M1;
    float* Ubuf = arena + 3 * M1;
    float* Vs   = arena + 3 * M1 + 524288;
    float* rlog = arena + 5 * M1;
    float* Tbuf = arena + 8 * M1;
    // precond / LS views
    float* P1 = arena + 8 * M1;
    float* P2 = arena + 8 * M1 + HH;
    float* pI  = arena + 9 * M1;
    float* pB  = arena + 10 * M1;

    float* ri = alloc(NI);
    float* rb = alloc(NB);
    float* zero_base = w + off;
    float* S8   = alloc(8 * (i64)HH);
    float* S_A0 = alloc(9);
    float* S_Ab0 = alloc(9);
    float* S_B2 = alloc(1);
    float* S_B2b = alloc(1);
    float* gW0 = alloc(1536);
    float* gW1 = alloc(HH);
    float* gW2 = alloc(H);
    float* gb0v = alloc(H);
    float* gb1v = alloc(H);
    float* gb2v = alloc(1);
    float* lossI = alloc(5);
    float* lossB = alloc(5);
    i64 zero_count = (w + off) - zero_base;
    float* UA0 = alloc(9);
    float* eA0 = alloc(3);
    float* eAb0 = alloc(3);
    float* eScal = alloc(2);
    float* evals = alloc(4096);
    int*   ranks = (int*)alloc(2048);
    float* pcat = alloc(TOT);
    float* mcat = alloc(TOT);
    float* bestA = alloc(1);
    float* wpart = alloc(3 * 16 * H);
    float* b0part = alloc(8 * 2048);
    if (ws_size < (size_t)off * sizeof(float)) return;

    hipStream_t st = stream;
    zero_k<<<(int)((zero_count + 255) / 256), 256, 0, st>>>(zero_base, zero_count);

    const int EW = (CH * H + 255) / 256;

    // ---------------- interior chunks ----------------
    for (int c = 0; c < 4; c++) {
        const float* Xc = Xi + (i64)c * CH * 3;
        float* ric = ri + (i64)c * CH;
        fwd0_k<1><<<EW, 256, 0, st>>>(Xc, W0, b0, CH, t0c, g1c, l1c);
        g64_bt(st, t0c, W1, b1, t1c, CH, H, H);
        g64<0>(st, g1c, W1, gs1c, 3 * CH, H, H);
        g64<0>(st, l1c, W1, ls1c, CH, H, H);
        lapbwd_k<<<CH, 256, 0, st>>>(t1c, ls1c, gs1c, W2, Xc, 1.f / NI, l2c, f1c, d1c, ric);
        g64_aux1(st, d1c, W1, ls1c, CH, H, H, t0c, e1c);        // bar_l1 + delta0
        {
            WJ wj = {};
            wj.src[0] = l2c; wj.wgt[0] = ric; wj.scale[0] = 1.f / NI; wj.dst[0] = gW2;
            wj.src[1] = f1c; wj.wgt[1] = nullptr; wj.scale[1] = 1.f; wj.dst[1] = gb1v;
            wcolp_k<<<dim3(2, 16, 2), 256, 0, st>>>(wj, CH, wpart);
            wcolr_k<<<dim3(2, 2), 256, 0, st>>>(wj, wpart);
        }
        {   // batched Gram: Bo1, Bo0, Ao1, Ao2
            SkBatch sb = {};
            sb.A[0] = d1c; sb.B[0] = d1c;
            sb.A[1] = e1c; sb.B[1] = e1c;
            sb.A[2] = t0c; sb.B[2] = t0c;
            sb.A[3] = t1c; sb.B[3] = t1c;
            sb.Ks = 1024;
            for (int z = 0; z < 8; z++) { sb.job_of_z[z] = z >> 1; sb.kb_of_z[z] = (z & 1) * 1024; }
            skb_k<<<dim3(8, 8, 8), 256, 0, st>>>(sb, skbuf);
            RedJ rj = {};
            rj.dst[0] = S8 + 2 * (i64)HH; rj.dst[1] = S8 + 0 * (i64)HH;
            rj.dst[2] = S8 + 1 * (i64)HH; rj.dst[3] = S8 + 3 * (i64)HH;
            rj.off[0] = 0; rj.off[1] = 2; rj.off[2] = 4; rj.off[3] = 6; rj.off[4] = 8;
            skred_k<<<dim3(1024, 4), 256, 0, st>>>(rj, skbuf);
        }
        {   // batched gW1
            SkBatch sb = {};
            sb.A[0] = f1c;  sb.B[0] = t0c;
            sb.A[1] = gs1c; sb.B[1] = g1c;
            sb.A[2] = d1c;  sb.B[2] = l1c;
            sb.Ks = 2048;
            int jo[5] = {0, 1, 1, 1, 2};
            int kb[5] = {0, 0, 2048, 4096, 0};
            for (int z = 0; z < 5; z++) { sb.job_of_z[z] = jo[z]; sb.kb_of_z[z] = kb[z]; }
            skb_k<<<dim3(8, 8, 5), 256, 0, st>>>(sb, skbuf);
            RedJ rj = {};
            rj.dst[0] = gW1;
            rj.off[0] = 0; rj.off[1] = 5;
            skred_k<<<dim3(1024, 1), 256, 0, st>>>(rj, skbuf);
        }
        g64<1>(st, f1c, W1, l2c, CH, H, H);                     // bar_t0
        g64<1>(st, gs1c, W1, g1c, 3 * CH, H, H);                // bar_g1
        bwd0p_k<<<dim3(2, 8), 256, 0, st>>>(Xc, CH, W0, t0c, l2c, ls1c, g1c, b0part);
        bwd0red_k<<<8, 256, 0, st>>>(b0part, gW0, gb0v);
    }

    // ---------------- boundary ----------------
    fwd0_k<0><<<(NB * H + 255) / 256, 256, 0, st>>>(Xb, W0, b0, NB, t0c, nullptr, nullptr);
    g64_bt(st, t0c, W1, b1, t1c, NB, H, H);
    bnd_fin_k<<<NB / 4, 256, 0, st>>>(t1c, W2, b2, Xb, NB, rb);
    dualred_k<<<2, 256, 0, st>>>(ri, rb, S_B2, gb2v, S_B2b);
    delta1_k<<<(NB * H + 255) / 256, 256, 0, st>>>(t1c, rb, W2, 1.f / NB, d1c, NB);
    {
        SkBatch sb = {};
        sb.A[0] = d1c; sb.B[0] = d1c;
        sb.A[1] = t0c; sb.B[1] = t0c;
        sb.A[2] = t1c; sb.B[2] = t1c;
        sb.Ks = 1024;
        for (int z = 0; z < 6; z++) { sb.job_of_z[z] = z >> 1; sb.kb_of_z[z] = (z & 1) * 1024; }
        skb_k<<<dim3(8, 8, 6), 256, 0, st>>>(sb, skbuf);
        RedJ rj = {};
        rj.dst[0] = S8 + 6 * (i64)HH; rj.dst[1] = S8 + 5 * (i64)HH; rj.dst[2] = S8 + 7 * (i64)HH;
        rj.off[0] = 0; rj.off[1] = 2; rj.off[2] = 4; rj.off[3] = 6;
        skred_k<<<dim3(1024, 3), 256, 0, st>>>(rj, skbuf);
    }
    g_sk(st, d1c, t0c, gW1, H, H, NB, skbuf);
    g64_aux2(st, d1c, W1, e1c, NB, H, H, t0c);
    {
        WJ wj = {};
        wj.src[0] = t1c; wj.wgt[0] = rb; wj.scale[0] = 1.f / NB; wj.dst[0] = gW2;
        wj.src[1] = d1c; wj.wgt[1] = nullptr; wj.scale[1] = 1.f; wj.dst[1] = gb1v;
        wj.src[2] = e1c; wj.wgt[2] = nullptr; wj.scale[2] = 1.f; wj.dst[2] = gb0v;
        wcolp_k<<<dim3(2, 16, 3), 256, 0, st>>>(wj, NB, wpart);
        wcolr_k<<<dim3(2, 3), 256, 0, st>>>(wj, wpart);
    }
    g_sk(st, e1c, e1c, S8 + 4 * (i64)HH, H, H, NB, skbuf);
    g_sk(st, e1c, Xb, gW0, H, 3, NB, skbuf);
    xtx3b_k<<<2, 256, 0, st>>>(Xi, Xb, S_A0, S_Ab0);

    // ---------------- factor build + eigensolve ----------------
    {
        P8 mom = {};
        mom.p[0] = Bom0; mom.p[1] = Aom1; mom.p[2] = Bom1; mom.p[3] = Aom2;
        mom.p[4] = Bbd0; mom.p[5] = Abd1; mom.p[6] = Bbd1; mom.p[7] = Abd2;
        fbuildb_k<<<dim3(1024, 8), 256, 0, st>>>(mom, S8, Aeig);
    }
    identv_k<<<(int)((4 * (i64)HH + 255) / 256), 256, 0, st>>>(Veig, 4 * (i64)HH);
    small_eig_k<<<1, 1, 0, st>>>(Aom0, S_A0, Abd0, S_Ab0, Bom2, S_B2, Bbd2, S_B2b,
                                 UA0, eA0, eAb0, eScal);

    for (int sw = 0; sw < SOUTER; sw++)
        for (int r = 0; r < 7; r++) {
            eig_sub_k<<<dim3(4, 8), 1024, 0, st>>>(Aeig, rlog, r);
            ubuild_k<<<dim3(8, 32), 256, 0, st>>>(rlog, Ubuf);
            etA_k<<<384, 256, 0, st>>>(Aeig, Veig, Ubuf, Tbuf, r);
            etB_k<<<256, 256, 0, st>>>(Aeig, Ubuf, Tbuf, r);
        }
    sort_k<<<8, 512, 0, st>>>(Aeig, evals, ranks);
    perm_k<<<(int)((4 * (i64)HH + 255) / 256), 256, 0, st>>>(Veig, ranks, Vs);

    // ---------------- preconditioning ----------------
    g64<2>(st, Vs + 0 * (i64)HH, gW0, P1, H, 3, H);
    g64<1>(st, P1, UA0, P2, H, 3, 3);
    div2_k<<<6, 256, 0, st>>>(P2, evals + 0 * H, eA0, evals + 4 * H, eAb0, H, 3);
    g64<1>(st, Vs + 0 * (i64)HH, P2, P1, H, 3, H);
    g64<0>(st, P1, UA0, pcat + 0, H, 3, 3);
    g64<2>(st, Vs + 0 * (i64)HH, gb0v, P2, H, 1, H);
    div1_k<<<2, 256, 0, st>>>(P2, evals + 0 * H, evals + 4 * H, H);
    g64<1>(st, Vs + 0 * (i64)HH, P2, pcat + OFF_B0, H, 1, H);

    g64<2>(st, Vs + 2 * (i64)HH, gW1, P1, H, H, H);
    g64<1>(st, P1, Vs + 1 * (i64)HH, P2, H, H, H);
    div2_k<<<1024, 256, 0, st>>>(P2, evals + 2 * H, evals + 1 * H, evals + 6 * H, evals + 5 * H, H, H);
    g64<1>(st, Vs + 2 * (i64)HH, P2, P1, H, H, H);
    g64<0>(st, P1, Vs + 1 * (i64)HH, pcat + OFF_W1, H, H, H);
    g64<2>(st, Vs + 2 * (i64)HH, gb1v, P2, H, 1, H);
    div1_k<<<2, 256, 0, st>>>(P2, evals + 2 * H, evals + 6 * H, H);
    g64<1>(st, Vs + 2 * (i64)HH, P2, pcat + OFF_B1, H, 1, H);

    g64<1>(st, gW2, Vs + 3 * (i64)HH, P2, 1, H, H);
    div2s_k<<<2, 256, 0, st>>>(P2, eScal, evals + 3 * H, evals + 7 * H, H);
    g64<0>(st, P2, Vs + 3 * (i64)HH, pcat + OFF_W2, 1, H, H);
    scal2_k<<<1, 1, 0, st>>>(gb2v, eScal, pcat + OFF_B2);

    // ---------------- momentum ----------------
    mom_k<<<(TOT + 255) / 256, 256, 0, st>>>(mw0, mw1, mw2, mb0, mb1, mb2, pcat, mcat);

    // ---------------- line search: 2 z-batched launches ----------------
    lsf2_k<1><<<dim3(NI / 64, 8, 5), 256, 0, st>>>(Xi, W0, b0, W1, b1, W2, b2, mcat, NI, pI);
    lsf2_k<0><<<dim3(NB / 64, 8, 5), 256, 0, st>>>(Xb, W0, b0, W1, b1, W2, b2, mcat, NB, pB);
    lsred_k<<<10, 256, 0, st>>>(pI, pB, Xi, Xb, lossI, lossB);
    argmin_k<<<1, 1, 0, st>>>(lossI, lossB, bestA);
    upd_k<<<(TOT + 255) / 256, 256, 0, st>>>(W0, W1, W2, b0, b1, b2, mcat, 0.f, bestA,
                                             (float*)d_out);
}

// Round 10
// 9954.250 us; speedup vs baseline: 2.3035x; 1.4229x over previous
//
#include <hip/hip_runtime.h>
#include <cmath>

typedef long long i64;

#define NI 8192
#define NB 2048
#define CH 2048
#define H  512
#define HH 262144
#define TOT 265217
#define OFF_W1 1536
#define OFF_W2 263680
#define OFF_B0 264192
#define OFF_B1 264704
#define OFF_B2 265216
#define DAMP 1e-3f
#define DEC  0.95f
#define INNER 1
#define SOUTER 2
#define STEPS (INNER * 127)

__device__ __forceinline__ int imin(int a, int b) { return a < b ? a : b; }

// ======================= 64x64 GEMM, K-tile 32 =======================
template<int MODE, int BIAS, int TANH_, int FAST, int AUX>
__global__ __launch_bounds__(256) void gemm64_k(
    const float* __restrict__ A, const float* __restrict__ B,
    const float* __restrict__ bias, float* __restrict__ C,
    int M, int N, int K, const float* __restrict__ t0p, float* __restrict__ dst2)
{
    __shared__ float As[32][68];
    __shared__ float Bs[32][68];
    int tid = threadIdx.x;
    int tx = tid & 15, ty = tid >> 4;
    int m0 = blockIdx.x * 64, n0 = blockIdx.y * 64;
    float acc[4][4] = {};
    for (int k0 = 0; k0 < K; k0 += 32) {
        if (MODE == 0 || MODE == 1) {
            int m = tid >> 2, kq = (tid & 3) * 4;
            if (FAST) {
                const float* Ap = &A[(i64)(m0 + m) * K + k0 + kq];
                float4 v0 = *(const float4*)Ap;
                float4 v1 = *(const float4*)(Ap + 16);
                As[kq + 0][m] = v0.x; As[kq + 1][m] = v0.y;
                As[kq + 2][m] = v0.z; As[kq + 3][m] = v0.w;
                As[kq + 16][m] = v1.x; As[kq + 17][m] = v1.y;
                As[kq + 18][m] = v1.z; As[kq + 19][m] = v1.w;
            } else {
                int mm = m0 + m;
#pragma unroll
                for (int h = 0; h < 32; h += 16)
#pragma unroll
                    for (int i = 0; i < 4; i++) {
                        int kk = k0 + h + kq + i;
                        As[h + kq + i][m] = (mm < M && kk < K) ? A[(i64)mm * K + kk] : 0.f;
                    }
            }
        } else {
            int k = tid >> 4, mq = (tid & 15) * 4;
            if (FAST) {
                *(float4*)&As[k][mq]      = *(const float4*)&A[(i64)(k0 + k) * M + m0 + mq];
                *(float4*)&As[k + 16][mq] = *(const float4*)&A[(i64)(k0 + k + 16) * M + m0 + mq];
            } else {
#pragma unroll
                for (int h = 0; h < 32; h += 16) {
                    int kk = k0 + k + h;
#pragma unroll
                    for (int i = 0; i < 4; i++) {
                        int mm = m0 + mq + i;
                        As[k + h][mq + i] = (kk < K && mm < M) ? A[(i64)kk * M + mm] : 0.f;
                    }
                }
            }
        }
        if (MODE == 0) {
            int n = tid >> 2, kq = (tid & 3) * 4;
            if (FAST) {
                const float* Bp = &B[(i64)(n0 + n) * K + k0 + kq];
                float4 v0 = *(const float4*)Bp;
                float4 v1 = *(const float4*)(Bp + 16);
                Bs[kq + 0][n] = v0.x; Bs[kq + 1][n] = v0.y;
                Bs[kq + 2][n] = v0.z; Bs[kq + 3][n] = v0.w;
                Bs[kq + 16][n] = v1.x; Bs[kq + 17][n] = v1.y;
                Bs[kq + 18][n] = v1.z; Bs[kq + 19][n] = v1.w;
            } else {
                int nn = n0 + n;
#pragma unroll
                for (int h = 0; h < 32; h += 16)
#pragma unroll
                    for (int i = 0; i < 4; i++) {
                        int kk = k0 + h + kq + i;
                        Bs[h + kq + i][n] = (nn < N && kk < K) ? B[(i64)nn * K + kk] : 0.f;
                    }
            }
        } else {
            int k = tid >> 4, nq = (tid & 15) * 4;
            if (FAST) {
                *(float4*)&Bs[k][nq]      = *(const float4*)&B[(i64)(k0 + k) * N + n0 + nq];
                *(float4*)&Bs[k + 16][nq] = *(const float4*)&B[(i64)(k0 + k + 16) * N + n0 + nq];
            } else {
#pragma unroll
                for (int h = 0; h < 32; h += 16) {
                    int kk = k0 + k + h;
#pragma unroll
                    for (int i = 0; i < 4; i++) {
                        int nn = n0 + nq + i;
                        Bs[k + h][nq + i] = (kk < K && nn < N) ? B[(i64)kk * N + nn] : 0.f;
                    }
                }
            }
        }
        __syncthreads();
#pragma unroll
        for (int ks = 0; ks < 32; ks++) {
            float4 a = *(const float4*)&As[ks][ty * 4];
            float4 b = *(const float4*)&Bs[ks][tx * 4];
            float av[4] = {a.x, a.y, a.z, a.w};
            float bv[4] = {b.x, b.y, b.z, b.w};
#pragma unroll
            for (int i = 0; i < 4; i++)
#pragma unroll
                for (int j = 0; j < 4; j++) acc[i][j] += av[i] * bv[j];
        }
        __syncthreads();
    }
#pragma unroll
    for (int i = 0; i < 4; i++) {
        int m = m0 + ty * 4 + i;
        if (!FAST && m >= M) continue;
        if (FAST) {
            float4 vc, v2;
            float* pc = (float*)&vc; float* p2 = (float*)&v2;
            float4 t0v;
            if (AUX) t0v = *(const float4*)&t0p[(i64)m * N + n0 + tx * 4];
            const float* t0a = (const float*)&t0v;
#pragma unroll
            for (int j = 0; j < 4; j++) {
                float t = acc[i][j];
                if (BIAS) t += bias[n0 + tx * 4 + j];
                if (TANH_) t = tanhf(t);
                if (AUX == 1) { pc[j] = t; p2[j] = (1.f - t0a[j] * t0a[j]) * t; }
                else if (AUX == 2) { pc[j] = (1.f - t0a[j] * t0a[j]) * t; }
                else pc[j] = t;
            }
            *(float4*)&C[(i64)m * N + n0 + tx * 4] = vc;
            if (AUX == 1) *(float4*)&dst2[(i64)m * N + n0 + tx * 4] = v2;
        } else {
#pragma unroll
            for (int j = 0; j < 4; j++) {
                int n = n0 + tx * 4 + j;
                if (n >= N) continue;
                float t = acc[i][j];
                if (BIAS) t += bias[n];
                if (TANH_) t = tanhf(t);
                if (AUX) {
                    float t0v = t0p[(i64)m * N + n];
                    if (AUX == 1) { C[(i64)m * N + n] = t; dst2[(i64)m * N + n] = (1.f - t0v * t0v) * t; }
                    else C[(i64)m * N + n] = (1.f - t0v * t0v) * t;
                } else C[(i64)m * N + n] = t;
            }
        }
    }
}

// single split-K TN (slow/odd shapes)
template<int FAST>
__global__ __launch_bounds__(256) void gemm_tn_sk_k(
    const float* __restrict__ A, const float* __restrict__ B,
    float* __restrict__ P, int M, int N, int K, int Ks)
{
    __shared__ float As[32][68];
    __shared__ float Bs[32][68];
    int tid = threadIdx.x;
    int tx = tid & 15, ty = tid >> 4;
    int m0 = blockIdx.x * 64, n0 = blockIdx.y * 64, s = blockIdx.z;
    int kb = s * Ks, ke = imin(K, kb + Ks);
    float acc[4][4] = {};
    for (int k0 = kb; k0 < ke; k0 += 32) {
        int k = tid >> 4, q = (tid & 15) * 4;
        if (FAST) {
            *(float4*)&As[k][q]      = *(const float4*)&A[(i64)(k0 + k) * M + m0 + q];
            *(float4*)&As[k + 16][q] = *(const float4*)&A[(i64)(k0 + k + 16) * M + m0 + q];
            *(float4*)&Bs[k][q]      = *(const float4*)&B[(i64)(k0 + k) * N + n0 + q];
            *(float4*)&Bs[k + 16][q] = *(const float4*)&B[(i64)(k0 + k + 16) * N + n0 + q];
        } else {
#pragma unroll
            for (int h = 0; h < 32; h += 16) {
                int kk = k0 + k + h;
#pragma unroll
                for (int i = 0; i < 4; i++) {
                    int mm = m0 + q + i, nn = n0 + q + i;
                    As[k + h][q + i] = (kk < ke && mm < M) ? A[(i64)kk * M + mm] : 0.f;
                    Bs[k + h][q + i] = (kk < ke && nn < N) ? B[(i64)kk * N + nn] : 0.f;
                }
            }
        }
        __syncthreads();
#pragma unroll
        for (int ks = 0; ks < 32; ks++) {
            float4 a = *(const float4*)&As[ks][ty * 4];
            float4 b = *(const float4*)&Bs[ks][tx * 4];
            float av[4] = {a.x, a.y, a.z, a.w};
            float bv[4] = {b.x, b.y, b.z, b.w};
#pragma unroll
            for (int i = 0; i < 4; i++)
#pragma unroll
                for (int j = 0; j < 4; j++) acc[i][j] += av[i] * bv[j];
        }
        __syncthreads();
    }
    float* Po = P + (i64)s * M * N;
#pragma unroll
    for (int i = 0; i < 4; i++) {
        int m = m0 + ty * 4 + i;
        if (m >= M) continue;
#pragma unroll
        for (int j = 0; j < 4; j++) {
            int n = n0 + tx * 4 + j;
            if (n >= N) continue;
            Po[(i64)m * N + n] = acc[i][j];
        }
    }
}
__global__ void sk_red_k(float* __restrict__ dst, const float* __restrict__ P, int cnt)
{
    int e = blockIdx.x * 256 + threadIdx.x;
    if (e >= cnt) return;
    float s = 0.f;
#pragma unroll
    for (int z = 0; z < 8; z++) s += P[(i64)z * cnt + e];
    dst[e] += s;
}

// ======== batched TN Gram/grad GEMMs (M=N=512, fast path only) ========
struct SkBatch {
    const float* A[5]; const float* B[5];
    int job_of_z[8];
    int kb_of_z[8];
    int Ks;
};
__global__ __launch_bounds__(256) void skb_k(SkBatch sb, float* __restrict__ P)
{
    __shared__ float As[32][68];
    __shared__ float Bs[32][68];
    int tid = threadIdx.x;
    int tx = tid & 15, ty = tid >> 4;
    int m0 = blockIdx.x * 64, n0 = blockIdx.y * 64, z = blockIdx.z;
    int j = sb.job_of_z[z];
    const float* A = sb.A[j]; const float* B = sb.B[j];
    int kb = sb.kb_of_z[z], ke = kb + sb.Ks;
    float acc[4][4] = {};
    for (int k0 = kb; k0 < ke; k0 += 32) {
        int k = tid >> 4, q = (tid & 15) * 4;
        *(float4*)&As[k][q]      = *(const float4*)&A[(i64)(k0 + k) * H + m0 + q];
        *(float4*)&As[k + 16][q] = *(const float4*)&A[(i64)(k0 + k + 16) * H + m0 + q];
        *(float4*)&Bs[k][q]      = *(const float4*)&B[(i64)(k0 + k) * H + n0 + q];
        *(float4*)&Bs[k + 16][q] = *(const float4*)&B[(i64)(k0 + k + 16) * H + n0 + q];
        __syncthreads();
#pragma unroll
        for (int ks = 0; ks < 32; ks++) {
            float4 a = *(const float4*)&As[ks][ty * 4];
            float4 b = *(const float4*)&Bs[ks][tx * 4];
            float av[4] = {a.x, a.y, a.z, a.w};
            float bv[4] = {b.x, b.y, b.z, b.w};
#pragma unroll
            for (int i = 0; i < 4; i++)
#pragma unroll
                for (int jj = 0; jj < 4; jj++) acc[i][jj] += av[i] * bv[jj];
        }
        __syncthreads();
    }
    float* Po = P + (i64)z * HH;
#pragma unroll
    for (int i = 0; i < 4; i++) {
        int m = m0 + ty * 4 + i;
#pragma unroll
        for (int jj = 0; jj < 4; jj++)
            Po[(i64)m * H + n0 + tx * 4 + jj] = acc[i][jj];
    }
}
struct RedJ { float* dst[4]; int off[5]; };
__global__ void skred_k(RedJ rj, const float* __restrict__ P)
{
    int e = blockIdx.x * 256 + threadIdx.x;
    int j = blockIdx.y;
    if (e >= HH) return;
    float s = 0.f;
    for (int z = rj.off[j]; z < rj.off[j + 1]; z++) s += P[(i64)z * HH + e];
    rj.dst[j][e] += s;
}

// ======================= elementwise / fused =======================
__global__ void zero_k(float* p, i64 n) {
    i64 e = (i64)blockIdx.x * 256 + threadIdx.x;
    if (e < n) p[e] = 0.f;
}

template<int FULL>
__global__ __launch_bounds__(256) void fwd0_k(
    const float* __restrict__ X, const float* __restrict__ W0,
    const float* __restrict__ b0, int rows,
    float* __restrict__ t0c, float* __restrict__ g1c, float* __restrict__ l1c)
{
    int e = blockIdx.x * 256 + threadIdx.x;
    if (e >= rows * H) return;
    int n = e >> 9, j = e & 511;
    const float* x = X + (i64)n * 3;
    float w0 = W0[j * 3 + 0], w1 = W0[j * 3 + 1], w2 = W0[j * 3 + 2];
    float s = x[0] * w0 + x[1] * w1 + x[2] * w2 + b0[j];
    float t = tanhf(s);
    t0c[e] = t;
    if (FULL) {
        float phi = 1.f - t * t;
        float u = -2.f * t * phi;
        float Q0 = w0 * w0 + w1 * w1 + w2 * w2;
        l1c[e] = u * Q0;
        i64 base = ((i64)n * 3) * H + j;
        g1c[base] = phi * w0;
        g1c[base + H] = phi * w1;
        g1c[base + 2 * H] = phi * w2;
    }
}

// fused lapfin + bwd_mid: per-row block; q kept in regs
__global__ __launch_bounds__(256) void lapbwd_k(
    const float* __restrict__ t1c, const float* __restrict__ ls1c,
    float* __restrict__ gs1c, const float* __restrict__ W2,
    const float* __restrict__ X, float invN,
    float* __restrict__ l2c, float* __restrict__ f1c, float* __restrict__ d1c,
    float* __restrict__ ri_out)
{
    __shared__ float red[4];
    __shared__ float riS;
    int n = blockIdx.x;
    int tid = threadIdx.x;
    float tv[2], phiv[2], uv[2], qv[2], lsv[2], g0v[2], g1v[2], g2v[2], w2v[2];
    float part = 0.f;
#pragma unroll
    for (int h = 0; h < 2; h++) {
        int m = tid + h * 256;
        i64 e = (i64)n * H + m;
        i64 b = ((i64)n * 3) * H + m;
        float g0 = gs1c[b], g1 = gs1c[b + H], g2 = gs1c[b + 2 * H];
        float q = g0 * g0 + g1 * g1 + g2 * g2;
        float t = t1c[e], phi = 1.f - t * t, u = -2.f * t * phi;
        float ls = ls1c[e];
        float l2 = phi * ls + u * q;
        l2c[e] = l2;
        part += l2 * W2[m];
        tv[h] = t; phiv[h] = phi; uv[h] = u; qv[h] = q; lsv[h] = ls;
        g0v[h] = g0; g1v[h] = g1; g2v[h] = g2; w2v[h] = W2[m];
    }
    for (int off = 32; off; off >>= 1) part += __shfl_down(part, off, 64);
    if ((tid & 63) == 0) red[tid >> 6] = part;
    __syncthreads();
    if (tid == 0) {
        float p = red[0] + red[1] + red[2] + red[3];
        const float* x = X + (i64)n * 3;
        float r = p - (sinf(x[0]) + sinf(x[1]) + sinf(x[2]));
        ri_out[n] = r;
        riS = r;
    }
    __syncthreads();
    float ri = riS;
#pragma unroll
    for (int h = 0; h < 2; h++) {
        int m = tid + h * 256;
        i64 e = (i64)n * H + m;
        i64 b = ((i64)n * 3) * H + m;
        float t = tv[h], phi = phiv[h], u = uv[h];
        float bl2 = ri * invN * w2v[h];
        f1c[e] = bl2 * (u * lsv[h] + (6.f * t * t - 2.f) * phi * qv[h]);
        d1c[e] = phi * bl2;
        float sc = 2.f * u * bl2;
        gs1c[b] = g0v[h] * sc; gs1c[b + H] = g1v[h] * sc; gs1c[b + 2 * H] = g2v[h] * sc;
    }
}

__global__ __launch_bounds__(256) void bnd_fin_k(
    const float* __restrict__ tb1, const float* __restrict__ W2,
    const float* __restrict__ b2, const float* __restrict__ X, int rows,
    float* __restrict__ rb_out)
{
    int wave = threadIdx.x >> 6, lane = threadIdx.x & 63;
    int n = blockIdx.x * 4 + wave;
    if (n >= rows) return;
    float p = 0.f;
    for (int m = lane; m < H; m += 64) p += tb1[(i64)n * H + m] * W2[m];
    for (int off = 32; off; off >>= 1) p += __shfl_down(p, off, 64);
    if (lane == 0) {
        const float* x = X + (i64)n * 3;
        rb_out[n] = p + b2[0] - (cosf(x[0]) + cosf(x[1]) + cosf(x[2]));
    }
}

// weighted column-sum jobs
struct WJ { const float* src[3]; const float* wgt[3]; float scale[3]; float* dst[3]; };
__global__ void wcolp_k(WJ wj, int rows, float* __restrict__ part)
{
    int m = blockIdx.x * 256 + threadIdx.x;
    int g = blockIdx.y, z = blockIdx.z;
    if (m >= H) return;
    const float* src = wj.src[z]; const float* w = wj.wgt[z];
    int per = (rows + 15) / 16;
    int n0 = g * per, n1 = imin(rows, n0 + per);
    float s = 0.f;
    for (int n = n0; n < n1; n++) {
        float ww = w ? w[n] : 1.f;
        s += ww * src[(i64)n * H + m];
    }
    part[(i64)(z * 16 + g) * H + m] = s;
}
__global__ void wcolr_k(WJ wj, const float* __restrict__ part)
{
    int m = blockIdx.x * 256 + threadIdx.x;
    int z = blockIdx.y;
    if (m >= H) return;
    float s = 0.f;
#pragma unroll
    for (int g = 0; g < 16; g++) s += part[(i64)(z * 16 + g) * H + m];
    wj.dst[z][m] += wj.scale[z] * s;
}

__global__ void dualred_k(const float* __restrict__ ri, const float* __restrict__ rb,
                          float* S_B2, float* gb2v, float* S_B2b)
{
    __shared__ float s1[256], s2[256];
    int z = blockIdx.x;
    const float* r = z ? rb : ri;
    int n = z ? NB : NI;
    float a = 0.f, b = 0.f;
    for (int i = threadIdx.x; i < n; i += 256) { float v = r[i]; a += v; b += v * v; }
    s1[threadIdx.x] = a; s2[threadIdx.x] = b; __syncthreads();
    for (int off = 128; off; off >>= 1) {
        if (threadIdx.x < off) { s1[threadIdx.x] += s1[threadIdx.x + off]; s2[threadIdx.x] += s2[threadIdx.x + off]; }
        __syncthreads();
    }
    if (threadIdx.x == 0) {
        float invN = 1.f / n;
        if (z == 0) { S_B2[0] += invN * invN * s2[0]; }
        else { gb2v[0] += invN * s1[0]; S_B2b[0] += invN * invN * s2[0]; }
    }
}

__global__ __launch_bounds__(256) void delta1_k(
    const float* __restrict__ t1c, const float* __restrict__ r,
    const float* __restrict__ W2, float invN, float* __restrict__ d1c, int rows)
{
    int e = blockIdx.x * 256 + threadIdx.x;
    if (e >= rows * H) return;
    int n = e >> 9, m = e & 511;
    float t = t1c[e];
    d1c[e] = (1.f - t * t) * (r[n] * invN) * W2[m];
}

__global__ void bwd0p_k(const float* __restrict__ X, int rows,
                        const float* __restrict__ W0,
                        const float* __restrict__ t0c, const float* __restrict__ bt0,
                        const float* __restrict__ bl1, const float* __restrict__ bg1,
                        float* __restrict__ part)
{
    int j = blockIdx.x * 256 + threadIdx.x;
    int g = blockIdx.y;
    if (j >= H) return;
    int per = (rows + 7) / 8;
    int n0 = g * per, n1 = imin(rows, n0 + per);
    float w0 = W0[j * 3], w1 = W0[j * 3 + 1], w2 = W0[j * 3 + 2];
    float Q0 = w0 * w0 + w1 * w1 + w2 * w2;
    float sW0 = 0, sW1 = 0, sW2 = 0, sUB = 0, sb = 0;
    for (int n = n0; n < n1; n++) {
        i64 e = (i64)n * H + j;
        float t = t0c[e], phi = 1.f - t * t, u = -2.f * t * phi;
        float bt = bt0[e], bl = bl1[e];
        i64 gb = ((i64)n * 3) * H + j;
        float g0 = bg1[gb], g1 = bg1[gb + H], g2 = bg1[gb + 2 * H];
        float bs = bt * phi + bl * (6.f * t * t - 2.f) * phi * Q0
                 + u * (g0 * w0 + g1 * w1 + g2 * w2);
        const float* x = X + (i64)n * 3;
        sW0 += bs * x[0] + phi * g0;
        sW1 += bs * x[1] + phi * g1;
        sW2 += bs * x[2] + phi * g2;
        sUB += u * bl;
        sb += bs;
    }
    float* pg = part + (i64)g * 2048;
    pg[j * 3 + 0] = sW0 + 2.f * w0 * sUB;
    pg[j * 3 + 1] = sW1 + 2.f * w1 * sUB;
    pg[j * 3 + 2] = sW2 + 2.f * w2 * sUB;
    pg[1536 + j] = sb;
}
__global__ void bwd0red_k(const float* __restrict__ part, float* __restrict__ gW0,
                          float* __restrict__ gb0)
{
    int e = blockIdx.x * 256 + threadIdx.x;
    if (e >= 2048) return;
    float s = 0.f;
#pragma unroll
    for (int g = 0; g < 8; g++) s += part[(i64)g * 2048 + e];
    if (e < 1536) gW0[e] += s;
    else gb0[e - 1536] += s;
}

__global__ __launch_bounds__(256) void xtx3b_k(const float* __restrict__ Xi,
                                               const float* __restrict__ Xb,
                                               float* __restrict__ S_A0,
                                               float* __restrict__ S_Ab0)
{
    __shared__ float red[256];
    int z = blockIdx.x;
    const float* X = z ? Xb : Xi;
    int rows = z ? NB : NI;
    float* dst = z ? S_Ab0 : S_A0;
    float s[9] = {};
    for (int n = threadIdx.x; n < rows; n += 256) {
        float x0 = X[(i64)n * 3], x1 = X[(i64)n * 3 + 1], x2 = X[(i64)n * 3 + 2];
        s[0] += x0 * x0; s[1] += x0 * x1; s[2] += x0 * x2;
        s[3] += x1 * x0; s[4] += x1 * x1; s[5] += x1 * x2;
        s[6] += x2 * x0; s[7] += x2 * x1; s[8] += x2 * x2;
    }
    for (int c = 0; c < 9; c++) {
        red[threadIdx.x] = s[c]; __syncthreads();
        for (int off = 128; off; off >>= 1) {
            if (threadIdx.x < off) red[threadIdx.x] += red[threadIdx.x + off];
            __syncthreads();
        }
        if (threadIdx.x == 0) dst[c] += red[0];
        __syncthreads();
    }
}

struct P8 { const float* p[8]; };
__global__ void fbuildb_k(P8 mom, const float* __restrict__ S, float* __restrict__ dst)
{
    int e = blockIdx.x * 256 + threadIdx.x;
    int z = blockIdx.y;
    if (e >= HH) return;
    float invN = (z < 4) ? (1.f / NI) : (1.f / NB);
    float v = DEC * mom.p[z][e] + (1.f - DEC) * invN * S[(i64)z * HH + e];
    if ((e >> 9) == (e & 511)) v += DAMP;
    dst[(i64)z * HH + e] = v;
}
__global__ void identv_k(float* V, i64 count) {
    i64 e = (i64)blockIdx.x * 256 + threadIdx.x;
    if (e >= count) return;
    i64 o = e % HH;
    V[e] = ((o >> 9) == (o & 511)) ? 1.f : 0.f;
}

// ======================= block Jacobi eigensolver =======================
__device__ __forceinline__ int pos7(int k, int r) { return k == 0 ? 0 : 1 + ((k - 1 + r) % 7); }
__device__ __forceinline__ int pos127s(int k, int s) {
    if (k == 0) return 0;
    int v = k - 1 + s;
    return 1 + (v < 127 ? v : v - 127);
}
__device__ __forceinline__ int gidx(int a, int gA, int gB) {
    return (a < 64) ? gA * 64 + a : gB * 64 + (a - 64);
}

// 128x128 subproblem: 1024 threads, incremental pair tracking,
// fused 2x2 transform, 1 barrier/step. Logs (c,s,p,q); reads A only.
__global__ __launch_bounds__(1024) void eig_sub_k(const float* __restrict__ Abase,
                                                  float* __restrict__ rlog, int r)
{
    __shared__ float Sa[128][129];
    __shared__ float Sb[128][129];
    int pr = blockIdx.x, mat = blockIdx.y;
    int gA = pos7(pr, r), gB = pos7(7 - pr, r);
    int tid = threadIdx.x, lane = tid & 63, wv = tid >> 6;  // wv 0..15
    const float* A = Abase + (i64)mat * HH;
    float4* lg = ((float4*)rlog) + (i64)(mat * 4 + pr) * (STEPS * 64);
    for (int e = tid; e < 128 * 128; e += 1024) {
        int a = e >> 7, b = e & 127;
        Sa[a][b] = A[(i64)gidx(a, gA, gB) * H + gidx(b, gA, gB)];
    }
    int pa = pos127s(lane, 0), qa = pos127s(127 - lane, 0);
    int pb[4], qb[4];
    bool pbz[4];
#pragma unroll
    for (int it = 0; it < 4; it++) {
        int bj = wv * 4 + it;
        pb[it] = pos127s(bj, 0);
        qb[it] = pos127s(127 - bj, 0);
        pbz[it] = (bj == 0);
    }
    bool paz = (lane == 0);
    __syncthreads();
    for (int gst = 0; gst < STEPS; ++gst) {
        float (*Scur)[129] = (gst & 1) ? Sb : Sa;
        float (*Snew)[129] = (gst & 1) ? Sa : Sb;
        float app = Scur[pa][pa], aqq = Scur[qa][qa], apq = Scur[pa][qa];
        float c = 1.f, s = 0.f;
        if (fabsf(apq) > 1e-30f) {
            float tau = (aqq - app) / (2.f * apq);
            float t = copysignf(1.f, tau) / (fabsf(tau) + sqrtf(1.f + tau * tau));
            c = 1.f / sqrtf(1.f + t * t); s = t * c;
        }
        if (tid < 64) lg[(i64)gst * 64 + lane] =
            make_float4(c, s, __int_as_float(pa), __int_as_float(qa));
        const float* rowp = &Scur[pa][0];
        const float* rowq = &Scur[qa][0];
        float* nrowp = &Snew[pa][0];
        float* nrowq = &Snew[qa][0];
#pragma unroll
        for (int it = 0; it < 4; it++) {
            int cb = pb[it], db = qb[it];
            float cj = __shfl(c, wv * 4 + it, 64);
            float sj = __shfl(s, wv * 4 + it, 64);
            float m00 = rowp[cb], m01 = rowp[db];
            float m10 = rowq[cb], m11 = rowq[db];
            float t0 = c * m00 - s * m10;
            float t1 = c * m01 - s * m11;
            float t2 = s * m00 + c * m10;
            float t3 = s * m01 + c * m11;
            nrowp[cb] = cj * t0 - sj * t1;
            nrowp[db] = sj * t0 + cj * t1;
            nrowq[cb] = cj * t2 - sj * t3;
            nrowq[db] = sj * t2 + cj * t3;
        }
        pa = paz ? 0 : (pa == 127 ? 1 : pa + 1);
        qa = (qa == 127 ? 1 : qa + 1);
#pragma unroll
        for (int it = 0; it < 4; it++) {
            pb[it] = pbz[it] ? 0 : (pb[it] == 127 ? 1 : pb[it] + 1);
            qb[it] = (qb[it] == 127 ? 1 : qb[it] + 1);
        }
        __syncthreads();
    }
}

__global__ __launch_bounds__(256) void ubuild_k(const float* __restrict__ rlog,
                                                float* __restrict__ Ubuf)
{
    __shared__ float U[16][132];
    __shared__ float4 lb[2][64];
    int sl = blockIdx.x, mp = blockIdx.y;
    int tid = threadIdx.x;
    const float4* lg = ((const float4*)rlog) + (i64)mp * (STEPS * 64);
    int ro0 = sl * 16;
    for (int e = tid; e < 16 * 128; e += 256) {
        int rr = e >> 7, cc = e & 127;
        U[rr][cc] = (ro0 + rr == cc) ? 1.f : 0.f;
    }
    if (tid < 64) lb[0][tid] = lg[tid];
    __syncthreads();
    for (int st = 0; st < STEPS; st++) {
        float4 e4 = lb[st & 1][tid & 63];
        if (tid < 64 && st + 1 < STEPS) lb[(st + 1) & 1][tid] = lg[(i64)(st + 1) * 64 + tid];
        float c = e4.x, s = e4.y;
        int p = __float_as_int(e4.z), q = __float_as_int(e4.w);
        int rch = tid >> 6;
#pragma unroll
        for (int j = 0; j < 4; j++) {
            int rr = rch * 4 + j;
            float x = U[rr][p], y = U[rr][q];
            U[rr][p] = c * x - s * y; U[rr][q] = s * x + c * y;
        }
        __syncthreads();
    }
    float* Uo = Ubuf + (i64)mp * 16384;
    for (int e = tid; e < 16 * 128; e += 256) Uo[(i64)ro0 * 128 + e] = U[e >> 7][e & 127];
}

// etA: z<256: Tbuf[region] = A_region rows @ UJ ; z>=256: V rows (in-place) @ U_pr
__global__ __launch_bounds__(256) void etA_k(const float* __restrict__ Abase,
                                             float* __restrict__ Vbase,
                                             const float* __restrict__ Ubuf,
                                             float* __restrict__ Tbuf, int r)
{
    __shared__ float As[64][132];
    __shared__ float Bs[32][132];
    int z = blockIdx.x, tid = threadIdx.x;
    int tx = tid & 15, ty = tid >> 4;
    bool vpath = (z >= 256);
    const float* srcA; const float* Bsrc;
    float* dstT = nullptr; float* Vw = nullptr;
    int rowbase, gAj, gBj;
    if (!vpath) {
        int region = z >> 1, rt = z & 1;
        int mat = region >> 4, pp = region & 15, pri = pp >> 2, prj = pp & 3;
        int gAi = pos7(pri, r), gBi = pos7(7 - pri, r);
        gAj = pos7(prj, r); gBj = pos7(7 - prj, r);
        rowbase = (rt ? gBi : gAi) * 64;
        srcA = Abase + (i64)mat * HH;
        Bsrc = Ubuf + (i64)(mat * 4 + prj) * 16384;
        dstT = Tbuf + (i64)region * 16384 + (i64)(rt * 64) * 128;
    } else {
        int vz = z - 256;
        int mat = vz >> 5, rest = vz & 31, pp2 = rest >> 3, tm = rest & 7;
        gAj = pos7(pp2, r); gBj = pos7(7 - pp2, r);
        rowbase = tm * 64;
        Vw = Vbase + (i64)mat * HH;
        srcA = Vw;
        Bsrc = Ubuf + (i64)(mat * 4 + pp2) * 16384;
    }
    for (int e = tid; e < 64 * 32; e += 256) {
        int i = e >> 5, k4 = (e & 31) * 4;
        int col = gidx(k4, gAj, gBj);
        *(float4*)&As[i][k4] = *(const float4*)&srcA[(i64)(rowbase + i) * H + col];
    }
    float acc[4][8] = {};
    __syncthreads();
    for (int k0 = 0; k0 < 128; k0 += 32) {
        for (int e = tid; e < 32 * 32; e += 256) {
            int ka = e >> 5, j4 = (e & 31) * 4;
            *(float4*)&Bs[ka][j4] = *(const float4*)&Bsrc[(i64)(k0 + ka) * 128 + j4];
        }
        __syncthreads();
#pragma unroll 4
        for (int kk = 0; kk < 32; kk++) {
            int k = k0 + kk;
            float av[4];
#pragma unroll
            for (int i = 0; i < 4; i++) av[i] = As[ty * 4 + i][k];
            float4 b0 = *(const float4*)&Bs[kk][tx * 8];
            float4 b1 = *(const float4*)&Bs[kk][tx * 8 + 4];
            float bv[8] = {b0.x, b0.y, b0.z, b0.w, b1.x, b1.y, b1.z, b1.w};
#pragma unroll
            for (int i = 0; i < 4; i++)
#pragma unroll
                for (int j = 0; j < 8; j++) acc[i][j] += av[i] * bv[j];
        }
        __syncthreads();
    }
    if (!vpath) {
#pragma unroll
        for (int i = 0; i < 4; i++) {
            int row = ty * 4 + i;
            float4 v0 = {acc[i][0], acc[i][1], acc[i][2], acc[i][3]};
            float4 v1 = {acc[i][4], acc[i][5], acc[i][6], acc[i][7]};
            *(float4*)&dstT[(i64)row * 128 + tx * 8] = v0;
            *(float4*)&dstT[(i64)row * 128 + tx * 8 + 4] = v1;
        }
    } else {
        int colbase = gidx(tx * 8, gAj, gBj);
#pragma unroll
        for (int i = 0; i < 4; i++) {
            int row = rowbase + ty * 4 + i;
            float4 v0 = {acc[i][0], acc[i][1], acc[i][2], acc[i][3]};
            float4 v1 = {acc[i][4], acc[i][5], acc[i][6], acc[i][7]};
            *(float4*)&Vw[(i64)row * H + colbase] = v0;
            *(float4*)&Vw[(i64)row * H + colbase + 4] = v1;
        }
    }
}

// etB: A_region = UI^T @ Tbuf[region]
__global__ __launch_bounds__(256) void etB_k(float* __restrict__ Abase,
                                             const float* __restrict__ Ubuf,
                                             const float* __restrict__ Tbuf, int r)
{
    __shared__ float As[32][68];
    __shared__ float Bs[32][132];
    int z = blockIdx.x, tid = threadIdx.x;
    int tx = tid & 15, ty = tid >> 4;
    int region = z >> 1, rt = z & 1;
    int mat = region >> 4, pp = region & 15, pri = pp >> 2, prj = pp & 3;
    int gAi = pos7(pri, r), gBi = pos7(7 - pri, r);
    int gAj = pos7(prj, r), gBj = pos7(7 - prj, r);
    const float* UI = Ubuf + (i64)(mat * 4 + pri) * 16384;
    const float* T = Tbuf + (i64)region * 16384;
    float* A = Abase + (i64)mat * HH;
    int outrowbase = (rt ? gBi : gAi) * 64;
    float acc[4][8] = {};
    for (int k0 = 0; k0 < 128; k0 += 32) {
        __syncthreads();
        for (int e = tid; e < 32 * 16; e += 256) {
            int ka = e >> 4, i4 = (e & 15) * 4;
            *(float4*)&As[ka][i4] = *(const float4*)&UI[(i64)(k0 + ka) * 128 + rt * 64 + i4];
        }
        for (int e = tid; e < 32 * 32; e += 256) {
            int ka = e >> 5, j4 = (e & 31) * 4;
            *(float4*)&Bs[ka][j4] = *(const float4*)&T[(i64)(k0 + ka) * 128 + j4];
        }
        __syncthreads();
#pragma unroll 4
        for (int kk = 0; kk < 32; kk++) {
            float4 a = *(const float4*)&As[kk][ty * 4];
            float av[4] = {a.x, a.y, a.z, a.w};
            float4 b0 = *(const float4*)&Bs[kk][tx * 8];
            float4 b1 = *(const float4*)&Bs[kk][tx * 8 + 4];
            float bv[8] = {b0.x, b0.y, b0.z, b0.w, b1.x, b1.y, b1.z, b1.w};
#pragma unroll
            for (int i = 0; i < 4; i++)
#pragma unroll
                for (int j = 0; j < 8; j++) acc[i][j] += av[i] * bv[j];
        }
    }
    int colbase = gidx(tx * 8, gAj, gBj);
#pragma unroll
    for (int i = 0; i < 4; i++) {
        int row = outrowbase + ty * 4 + i;
        float4 v0 = {acc[i][0], acc[i][1], acc[i][2], acc[i][3]};
        float4 v1 = {acc[i][4], acc[i][5], acc[i][6], acc[i][7]};
        *(float4*)&A[(i64)row * H + colbase] = v0;
        *(float4*)&A[(i64)row * H + colbase + 4] = v1;
    }
}

__global__ __launch_bounds__(512) void sort_k(const float* __restrict__ Afin,
                                              float* __restrict__ evals, int* __restrict__ rankbuf)
{
    __shared__ float d[512];
    int mat = blockIdx.x, i = threadIdx.x;
    float li = Afin[(i64)mat * HH + (i64)i * H + i];
    d[i] = li; __syncthreads();
    int cnt = 0;
    for (int j = 0; j < 512; j++) { float lj = d[j]; cnt += (lj < li) || (lj == li && j < i); }
    evals[mat * H + cnt] = li;
    if (mat < 4) rankbuf[mat * H + i] = cnt;
}
__global__ void perm_k(const float* __restrict__ Vfin, const int* __restrict__ rankbuf,
                       float* __restrict__ Vs)
{
    i64 e = (i64)blockIdx.x * 256 + threadIdx.x;
    if (e >= (i64)4 * HH) return;
    int mat = (int)(e / HH); i64 o = e % HH;
    int rrow = (int)(o >> 9), i = (int)(o & 511);
    Vs[(i64)mat * HH + (i64)rrow * H + rankbuf[mat * H + i]] = Vfin[e];
}

// ======================= small (3x3, 1x1) eigens =======================
__device__ void jacobi3(float A[3][3], float V[3][3], bool wantV) {
    if (wantV) for (int r = 0; r < 3; r++) for (int c = 0; c < 3; c++) V[r][c] = (r == c) ? 1.f : 0.f;
    const int PP[3] = {0, 0, 1}, QQ[3] = {1, 2, 2};
    for (int sw = 0; sw < 30; sw++)
        for (int e = 0; e < 3; e++) {
            int p = PP[e], q = QQ[e];
            float apq = A[p][q];
            if (fabsf(apq) < 1e-30f) continue;
            float tau = (A[q][q] - A[p][p]) / (2.f * apq);
            float t = copysignf(1.f, tau) / (fabsf(tau) + sqrtf(1.f + tau * tau));
            float c = 1.f / sqrtf(1.f + t * t), s = t * c;
            for (int k = 0; k < 3; k++) { float x = A[p][k], y = A[q][k]; A[p][k] = c * x - s * y; A[q][k] = s * x + c * y; }
            for (int k = 0; k < 3; k++) { float x = A[k][p], y = A[k][q]; A[k][p] = c * x - s * y; A[k][q] = s * x + c * y; }
            if (wantV) for (int k = 0; k < 3; k++) { float x = V[k][p], y = V[k][q]; V[k][p] = c * x - s * y; V[k][q] = s * x + c * y; }
        }
}

__global__ void small_eig_k(const float* Aom0, const float* S_A0,
                            const float* Abd0, const float* S_Ab0,
                            const float* Bom2, const float* S_B2,
                            const float* Bbd2, const float* S_B2b,
                            float* UA0, float* eA0, float* eAb0, float* eScal)
{
    if (threadIdx.x || blockIdx.x) return;
    float A[3][3], V[3][3];
    for (int r = 0; r < 3; r++) for (int c = 0; c < 3; c++) {
        A[r][c] = DEC * Aom0[r * 3 + c] + (1.f - DEC) * S_A0[r * 3 + c] / (float)NI;
        if (r == c) A[r][c] += DAMP;
    }
    jacobi3(A, V, true);
    int ord[3] = {0, 1, 2};
    for (int i = 0; i < 2; i++) for (int j = 0; j < 2 - i; j++)
        if (A[ord[j]][ord[j]] > A[ord[j + 1]][ord[j + 1]]) { int t = ord[j]; ord[j] = ord[j + 1]; ord[j + 1] = t; }
    for (int k = 0; k < 3; k++) { eA0[k] = A[ord[k]][ord[k]]; for (int r = 0; r < 3; r++) UA0[r * 3 + k] = V[r][ord[k]]; }

    for (int r = 0; r < 3; r++) for (int c = 0; c < 3; c++) {
        A[r][c] = DEC * Abd0[r * 3 + c] + (1.f - DEC) * S_Ab0[r * 3 + c] / (float)NB;
        if (r == c) A[r][c] += DAMP;
    }
    jacobi3(A, V, false);
    int ord2[3] = {0, 1, 2};
    for (int i = 0; i < 2; i++) for (int j = 0; j < 2 - i; j++)
        if (A[ord2[j]][ord2[j]] > A[ord2[j + 1]][ord2[j + 1]]) { int t = ord2[j]; ord2[j] = ord2[j + 1]; ord2[j + 1] = t; }
    for (int k = 0; k < 3; k++) eAb0[k] = A[ord2[k]][ord2[k]];

    eScal[0] = DEC * Bom2[0] + (1.f - DEC) * S_B2[0] / (float)NI + DAMP;
    eScal[1] = DEC * Bbd2[0] + (1.f - DEC) * S_B2b[0] / (float)NB + DAMP;
}

// ======================= preconditioning =======================
__global__ void div2_k(float* P, const float* eG, const float* eA,
                       const float* eGb, const float* eAb, int Mg, int Na)
{
    int e = blockIdx.x * 256 + threadIdx.x;
    if (e >= Mg * Na) return;
    int a = e / Na, b = e % Na;
    P[e] /= (eG[a] * eA[b] + eGb[a] * eAb[b]);
}
__global__ void div1_k(float* v, const float* eG, const float* eGb, int Mg)
{
    int e = blockIdx.x * 256 + threadIdx.x;
    if (e >= Mg) return;
    v[e] /= (eG[e] + eGb[e]);
}
__global__ void div2s_k(float* P, const float* eScal, const float* eA, const float* eAb, int Na)
{
    int e = blockIdx.x * 256 + threadIdx.x;
    if (e >= Na) return;
    P[e] /= (eScal[0] * eA[e] + eScal[1] * eAb[e]);
}
__global__ void scal2_k(const float* g, const float* eScal, float* out)
{
    if (threadIdx.x || blockIdx.x) return;
    out[0] = g[0] / (eScal[0] + eScal[1]);
}

// ======================= params concat helpers =======================
__device__ __forceinline__ float pick6(int e, const float* W0, const float* W1, const float* W2,
                                       const float* b0, const float* b1, const float* b2)
{
    if (e < OFF_W1) return W0[e];
    if (e < OFF_W2) return W1[e - OFF_W1];
    if (e < OFF_B0) return W2[e - OFF_W2];
    if (e < OFF_B1) return b0[e - OFF_B0];
    if (e < OFF_B2) return b1[e - OFF_B1];
    return b2[0];
}
__global__ void mom_k(const float* mw0, const float* mw1, const float* mw2,
                      const float* mb0, const float* mb1, const float* mb2,
                      const float* __restrict__ pcat, float* __restrict__ mcat)
{
    int e = blockIdx.x * 256 + threadIdx.x;
    if (e >= TOT) return;
    mcat[e] = 0.9f * pick6(e, mw0, mw1, mw2, mb0, mb1, mb2) + pcat[e];
}
__global__ void upd_k(const float* W0, const float* W1, const float* W2,
                      const float* b0, const float* b1, const float* b2,
                      const float* __restrict__ mcat, float alpha, const float* alphap,
                      float* __restrict__ out)
{
    int e = blockIdx.x * 256 + threadIdx.x;
    if (e >= TOT) return;
    float a = alphap ? alphap[0] : alpha;
    out[e] = pick6(e, W0, W1, W2, b0, b1, b2) - a * mcat[e];
}
__global__ void argmin_k(const float* lossI, const float* lossB, float* bestA)
{
    if (threadIdx.x || blockIdx.x) return;
    float best = 3.4e38f, ba = 0.01f;
    for (int k = 0; k < 5; k++) {
        float l = 0.5f * (lossI[k] / (float)NI) + 0.5f * (lossB[k] / (float)NB);
        float al = 0.01f * (1.0f / (float)(1 << k));
        if (l < best) { best = l; ba = al; }
    }
    bestA[0] = ba;
}

// ============ line-search mega kernel v2: fused t0, z = alpha ============
template<int LAP>
__global__ __launch_bounds__(256) void lsf2_k(
    const float* __restrict__ X,
    const float* __restrict__ W0, const float* __restrict__ b0,
    const float* __restrict__ W1, const float* __restrict__ b1,
    const float* __restrict__ W2, const float* __restrict__ b2,
    const float* __restrict__ mcat, int nrows, float* __restrict__ part)
{
    __shared__ float As[32][68];
    __shared__ float Bs[32][68];
    __shared__ float wq[32][8];
    __shared__ float Xs[64][4];
    __shared__ float red[64][17];
    int tid = threadIdx.x, tx = tid & 15, ty = tid >> 4;
    int n0 = blockIdx.x * 64, m0 = blockIdx.y * 64;
    float al = 0.01f * (1.0f / (float)(1 << blockIdx.z));
    if (tid < 192) { int n = tid / 3, d = tid - n * 3; Xs[n][d] = X[(i64)(n0 + n) * 3 + d]; }
    float a_t[4][4] = {}, a_g0[4][4] = {}, a_g1[4][4] = {}, a_g2[4][4] = {}, a_l[4][4] = {};
    __syncthreads();
    for (int k0 = 0; k0 < 512; k0 += 32) {
        {
            int n = tid >> 2, kq = (tid & 3) * 4;
            const float* p = &W1[(i64)(m0 + n) * 512 + k0 + kq];
            const float* pm = &mcat[OFF_W1 + (i64)(m0 + n) * 512 + k0 + kq];
            float4 v0 = *(const float4*)p, v1 = *(const float4*)(p + 16);
            float4 m0v = *(const float4*)pm, m1v = *(const float4*)(pm + 16);
            Bs[kq + 0][n] = v0.x - al * m0v.x; Bs[kq + 1][n] = v0.y - al * m0v.y;
            Bs[kq + 2][n] = v0.z - al * m0v.z; Bs[kq + 3][n] = v0.w - al * m0v.w;
            Bs[kq + 16][n] = v1.x - al * m1v.x; Bs[kq + 17][n] = v1.y - al * m1v.y;
            Bs[kq + 18][n] = v1.z - al * m1v.z; Bs[kq + 19][n] = v1.w - al * m1v.w;
        }
        if (tid < 32) {
            int j = k0 + tid;
            float w0 = W0[j * 3]     - al * mcat[j * 3];
            float w1 = W0[j * 3 + 1] - al * mcat[j * 3 + 1];
            float w2 = W0[j * 3 + 2] - al * mcat[j * 3 + 2];
            float bb = b0[j] - al * mcat[OFF_B0 + j];
            wq[tid][0] = w0; wq[tid][1] = w1; wq[tid][2] = w2; wq[tid][3] = bb;
            wq[tid][4] = w0 * w0 + w1 * w1 + w2 * w2;
        }
        __syncthreads();
        {
            int n = tid >> 2, a = tid & 3;
            float x0 = Xs[n][0], x1 = Xs[n][1], x2 = Xs[n][2];
#pragma unroll
            for (int i = 0; i < 8; i++) {
                int k = a + 4 * i;
                float s = x0 * wq[k][0] + x1 * wq[k][1] + x2 * wq[k][2] + wq[k][3];
                As[k][n] = tanhf(s);
            }
        }
        __syncthreads();
#pragma unroll
        for (int ks = 0; ks < 32; ks++) {
            float4 a = *(const float4*)&As[ks][ty * 4];
            float4 b = *(const float4*)&Bs[ks][tx * 4];
            float av[4] = {a.x, a.y, a.z, a.w};
            float bv[4] = {b.x, b.y, b.z, b.w};
            if (LAP) {
                float w0 = wq[ks][0], w1 = wq[ks][1], w2 = wq[ks][2], q0 = wq[ks][4];
                float gv0[4], gv1[4], gv2[4], lv[4];
#pragma unroll
                for (int i = 0; i < 4; i++) {
                    float t = av[i], phi = 1.f - t * t, u = -2.f * t * phi;
                    gv0[i] = phi * w0; gv1[i] = phi * w1; gv2[i] = phi * w2; lv[i] = u * q0;
                }
#pragma unroll
                for (int i = 0; i < 4; i++)
#pragma unroll
                    for (int j = 0; j < 4; j++) {
                        a_t[i][j]  += av[i]  * bv[j];
                        a_g0[i][j] += gv0[i] * bv[j];
                        a_g1[i][j] += gv1[i] * bv[j];
                        a_g2[i][j] += gv2[i] * bv[j];
                        a_l[i][j]  += lv[i]  * bv[j];
                    }
            } else {
#pragma unroll
                for (int i = 0; i < 4; i++)
#pragma unroll
                    for (int j = 0; j < 4; j++) a_t[i][j] += av[i] * bv[j];
            }
        }
        __syncthreads();
    }
    float rowpart[4];
#pragma unroll
    for (int i = 0; i < 4; i++) {
        rowpart[i] = 0.f;
#pragma unroll
        for (int j = 0; j < 4; j++) {
            int m = m0 + tx * 4 + j;
            float s = a_t[i][j] + (b1[m] - al * mcat[OFF_B1 + m]);
            float t1 = tanhf(s);
            float val;
            if (LAP) {
                float phi = 1.f - t1 * t1, u = -2.f * t1 * phi;
                float q = a_g0[i][j] * a_g0[i][j] + a_g1[i][j] * a_g1[i][j] + a_g2[i][j] * a_g2[i][j];
                val = phi * a_l[i][j] + u * q;
            } else val = t1;
            rowpart[i] += val * (W2[m] - al * mcat[OFF_W2 + m]);
        }
    }
#pragma unroll
    for (int i = 0; i < 4; i++) red[ty * 4 + i][tx] = rowpart[i];
    __syncthreads();
    if (tid < 64) {
        float s = 0.f;
#pragma unroll
        for (int x = 0; x < 16; x++) s += red[tid][x];
        if (!LAP && blockIdx.y == 0) s += (b2[0] - al * mcat[OFF_B2]);
        part[((i64)blockIdx.z * 8 + blockIdx.y) * nrows + n0 + tid] = s;
    }
}

__global__ __launch_bounds__(256) void lsred_k(const float* __restrict__ pI,
                                               const float* __restrict__ pB,
                                               const float* __restrict__ Xi,
                                               const float* __restrict__ Xb,
                                               float* __restrict__ lossI,
                                               float* __restrict__ lossB)
{
    __shared__ float red[256];
    int z = blockIdx.x, a = z >> 1, isB = z & 1;
    int rows = isB ? NB : NI;
    const float* src = isB ? (pB + (i64)a * 8 * NB) : (pI + (i64)a * 8 * NI);
    const float* X = isB ? Xb : Xi;
    float acc = 0.f;
    for (int n = threadIdx.x; n < rows; n += 256) {
        float s = 0.f;
#pragma unroll
        for (int t = 0; t < 8; t++) s += src[(i64)t * rows + n];
        const float* x = X + (i64)n * 3;
        float rhs = isB ? (cosf(x[0]) + cosf(x[1]) + cosf(x[2]))
                        : (sinf(x[0]) + sinf(x[1]) + sinf(x[2]));
        float r = s - rhs;
        acc += r * r;
    }
    red[threadIdx.x] = acc; __syncthreads();
    for (int off = 128; off; off >>= 1) {
        if (threadIdx.x < off) red[threadIdx.x] += red[threadIdx.x + off];
        __syncthreads();
    }
    if (threadIdx.x == 0) {
        if (isB) lossB[a] = red[0];
        else lossI[a] = red[0];
    }
}

// ======================= host helpers =======================
template<int MODE>
static inline void g64(hipStream_t st, const float* A, const float* B, float* C,
                       int M, int N, int K) {
    dim3 g((M + 63) / 64, (N + 63) / 64);
    bool fast = (M % 64 == 0) && (N % 64 == 0) && (K % 32 == 0);
    if (fast) gemm64_k<MODE, 0, 0, 1, 0><<<g, 256, 0, st>>>(A, B, nullptr, C, M, N, K, nullptr, nullptr);
    else      gemm64_k<MODE, 0, 0, 0, 0><<<g, 256, 0, st>>>(A, B, nullptr, C, M, N, K, nullptr, nullptr);
}
static inline void g64_bt(hipStream_t st, const float* A, const float* B, const float* bias,
                          float* C, int M, int N, int K) {
    dim3 g((M + 63) / 64, (N + 63) / 64);
    gemm64_k<0, 1, 1, 1, 0><<<g, 256, 0, st>>>(A, B, bias, C, M, N, K, nullptr, nullptr);
}
static inline void g64_aux1(hipStream_t st, const float* A, const float* B, float* C,
                            int M, int N, int K, const float* t0p, float* dst2) {
    dim3 g((M + 63) / 64, (N + 63) / 64);
    gemm64_k<1, 0, 0, 1, 1><<<g, 256, 0, st>>>(A, B, nullptr, C, M, N, K, t0p, dst2);
}
static inline void g64_aux2(hipStream_t st, const float* A, const float* B, float* C,
                            int M, int N, int K, const float* t0p) {
    dim3 g((M + 63) / 64, (N + 63) / 64);
    gemm64_k<1, 0, 0, 1, 2><<<g, 256, 0, st>>>(A, B, nullptr, C, M, N, K, t0p, nullptr);
}
static inline void g_sk(hipStream_t st, const float* A, const float* B, float* dst,
                        int M, int N, int K, float* skbuf) {
    int Ks = ((K / 8) + 31) / 32 * 32;
    if (Ks * 8 < K) Ks += 32;
    dim3 g((M + 63) / 64, (N + 63) / 64, 8);
    bool fast = (M % 64 == 0) && (N % 64 == 0) && (K == Ks * 8);
    if (fast) gemm_tn_sk_k<1><<<g, 256, 0, st>>>(A, B, skbuf, M, N, K, Ks);
    else      gemm_tn_sk_k<0><<<g, 256, 0, st>>>(A, B, skbuf, M, N, K, Ks);
    int cnt = M * N;
    sk_red_k<<<(cnt + 255) / 256, 256, 0, st>>>(dst, skbuf, cnt);
}

extern "C" void kernel_launch(void* const* d_in, const int* in_sizes, int n_in,
                              void* d_out, int out_size, void* d_ws, size_t ws_size,
                              hipStream_t stream)
{
    const float* Xi   = (const float*)d_in[0];
    const float* Xb   = (const float*)d_in[1];
    const float* W0   = (const float*)d_in[2];
    const float* b0   = (const float*)d_in[3];
    const float* Aom0 = (const float*)d_in[4];
    const float* Bom0 = (const float*)d_in[5];
    const float* Abd0 = (const float*)d_in[6];
    const float* Bbd0 = (const float*)d_in[7];
    const float* mw0  = (const float*)d_in[8];
    const float* mb0  = (const float*)d_in[9];
    const float* W1   = (const float*)d_in[10];
    const float* b1   = (const float*)d_in[11];
    const float* Aom1 = (const float*)d_in[12];
    const float* Bom1 = (const float*)d_in[13];
    const float* Abd1 = (const float*)d_in[14];
    const float* Bbd1 = (const float*)d_in[15];
    const float* mw1  = (const float*)d_in[16];
    const float* mb1  = (const float*)d_in[17];
    const float* W2   = (const float*)d_in[18];
    const float* b2   = (const float*)d_in[19];
    const float* Aom2 = (const float*)d_in[20];
    const float* Bom2 = (const float*)d_in[21];
    const float* Abd2 = (const float*)d_in[22];
    const float* Bbd2 = (const float*)d_in[23];
    const float* mw2  = (const float*)d_in[24];
    const float* mb2  = (const float*)d_in[25];

    float* w = (float*)d_ws;
    i64 off = 0;
    auto alloc = [&](i64 n) { float* p = w + off; off += n; return p; };

    const i64 M1 = 1048576;
    float* arena = alloc(15 * M1);
    float* t0c = arena + 0 * M1;
    float* t1c = arena + 1 * M1;
    float* l1c = arena + 2 * M1;
    float* ls1c = arena + 3 * M1;
    float* l2c = arena + 5 * M1;
    float* d1c = arena + 6 * M1;
    float* e1c = arena + 7 * M1;
    float* f1c = arena + 8 * M1;
    float* g1c = arena + 9 * M1;
    float* gs1c = arena + 12 * M1;
    float* skbuf = arena + 4 * M1;
    // eigen views (phase-disjoint: rlog [eig_sub->ubuild], Tbuf [etA->etB])
    float* Aeig = arena + 0 * M1;
    float* Veig = arena + 2 * M1;
    float* Ubuf = arena + 3 * M1;
    float* Vs   = arena + 3 * M1 + 524288;
    float* rlog = arena + 5 * M1;
    float* Tbuf = arena + 8 * M1;
    // precond / LS views
    float* P1 = arena + 8 * M1;
    float* P2 = arena + 8 * M1 + HH;
    float* pI  = arena + 9 * M1;
    float* pB  = arena + 10 * M1;

    float* ri = alloc(NI);
    float* rb = alloc(NB);
    float* zero_base = w + off;
    float* S8   = alloc(8 * (i64)HH);
    float* S_A0 = alloc(9);
    float* S_Ab0 = alloc(9);
    float* S_B2 = alloc(1);
    float* S_B2b = alloc(1);
    float* gW0 = alloc(1536);
    float* gW1 = alloc(HH);
    float* gW2 = alloc(H);
    float* gb0v = alloc(H);
    float* gb1v = alloc(H);
    float* gb2v = alloc(1);
    float* lossI = alloc(5);
    float* lossB = alloc(5);
    i64 zero_count = (w + off) - zero_base;
    float* UA0 = alloc(9);
    float* eA0 = alloc(3);
    float* eAb0 = alloc(3);
    float* eScal = alloc(2);
    float* evals = alloc(4096);
    int*   ranks = (int*)alloc(2048);
    float* pcat = alloc(TOT);
    float* mcat = alloc(TOT);
    float* bestA = alloc(1);
    float* wpart = alloc(3 * 16 * H);
    float* b0part = alloc(8 * 2048);
    if (ws_size < (size_t)off * sizeof(float)) return;

    hipStream_t st = stream;
    zero_k<<<(int)((zero_count + 255) / 256), 256, 0, st>>>(zero_base, zero_count);

    const int EW = (CH * H + 255) / 256;

    // ---------------- interior chunks ----------------
    for (int c = 0; c < 4; c++) {
        const float* Xc = Xi + (i64)c * CH * 3;
        float* ric = ri + (i64)c * CH;
        fwd0_k<1><<<EW, 256, 0, st>>>(Xc, W0, b0, CH, t0c, g1c, l1c);
        g64_bt(st, t0c, W1, b1, t1c, CH, H, H);
        g64<0>(st, g1c, W1, gs1c, 3 * CH, H, H);
        g64<0>(st, l1c, W1, ls1c, CH, H, H);
        lapbwd_k<<<CH, 256, 0, st>>>(t1c, ls1c, gs1c, W2, Xc, 1.f / NI, l2c, f1c, d1c, ric);
        g64_aux1(st, d1c, W1, ls1c, CH, H, H, t0c, e1c);        // bar_l1 + delta0
        {
            WJ wj = {};
            wj.src[0] = l2c; wj.wgt[0] = ric; wj.scale[0] = 1.f / NI; wj.dst[0] = gW2;
            wj.src[1] = f1c; wj.wgt[1] = nullptr; wj.scale[1] = 1.f; wj.dst[1] = gb1v;
            wcolp_k<<<dim3(2, 16, 2), 256, 0, st>>>(wj, CH, wpart);
            wcolr_k<<<dim3(2, 2), 256, 0, st>>>(wj, wpart);
        }
        {   // batched Gram: Bo1, Bo0, Ao1, Ao2
            SkBatch sb = {};
            sb.A[0] = d1c; sb.B[0] = d1c;
            sb.A[1] = e1c; sb.B[1] = e1c;
            sb.A[2] = t0c; sb.B[2] = t0c;
            sb.A[3] = t1c; sb.B[3] = t1c;
            sb.Ks = 1024;
            for (int z = 0; z < 8; z++) { sb.job_of_z[z] = z >> 1; sb.kb_of_z[z] = (z & 1) * 1024; }
            skb_k<<<dim3(8, 8, 8), 256, 0, st>>>(sb, skbuf);
            RedJ rj = {};
            rj.dst[0] = S8 + 2 * (i64)HH; rj.dst[1] = S8 + 0 * (i64)HH;
            rj.dst[2] = S8 + 1 * (i64)HH; rj.dst[3] = S8 + 3 * (i64)HH;
            rj.off[0] = 0; rj.off[1] = 2; rj.off[2] = 4; rj.off[3] = 6; rj.off[4] = 8;
            skred_k<<<dim3(1024, 4), 256, 0, st>>>(rj, skbuf);
        }
        {   // batched gW1
            SkBatch sb = {};
            sb.A[0] = f1c;  sb.B[0] = t0c;
            sb.A[1] = gs1c; sb.B[1] = g1c;
            sb.A[2] = d1c;  sb.B[2] = l1c;
            sb.Ks = 2048;
            int jo[5] = {0, 1, 1, 1, 2};
            int kb[5] = {0, 0, 2048, 4096, 0};
            for (int z = 0; z < 5; z++) { sb.job_of_z[z] = jo[z]; sb.kb_of_z[z] = kb[z]; }
            skb_k<<<dim3(8, 8, 5), 256, 0, st>>>(sb, skbuf);
            RedJ rj = {};
            rj.dst[0] = gW1;
            rj.off[0] = 0; rj.off[1] = 5;
            skred_k<<<dim3(1024, 1), 256, 0, st>>>(rj, skbuf);
        }
        g64<1>(st, f1c, W1, l2c, CH, H, H);                     // bar_t0
        g64<1>(st, gs1c, W1, g1c, 3 * CH, H, H);                // bar_g1
        bwd0p_k<<<dim3(2, 8), 256, 0, st>>>(Xc, CH, W0, t0c, l2c, ls1c, g1c, b0part);
        bwd0red_k<<<8, 256, 0, st>>>(b0part, gW0, gb0v);
    }

    // ---------------- boundary ----------------
    fwd0_k<0><<<(NB * H + 255) / 256, 256, 0, st>>>(Xb, W0, b0, NB, t0c, nullptr, nullptr);
    g64_bt(st, t0c, W1, b1, t1c, NB, H, H);
    bnd_fin_k<<<NB / 4, 256, 0, st>>>(t1c, W2, b2, Xb, NB, rb);
    dualred_k<<<2, 256, 0, st>>>(ri, rb, S_B2, gb2v, S_B2b);
    delta1_k<<<(NB * H + 255) / 256, 256, 0, st>>>(t1c, rb, W2, 1.f / NB, d1c, NB);
    {
        SkBatch sb = {};
        sb.A[0] = d1c; sb.B[0] = d1c;
        sb.A[1] = t0c; sb.B[1] = t0c;
        sb.A[2] = t1c; sb.B[2] = t1c;
        sb.Ks = 1024;
        for (int z = 0; z < 6; z++) { sb.job_of_z[z] = z >> 1; sb.kb_of_z[z] = (z & 1) * 1024; }
        skb_k<<<dim3(8, 8, 6), 256, 0, st>>>(sb, skbuf);
        RedJ rj = {};
        rj.dst[0] = S8 + 6 * (i64)HH; rj.dst[1] = S8 + 5 * (i64)HH; rj.dst[2] = S8 + 7 * (i64)HH;
        rj.off[0] = 0; rj.off[1] = 2; rj.off[2] = 4; rj.off[3] = 6;
        skred_k<<<dim3(1024, 3), 256, 0, st>>>(rj, skbuf);
    }
    g_sk(st, d1c, t0c, gW1, H, H, NB, skbuf);
    g64_aux2(st, d1c, W1, e1c, NB, H, H, t0c);
    {
        WJ wj = {};
        wj.src[0] = t1c; wj.wgt[0] = rb; wj.scale[0] = 1.f / NB; wj.dst[0] = gW2;
        wj.src[1] = d1c; wj.wgt[1] = nullptr; wj.scale[1] = 1.f; wj.dst[1] = gb1v;
        wj.src[2] = e1c; wj.wgt[2] = nullptr; wj.scale[2] = 1.f; wj.dst[2] = gb0v;
        wcolp_k<<<dim3(2, 16, 3), 256, 0, st>>>(wj, NB, wpart);
        wcolr_k<<<dim3(2, 3), 256, 0, st>>>(wj, wpart);
    }
    g_sk(st, e1c, e1c, S8 + 4 * (i64)HH, H, H, NB, skbuf);
    g_sk(st, e1c, Xb, gW0, H, 3, NB, skbuf);
    xtx3b_k<<<2, 256, 0, st>>>(Xi, Xb, S_A0, S_Ab0);

    // ---------------- factor build + eigensolve ----------------
    {
        P8 mom = {};
        mom.p[0] = Bom0; mom.p[1] = Aom1; mom.p[2] = Bom1; mom.p[3] = Aom2;
        mom.p[4] = Bbd0; mom.p[5] = Abd1; mom.p[6] = Bbd1; mom.p[7] = Abd2;
        fbuildb_k<<<dim3(1024, 8), 256, 0, st>>>(mom, S8, Aeig);
    }
    identv_k<<<(int)((4 * (i64)HH + 255) / 256), 256, 0, st>>>(Veig, 4 * (i64)HH);
    small_eig_k<<<1, 1, 0, st>>>(Aom0, S_A0, Abd0, S_Ab0, Bom2, S_B2, Bbd2, S_B2b,
                                 UA0, eA0, eAb0, eScal);

    for (int sw = 0; sw < SOUTER; sw++)
        for (int r = 0; r < 7; r++) {
            eig_sub_k<<<dim3(4, 8), 1024, 0, st>>>(Aeig, rlog, r);
            ubuild_k<<<dim3(8, 32), 256, 0, st>>>(rlog, Ubuf);
            etA_k<<<384, 256, 0, st>>>(Aeig, Veig, Ubuf, Tbuf, r);
            etB_k<<<256, 256, 0, st>>>(Aeig, Ubuf, Tbuf, r);
        }
    sort_k<<<8, 512, 0, st>>>(Aeig, evals, ranks);
    perm_k<<<(int)((4 * (i64)HH + 255) / 256), 256, 0, st>>>(Veig, ranks, Vs);

    // ---------------- preconditioning ----------------
    g64<2>(st, Vs + 0 * (i64)HH, gW0, P1, H, 3, H);
    g64<1>(st, P1, UA0, P2, H, 3, 3);
    div2_k<<<6, 256, 0, st>>>(P2, evals + 0 * H, eA0, evals + 4 * H, eAb0, H, 3);
    g64<1>(st, Vs + 0 * (i64)HH, P2, P1, H, 3, H);
    g64<0>(st, P1, UA0, pcat + 0, H, 3, 3);
    g64<2>(st, Vs + 0 * (i64)HH, gb0v, P2, H, 1, H);
    div1_k<<<2, 256, 0, st>>>(P2, evals + 0 * H, evals + 4 * H, H);
    g64<1>(st, Vs + 0 * (i64)HH, P2, pcat + OFF_B0, H, 1, H);

    g64<2>(st, Vs + 2 * (i64)HH, gW1, P1, H, H, H);
    g64<1>(st, P1, Vs + 1 * (i64)HH, P2, H, H, H);
    div2_k<<<1024, 256, 0, st>>>(P2, evals + 2 * H, evals + 1 * H, evals + 6 * H, evals + 5 * H, H, H);
    g64<1>(st, Vs + 2 * (i64)HH, P2, P1, H, H, H);
    g64<0>(st, P1, Vs + 1 * (i64)HH, pcat + OFF_W1, H, H, H);
    g64<2>(st, Vs + 2 * (i64)HH, gb1v, P2, H, 1, H);
    div1_k<<<2, 256, 0, st>>>(P2, evals + 2 * H, evals + 6 * H, H);
    g64<1>(st, Vs + 2 * (i64)HH, P2, pcat + OFF_B1, H, 1, H);

    g64<1>(st, gW2, Vs + 3 * (i64)HH, P2, 1, H, H);
    div2s_k<<<2, 256, 0, st>>>(P2, eScal, evals + 3 * H, evals + 7 * H, H);
    g64<0>(st, P2, Vs + 3 * (i64)HH, pcat + OFF_W2, 1, H, H);
    scal2_k<<<1, 1, 0, st>>>(gb2v, eScal, pcat + OFF_B2);

    // ---------------- momentum ----------------
    mom_k<<<(TOT + 255) / 256, 256, 0, st>>>(mw0, mw1, mw2, mb0, mb1, mb2, pcat, mcat);

    // ---------------- line search: 2 z-batched launches ----------------
    lsf2_k<1><<<dim3(NI / 64, 8, 5), 256, 0, st>>>(Xi, W0, b0, W1, b1, W2, b2, mcat, NI, pI);
    lsf2_k<0><<<dim3(NB / 64, 8, 5), 256, 0, st>>>(Xb, W0, b0, W1, b1, W2, b2, mcat, NB, pB);
    lsred_k<<<10, 256, 0, st>>>(pI, pB, Xi, Xb, lossI, lossB);
    argmin_k<<<1, 1, 0, st>>>(lossI, lossB, bestA);
    upd_k<<<(TOT + 255) / 256, 256, 0, st>>>(W0, W1, W2, b0, b1, b2, mcat, 0.f, bestA,
                                             (float*)d_out);
}

// Round 11
// 7416.852 us; speedup vs baseline: 3.0916x; 1.3421x over previous
//
#include <hip/hip_runtime.h>
#include <cmath>

typedef long long i64;

#define NI 8192
#define NB 2048
#define CH 2048
#define H  512
#define HH 262144
#define TOT 265217
#define OFF_W1 1536
#define OFF_W2 263680
#define OFF_B0 264192
#define OFF_B1 264704
#define OFF_B2 265216
#define DAMP 1e-3f
#define DEC  0.95f
#define INNER 1
#define SOUTER 1
#define STEPS (INNER * 127)

__device__ __forceinline__ int imin(int a, int b) { return a < b ? a : b; }

// ======================= 64x64 GEMM, K-tile 32 =======================
template<int MODE, int BIAS, int TANH_, int FAST, int AUX>
__global__ __launch_bounds__(256) void gemm64_k(
    const float* __restrict__ A, const float* __restrict__ B,
    const float* __restrict__ bias, float* __restrict__ C,
    int M, int N, int K, const float* __restrict__ t0p, float* __restrict__ dst2)
{
    __shared__ float As[32][68];
    __shared__ float Bs[32][68];
    int tid = threadIdx.x;
    int tx = tid & 15, ty = tid >> 4;
    int m0 = blockIdx.x * 64, n0 = blockIdx.y * 64;
    float acc[4][4] = {};
    for (int k0 = 0; k0 < K; k0 += 32) {
        if (MODE == 0 || MODE == 1) {
            int m = tid >> 2, kq = (tid & 3) * 4;
            if (FAST) {
                const float* Ap = &A[(i64)(m0 + m) * K + k0 + kq];
                float4 v0 = *(const float4*)Ap;
                float4 v1 = *(const float4*)(Ap + 16);
                As[kq + 0][m] = v0.x; As[kq + 1][m] = v0.y;
                As[kq + 2][m] = v0.z; As[kq + 3][m] = v0.w;
                As[kq + 16][m] = v1.x; As[kq + 17][m] = v1.y;
                As[kq + 18][m] = v1.z; As[kq + 19][m] = v1.w;
            } else {
                int mm = m0 + m;
#pragma unroll
                for (int h = 0; h < 32; h += 16)
#pragma unroll
                    for (int i = 0; i < 4; i++) {
                        int kk = k0 + h + kq + i;
                        As[h + kq + i][m] = (mm < M && kk < K) ? A[(i64)mm * K + kk] : 0.f;
                    }
            }
        } else {
            int k = tid >> 4, mq = (tid & 15) * 4;
            if (FAST) {
                *(float4*)&As[k][mq]      = *(const float4*)&A[(i64)(k0 + k) * M + m0 + mq];
                *(float4*)&As[k + 16][mq] = *(const float4*)&A[(i64)(k0 + k + 16) * M + m0 + mq];
            } else {
#pragma unroll
                for (int h = 0; h < 32; h += 16) {
                    int kk = k0 + k + h;
#pragma unroll
                    for (int i = 0; i < 4; i++) {
                        int mm = m0 + mq + i;
                        As[k + h][mq + i] = (kk < K && mm < M) ? A[(i64)kk * M + mm] : 0.f;
                    }
                }
            }
        }
        if (MODE == 0) {
            int n = tid >> 2, kq = (tid & 3) * 4;
            if (FAST) {
                const float* Bp = &B[(i64)(n0 + n) * K + k0 + kq];
                float4 v0 = *(const float4*)Bp;
                float4 v1 = *(const float4*)(Bp + 16);
                Bs[kq + 0][n] = v0.x; Bs[kq + 1][n] = v0.y;
                Bs[kq + 2][n] = v0.z; Bs[kq + 3][n] = v0.w;
                Bs[kq + 16][n] = v1.x; Bs[kq + 17][n] = v1.y;
                Bs[kq + 18][n] = v1.z; Bs[kq + 19][n] = v1.w;
            } else {
                int nn = n0 + n;
#pragma unroll
                for (int h = 0; h < 32; h += 16)
#pragma unroll
                    for (int i = 0; i < 4; i++) {
                        int kk = k0 + h + kq + i;
                        Bs[h + kq + i][n] = (nn < N && kk < K) ? B[(i64)nn * K + kk] : 0.f;
                    }
            }
        } else {
            int k = tid >> 4, nq = (tid & 15) * 4;
            if (FAST) {
                *(float4*)&Bs[k][nq]      = *(const float4*)&B[(i64)(k0 + k) * N + n0 + nq];
                *(float4*)&Bs[k + 16][nq] = *(const float4*)&B[(i64)(k0 + k + 16) * N + n0 + nq];
            } else {
#pragma unroll
                for (int h = 0; h < 32; h += 16) {
                    int kk = k0 + k + h;
#pragma unroll
                    for (int i = 0; i < 4; i++) {
                        int nn = n0 + nq + i;
                        Bs[k + h][nq + i] = (kk < K && nn < N) ? B[(i64)kk * N + nn] : 0.f;
                    }
                }
            }
        }
        __syncthreads();
#pragma unroll
        for (int ks = 0; ks < 32; ks++) {
            float4 a = *(const float4*)&As[ks][ty * 4];
            float4 b = *(const float4*)&Bs[ks][tx * 4];
            float av[4] = {a.x, a.y, a.z, a.w};
            float bv[4] = {b.x, b.y, b.z, b.w};
#pragma unroll
            for (int i = 0; i < 4; i++)
#pragma unroll
                for (int j = 0; j < 4; j++) acc[i][j] += av[i] * bv[j];
        }
        __syncthreads();
    }
#pragma unroll
    for (int i = 0; i < 4; i++) {
        int m = m0 + ty * 4 + i;
        if (!FAST && m >= M) continue;
        if (FAST) {
            float4 vc, v2;
            float* pc = (float*)&vc; float* p2 = (float*)&v2;
            float4 t0v;
            if (AUX) t0v = *(const float4*)&t0p[(i64)m * N + n0 + tx * 4];
            const float* t0a = (const float*)&t0v;
#pragma unroll
            for (int j = 0; j < 4; j++) {
                float t = acc[i][j];
                if (BIAS) t += bias[n0 + tx * 4 + j];
                if (TANH_) t = tanhf(t);
                if (AUX == 1) { pc[j] = t; p2[j] = (1.f - t0a[j] * t0a[j]) * t; }
                else if (AUX == 2) { pc[j] = (1.f - t0a[j] * t0a[j]) * t; }
                else pc[j] = t;
            }
            *(float4*)&C[(i64)m * N + n0 + tx * 4] = vc;
            if (AUX == 1) *(float4*)&dst2[(i64)m * N + n0 + tx * 4] = v2;
        } else {
#pragma unroll
            for (int j = 0; j < 4; j++) {
                int n = n0 + tx * 4 + j;
                if (n >= N) continue;
                float t = acc[i][j];
                if (BIAS) t += bias[n];
                if (TANH_) t = tanhf(t);
                if (AUX) {
                    float t0v = t0p[(i64)m * N + n];
                    if (AUX == 1) { C[(i64)m * N + n] = t; dst2[(i64)m * N + n] = (1.f - t0v * t0v) * t; }
                    else C[(i64)m * N + n] = (1.f - t0v * t0v) * t;
                } else C[(i64)m * N + n] = t;
            }
        }
    }
}

// single split-K TN (slow/odd shapes)
template<int FAST>
__global__ __launch_bounds__(256) void gemm_tn_sk_k(
    const float* __restrict__ A, const float* __restrict__ B,
    float* __restrict__ P, int M, int N, int K, int Ks)
{
    __shared__ float As[32][68];
    __shared__ float Bs[32][68];
    int tid = threadIdx.x;
    int tx = tid & 15, ty = tid >> 4;
    int m0 = blockIdx.x * 64, n0 = blockIdx.y * 64, s = blockIdx.z;
    int kb = s * Ks, ke = imin(K, kb + Ks);
    float acc[4][4] = {};
    for (int k0 = kb; k0 < ke; k0 += 32) {
        int k = tid >> 4, q = (tid & 15) * 4;
        if (FAST) {
            *(float4*)&As[k][q]      = *(const float4*)&A[(i64)(k0 + k) * M + m0 + q];
            *(float4*)&As[k + 16][q] = *(const float4*)&A[(i64)(k0 + k + 16) * M + m0 + q];
            *(float4*)&Bs[k][q]      = *(const float4*)&B[(i64)(k0 + k) * N + n0 + q];
            *(float4*)&Bs[k + 16][q] = *(const float4*)&B[(i64)(k0 + k + 16) * N + n0 + q];
        } else {
#pragma unroll
            for (int h = 0; h < 32; h += 16) {
                int kk = k0 + k + h;
#pragma unroll
                for (int i = 0; i < 4; i++) {
                    int mm = m0 + q + i, nn = n0 + q + i;
                    As[k + h][q + i] = (kk < ke && mm < M) ? A[(i64)kk * M + mm] : 0.f;
                    Bs[k + h][q + i] = (kk < ke && nn < N) ? B[(i64)kk * N + nn] : 0.f;
                }
            }
        }
        __syncthreads();
#pragma unroll
        for (int ks = 0; ks < 32; ks++) {
            float4 a = *(const float4*)&As[ks][ty * 4];
            float4 b = *(const float4*)&Bs[ks][tx * 4];
            float av[4] = {a.x, a.y, a.z, a.w};
            float bv[4] = {b.x, b.y, b.z, b.w};
#pragma unroll
            for (int i = 0; i < 4; i++)
#pragma unroll
                for (int j = 0; j < 4; j++) acc[i][j] += av[i] * bv[j];
        }
        __syncthreads();
    }
    float* Po = P + (i64)s * M * N;
#pragma unroll
    for (int i = 0; i < 4; i++) {
        int m = m0 + ty * 4 + i;
        if (m >= M) continue;
#pragma unroll
        for (int j = 0; j < 4; j++) {
            int n = n0 + tx * 4 + j;
            if (n >= N) continue;
            Po[(i64)m * N + n] = acc[i][j];
        }
    }
}
__global__ void sk_red_k(float* __restrict__ dst, const float* __restrict__ P, int cnt)
{
    int e = blockIdx.x * 256 + threadIdx.x;
    if (e >= cnt) return;
    float s = 0.f;
#pragma unroll
    for (int z = 0; z < 8; z++) s += P[(i64)z * cnt + e];
    dst[e] += s;
}

// ======== batched TN Gram/grad GEMMs (M=N=512, fast path only) ========
struct SkBatch {
    const float* A[5]; const float* B[5];
    int job_of_z[8];
    int kb_of_z[8];
    int Ks;
};
__global__ __launch_bounds__(256) void skb_k(SkBatch sb, float* __restrict__ P)
{
    __shared__ float As[32][68];
    __shared__ float Bs[32][68];
    int tid = threadIdx.x;
    int tx = tid & 15, ty = tid >> 4;
    int m0 = blockIdx.x * 64, n0 = blockIdx.y * 64, z = blockIdx.z;
    int j = sb.job_of_z[z];
    const float* A = sb.A[j]; const float* B = sb.B[j];
    int kb = sb.kb_of_z[z], ke = kb + sb.Ks;
    float acc[4][4] = {};
    for (int k0 = kb; k0 < ke; k0 += 32) {
        int k = tid >> 4, q = (tid & 15) * 4;
        *(float4*)&As[k][q]      = *(const float4*)&A[(i64)(k0 + k) * H + m0 + q];
        *(float4*)&As[k + 16][q] = *(const float4*)&A[(i64)(k0 + k + 16) * H + m0 + q];
        *(float4*)&Bs[k][q]      = *(const float4*)&B[(i64)(k0 + k) * H + n0 + q];
        *(float4*)&Bs[k + 16][q] = *(const float4*)&B[(i64)(k0 + k + 16) * H + n0 + q];
        __syncthreads();
#pragma unroll
        for (int ks = 0; ks < 32; ks++) {
            float4 a = *(const float4*)&As[ks][ty * 4];
            float4 b = *(const float4*)&Bs[ks][tx * 4];
            float av[4] = {a.x, a.y, a.z, a.w};
            float bv[4] = {b.x, b.y, b.z, b.w};
#pragma unroll
            for (int i = 0; i < 4; i++)
#pragma unroll
                for (int jj = 0; jj < 4; jj++) acc[i][jj] += av[i] * bv[jj];
        }
        __syncthreads();
    }
    float* Po = P + (i64)z * HH;
#pragma unroll
    for (int i = 0; i < 4; i++) {
        int m = m0 + ty * 4 + i;
#pragma unroll
        for (int jj = 0; jj < 4; jj++)
            Po[(i64)m * H + n0 + tx * 4 + jj] = acc[i][jj];
    }
}
struct RedJ { float* dst[4]; int off[5]; };
__global__ void skred_k(RedJ rj, const float* __restrict__ P)
{
    int e = blockIdx.x * 256 + threadIdx.x;
    int j = blockIdx.y;
    if (e >= HH) return;
    float s = 0.f;
    for (int z = rj.off[j]; z < rj.off[j + 1]; z++) s += P[(i64)z * HH + e];
    rj.dst[j][e] += s;
}

// ======================= elementwise / fused =======================
__global__ void zero_k(float* p, i64 n) {
    i64 e = (i64)blockIdx.x * 256 + threadIdx.x;
    if (e < n) p[e] = 0.f;
}

template<int FULL>
__global__ __launch_bounds__(256) void fwd0_k(
    const float* __restrict__ X, const float* __restrict__ W0,
    const float* __restrict__ b0, int rows,
    float* __restrict__ t0c, float* __restrict__ g1c, float* __restrict__ l1c)
{
    int e = blockIdx.x * 256 + threadIdx.x;
    if (e >= rows * H) return;
    int n = e >> 9, j = e & 511;
    const float* x = X + (i64)n * 3;
    float w0 = W0[j * 3 + 0], w1 = W0[j * 3 + 1], w2 = W0[j * 3 + 2];
    float s = x[0] * w0 + x[1] * w1 + x[2] * w2 + b0[j];
    float t = tanhf(s);
    t0c[e] = t;
    if (FULL) {
        float phi = 1.f - t * t;
        float u = -2.f * t * phi;
        float Q0 = w0 * w0 + w1 * w1 + w2 * w2;
        l1c[e] = u * Q0;
        i64 base = ((i64)n * 3) * H + j;
        g1c[base] = phi * w0;
        g1c[base + H] = phi * w1;
        g1c[base + 2 * H] = phi * w2;
    }
}

// fused lapfin + bwd_mid: per-row block; q kept in regs
__global__ __launch_bounds__(256) void lapbwd_k(
    const float* __restrict__ t1c, const float* __restrict__ ls1c,
    float* __restrict__ gs1c, const float* __restrict__ W2,
    const float* __restrict__ X, float invN,
    float* __restrict__ l2c, float* __restrict__ f1c, float* __restrict__ d1c,
    float* __restrict__ ri_out)
{
    __shared__ float red[4];
    __shared__ float riS;
    int n = blockIdx.x;
    int tid = threadIdx.x;
    float tv[2], phiv[2], uv[2], qv[2], lsv[2], g0v[2], g1v[2], g2v[2], w2v[2];
    float part = 0.f;
#pragma unroll
    for (int h = 0; h < 2; h++) {
        int m = tid + h * 256;
        i64 e = (i64)n * H + m;
        i64 b = ((i64)n * 3) * H + m;
        float g0 = gs1c[b], g1 = gs1c[b + H], g2 = gs1c[b + 2 * H];
        float q = g0 * g0 + g1 * g1 + g2 * g2;
        float t = t1c[e], phi = 1.f - t * t, u = -2.f * t * phi;
        float ls = ls1c[e];
        float l2 = phi * ls + u * q;
        l2c[e] = l2;
        part += l2 * W2[m];
        tv[h] = t; phiv[h] = phi; uv[h] = u; qv[h] = q; lsv[h] = ls;
        g0v[h] = g0; g1v[h] = g1; g2v[h] = g2; w2v[h] = W2[m];
    }
    for (int off = 32; off; off >>= 1) part += __shfl_down(part, off, 64);
    if ((tid & 63) == 0) red[tid >> 6] = part;
    __syncthreads();
    if (tid == 0) {
        float p = red[0] + red[1] + red[2] + red[3];
        const float* x = X + (i64)n * 3;
        float r = p - (sinf(x[0]) + sinf(x[1]) + sinf(x[2]));
        ri_out[n] = r;
        riS = r;
    }
    __syncthreads();
    float ri = riS;
#pragma unroll
    for (int h = 0; h < 2; h++) {
        int m = tid + h * 256;
        i64 e = (i64)n * H + m;
        i64 b = ((i64)n * 3) * H + m;
        float t = tv[h], phi = phiv[h], u = uv[h];
        float bl2 = ri * invN * w2v[h];
        f1c[e] = bl2 * (u * lsv[h] + (6.f * t * t - 2.f) * phi * qv[h]);
        d1c[e] = phi * bl2;
        float sc = 2.f * u * bl2;
        gs1c[b] = g0v[h] * sc; gs1c[b + H] = g1v[h] * sc; gs1c[b + 2 * H] = g2v[h] * sc;
    }
}

__global__ __launch_bounds__(256) void bnd_fin_k(
    const float* __restrict__ tb1, const float* __restrict__ W2,
    const float* __restrict__ b2, const float* __restrict__ X, int rows,
    float* __restrict__ rb_out)
{
    int wave = threadIdx.x >> 6, lane = threadIdx.x & 63;
    int n = blockIdx.x * 4 + wave;
    if (n >= rows) return;
    float p = 0.f;
    for (int m = lane; m < H; m += 64) p += tb1[(i64)n * H + m] * W2[m];
    for (int off = 32; off; off >>= 1) p += __shfl_down(p, off, 64);
    if (lane == 0) {
        const float* x = X + (i64)n * 3;
        rb_out[n] = p + b2[0] - (cosf(x[0]) + cosf(x[1]) + cosf(x[2]));
    }
}

// weighted column-sum jobs
struct WJ { const float* src[3]; const float* wgt[3]; float scale[3]; float* dst[3]; };
__global__ void wcolp_k(WJ wj, int rows, float* __restrict__ part)
{
    int m = blockIdx.x * 256 + threadIdx.x;
    int g = blockIdx.y, z = blockIdx.z;
    if (m >= H) return;
    const float* src = wj.src[z]; const float* w = wj.wgt[z];
    int per = (rows + 15) / 16;
    int n0 = g * per, n1 = imin(rows, n0 + per);
    float s = 0.f;
    for (int n = n0; n < n1; n++) {
        float ww = w ? w[n] : 1.f;
        s += ww * src[(i64)n * H + m];
    }
    part[(i64)(z * 16 + g) * H + m] = s;
}
__global__ void wcolr_k(WJ wj, const float* __restrict__ part)
{
    int m = blockIdx.x * 256 + threadIdx.x;
    int z = blockIdx.y;
    if (m >= H) return;
    float s = 0.f;
#pragma unroll
    for (int g = 0; g < 16; g++) s += part[(i64)(z * 16 + g) * H + m];
    wj.dst[z][m] += wj.scale[z] * s;
}

__global__ void dualred_k(const float* __restrict__ ri, const float* __restrict__ rb,
                          float* S_B2, float* gb2v, float* S_B2b)
{
    __shared__ float s1[256], s2[256];
    int z = blockIdx.x;
    const float* r = z ? rb : ri;
    int n = z ? NB : NI;
    float a = 0.f, b = 0.f;
    for (int i = threadIdx.x; i < n; i += 256) { float v = r[i]; a += v; b += v * v; }
    s1[threadIdx.x] = a; s2[threadIdx.x] = b; __syncthreads();
    for (int off = 128; off; off >>= 1) {
        if (threadIdx.x < off) { s1[threadIdx.x] += s1[threadIdx.x + off]; s2[threadIdx.x] += s2[threadIdx.x + off]; }
        __syncthreads();
    }
    if (threadIdx.x == 0) {
        float invN = 1.f / n;
        if (z == 0) { S_B2[0] += invN * invN * s2[0]; }
        else { gb2v[0] += invN * s1[0]; S_B2b[0] += invN * invN * s2[0]; }
    }
}

__global__ __launch_bounds__(256) void delta1_k(
    const float* __restrict__ t1c, const float* __restrict__ r,
    const float* __restrict__ W2, float invN, float* __restrict__ d1c, int rows)
{
    int e = blockIdx.x * 256 + threadIdx.x;
    if (e >= rows * H) return;
    int n = e >> 9, m = e & 511;
    float t = t1c[e];
    d1c[e] = (1.f - t * t) * (r[n] * invN) * W2[m];
}

__global__ void bwd0p_k(const float* __restrict__ X, int rows,
                        const float* __restrict__ W0,
                        const float* __restrict__ t0c, const float* __restrict__ bt0,
                        const float* __restrict__ bl1, const float* __restrict__ bg1,
                        float* __restrict__ part)
{
    int j = blockIdx.x * 256 + threadIdx.x;
    int g = blockIdx.y;
    if (j >= H) return;
    int per = (rows + 7) / 8;
    int n0 = g * per, n1 = imin(rows, n0 + per);
    float w0 = W0[j * 3], w1 = W0[j * 3 + 1], w2 = W0[j * 3 + 2];
    float Q0 = w0 * w0 + w1 * w1 + w2 * w2;
    float sW0 = 0, sW1 = 0, sW2 = 0, sUB = 0, sb = 0;
    for (int n = n0; n < n1; n++) {
        i64 e = (i64)n * H + j;
        float t = t0c[e], phi = 1.f - t * t, u = -2.f * t * phi;
        float bt = bt0[e], bl = bl1[e];
        i64 gb = ((i64)n * 3) * H + j;
        float g0 = bg1[gb], g1 = bg1[gb + H], g2 = bg1[gb + 2 * H];
        float bs = bt * phi + bl * (6.f * t * t - 2.f) * phi * Q0
                 + u * (g0 * w0 + g1 * w1 + g2 * w2);
        const float* x = X + (i64)n * 3;
        sW0 += bs * x[0] + phi * g0;
        sW1 += bs * x[1] + phi * g1;
        sW2 += bs * x[2] + phi * g2;
        sUB += u * bl;
        sb += bs;
    }
    float* pg = part + (i64)g * 2048;
    pg[j * 3 + 0] = sW0 + 2.f * w0 * sUB;
    pg[j * 3 + 1] = sW1 + 2.f * w1 * sUB;
    pg[j * 3 + 2] = sW2 + 2.f * w2 * sUB;
    pg[1536 + j] = sb;
}
__global__ void bwd0red_k(const float* __restrict__ part, float* __restrict__ gW0,
                          float* __restrict__ gb0)
{
    int e = blockIdx.x * 256 + threadIdx.x;
    if (e >= 2048) return;
    float s = 0.f;
#pragma unroll
    for (int g = 0; g < 8; g++) s += part[(i64)g * 2048 + e];
    if (e < 1536) gW0[e] += s;
    else gb0[e - 1536] += s;
}

__global__ __launch_bounds__(256) void xtx3b_k(const float* __restrict__ Xi,
                                               const float* __restrict__ Xb,
                                               float* __restrict__ S_A0,
                                               float* __restrict__ S_Ab0)
{
    __shared__ float red[256];
    int z = blockIdx.x;
    const float* X = z ? Xb : Xi;
    int rows = z ? NB : NI;
    float* dst = z ? S_Ab0 : S_A0;
    float s[9] = {};
    for (int n = threadIdx.x; n < rows; n += 256) {
        float x0 = X[(i64)n * 3], x1 = X[(i64)n * 3 + 1], x2 = X[(i64)n * 3 + 2];
        s[0] += x0 * x0; s[1] += x0 * x1; s[2] += x0 * x2;
        s[3] += x1 * x0; s[4] += x1 * x1; s[5] += x1 * x2;
        s[6] += x2 * x0; s[7] += x2 * x1; s[8] += x2 * x2;
    }
    for (int c = 0; c < 9; c++) {
        red[threadIdx.x] = s[c]; __syncthreads();
        for (int off = 128; off; off >>= 1) {
            if (threadIdx.x < off) red[threadIdx.x] += red[threadIdx.x + off];
            __syncthreads();
        }
        if (threadIdx.x == 0) dst[c] += red[0];
        __syncthreads();
    }
}

struct P8 { const float* p[8]; };
__global__ void fbuildb_k(P8 mom, const float* __restrict__ S, float* __restrict__ dst)
{
    int e = blockIdx.x * 256 + threadIdx.x;
    int z = blockIdx.y;
    if (e >= HH) return;
    float invN = (z < 4) ? (1.f / NI) : (1.f / NB);
    float v = DEC * mom.p[z][e] + (1.f - DEC) * invN * S[(i64)z * HH + e];
    if ((e >> 9) == (e & 511)) v += DAMP;
    dst[(i64)z * HH + e] = v;
}
__global__ void identv_k(float* V, i64 count) {
    i64 e = (i64)blockIdx.x * 256 + threadIdx.x;
    if (e >= count) return;
    i64 o = e % HH;
    V[e] = ((o >> 9) == (o & 511)) ? 1.f : 0.f;
}

// ======================= block Jacobi eigensolver =======================
__device__ __forceinline__ int pos7(int k, int r) { return k == 0 ? 0 : 1 + ((k - 1 + r) % 7); }
__device__ __forceinline__ int pos127s(int k, int s) {
    if (k == 0) return 0;
    int v = k - 1 + s;
    return 1 + (v < 127 ? v : v - 127);
}
__device__ __forceinline__ int gidx(int a, int gA, int gB) {
    return (a < 64) ? gA * 64 + a : gB * 64 + (a - 64);
}

// 128x128 subproblem: 1024 threads, incremental pair tracking,
// fused 2x2 transform, 1 barrier/step. Logs (c,s,p,q); reads A only.
__global__ __launch_bounds__(1024) void eig_sub_k(const float* __restrict__ Abase,
                                                  float* __restrict__ rlog, int r)
{
    __shared__ float Sa[128][129];
    __shared__ float Sb[128][129];
    int pr = blockIdx.x, mat = blockIdx.y;
    int gA = pos7(pr, r), gB = pos7(7 - pr, r);
    int tid = threadIdx.x, lane = tid & 63, wv = tid >> 6;  // wv 0..15
    const float* A = Abase + (i64)mat * HH;
    float4* lg = ((float4*)rlog) + (i64)(mat * 4 + pr) * (STEPS * 64);
    for (int e = tid; e < 128 * 128; e += 1024) {
        int a = e >> 7, b = e & 127;
        Sa[a][b] = A[(i64)gidx(a, gA, gB) * H + gidx(b, gA, gB)];
    }
    int pa = pos127s(lane, 0), qa = pos127s(127 - lane, 0);
    int pb[4], qb[4];
    bool pbz[4];
#pragma unroll
    for (int it = 0; it < 4; it++) {
        int bj = wv * 4 + it;
        pb[it] = pos127s(bj, 0);
        qb[it] = pos127s(127 - bj, 0);
        pbz[it] = (bj == 0);
    }
    bool paz = (lane == 0);
    __syncthreads();
    for (int gst = 0; gst < STEPS; ++gst) {
        float (*Scur)[129] = (gst & 1) ? Sb : Sa;
        float (*Snew)[129] = (gst & 1) ? Sa : Sb;
        float app = Scur[pa][pa], aqq = Scur[qa][qa], apq = Scur[pa][qa];
        float c = 1.f, s = 0.f;
        if (fabsf(apq) > 1e-30f) {
            float tau = (aqq - app) / (2.f * apq);
            float t = copysignf(1.f, tau) / (fabsf(tau) + sqrtf(1.f + tau * tau));
            c = 1.f / sqrtf(1.f + t * t); s = t * c;
        }
        if (tid < 64) lg[(i64)gst * 64 + lane] =
            make_float4(c, s, __int_as_float(pa), __int_as_float(qa));
        const float* rowp = &Scur[pa][0];
        const float* rowq = &Scur[qa][0];
        float* nrowp = &Snew[pa][0];
        float* nrowq = &Snew[qa][0];
#pragma unroll
        for (int it = 0; it < 4; it++) {
            int cb = pb[it], db = qb[it];
            float cj = __shfl(c, wv * 4 + it, 64);
            float sj = __shfl(s, wv * 4 + it, 64);
            float m00 = rowp[cb], m01 = rowp[db];
            float m10 = rowq[cb], m11 = rowq[db];
            float t0 = c * m00 - s * m10;
            float t1 = c * m01 - s * m11;
            float t2 = s * m00 + c * m10;
            float t3 = s * m01 + c * m11;
            nrowp[cb] = cj * t0 - sj * t1;
            nrowp[db] = sj * t0 + cj * t1;
            nrowq[cb] = cj * t2 - sj * t3;
            nrowq[db] = sj * t2 + cj * t3;
        }
        pa = paz ? 0 : (pa == 127 ? 1 : pa + 1);
        qa = (qa == 127 ? 1 : qa + 1);
#pragma unroll
        for (int it = 0; it < 4; it++) {
            pb[it] = pbz[it] ? 0 : (pb[it] == 127 ? 1 : pb[it] + 1);
            qb[it] = (qb[it] == 127 ? 1 : qb[it] + 1);
        }
        __syncthreads();
    }
}

__global__ __launch_bounds__(256) void ubuild_k(const float* __restrict__ rlog,
                                                float* __restrict__ Ubuf)
{
    __shared__ float U[16][132];
    __shared__ float4 lb[2][64];
    int sl = blockIdx.x, mp = blockIdx.y;
    int tid = threadIdx.x;
    const float4* lg = ((const float4*)rlog) + (i64)mp * (STEPS * 64);
    int ro0 = sl * 16;
    for (int e = tid; e < 16 * 128; e += 256) {
        int rr = e >> 7, cc = e & 127;
        U[rr][cc] = (ro0 + rr == cc) ? 1.f : 0.f;
    }
    if (tid < 64) lb[0][tid] = lg[tid];
    __syncthreads();
    for (int st = 0; st < STEPS; st++) {
        float4 e4 = lb[st & 1][tid & 63];
        if (tid < 64 && st + 1 < STEPS) lb[(st + 1) & 1][tid] = lg[(i64)(st + 1) * 64 + tid];
        float c = e4.x, s = e4.y;
        int p = __float_as_int(e4.z), q = __float_as_int(e4.w);
        int rch = tid >> 6;
#pragma unroll
        for (int j = 0; j < 4; j++) {
            int rr = rch * 4 + j;
            float x = U[rr][p], y = U[rr][q];
            U[rr][p] = c * x - s * y; U[rr][q] = s * x + c * y;
        }
        __syncthreads();
    }
    float* Uo = Ubuf + (i64)mp * 16384;
    for (int e = tid; e < 16 * 128; e += 256) Uo[(i64)ro0 * 128 + e] = U[e >> 7][e & 127];
}

// etA: z<256: Tbuf[region] = A_region rows @ UJ ; z>=256: V rows (in-place) @ U_pr
__global__ __launch_bounds__(256) void etA_k(const float* __restrict__ Abase,
                                             float* __restrict__ Vbase,
                                             const float* __restrict__ Ubuf,
                                             float* __restrict__ Tbuf, int r)
{
    __shared__ float As[64][132];
    __shared__ float Bs[32][132];
    int z = blockIdx.x, tid = threadIdx.x;
    int tx = tid & 15, ty = tid >> 4;
    bool vpath = (z >= 256);
    const float* srcA; const float* Bsrc;
    float* dstT = nullptr; float* Vw = nullptr;
    int rowbase, gAj, gBj;
    if (!vpath) {
        int region = z >> 1, rt = z & 1;
        int mat = region >> 4, pp = region & 15, pri = pp >> 2, prj = pp & 3;
        int gAi = pos7(pri, r), gBi = pos7(7 - pri, r);
        gAj = pos7(prj, r); gBj = pos7(7 - prj, r);
        rowbase = (rt ? gBi : gAi) * 64;
        srcA = Abase + (i64)mat * HH;
        Bsrc = Ubuf + (i64)(mat * 4 + prj) * 16384;
        dstT = Tbuf + (i64)region * 16384 + (i64)(rt * 64) * 128;
    } else {
        int vz = z - 256;
        int mat = vz >> 5, rest = vz & 31, pp2 = rest >> 3, tm = rest & 7;
        gAj = pos7(pp2, r); gBj = pos7(7 - pp2, r);
        rowbase = tm * 64;
        Vw = Vbase + (i64)mat * HH;
        srcA = Vw;
        Bsrc = Ubuf + (i64)(mat * 4 + pp2) * 16384;
    }
    for (int e = tid; e < 64 * 32; e += 256) {
        int i = e >> 5, k4 = (e & 31) * 4;
        int col = gidx(k4, gAj, gBj);
        *(float4*)&As[i][k4] = *(const float4*)&srcA[(i64)(rowbase + i) * H + col];
    }
    float acc[4][8] = {};
    __syncthreads();
    for (int k0 = 0; k0 < 128; k0 += 32) {
        for (int e = tid; e < 32 * 32; e += 256) {
            int ka = e >> 5, j4 = (e & 31) * 4;
            *(float4*)&Bs[ka][j4] = *(const float4*)&Bsrc[(i64)(k0 + ka) * 128 + j4];
        }
        __syncthreads();
#pragma unroll 4
        for (int kk = 0; kk < 32; kk++) {
            int k = k0 + kk;
            float av[4];
#pragma unroll
            for (int i = 0; i < 4; i++) av[i] = As[ty * 4 + i][k];
            float4 b0 = *(const float4*)&Bs[kk][tx * 8];
            float4 b1 = *(const float4*)&Bs[kk][tx * 8 + 4];
            float bv[8] = {b0.x, b0.y, b0.z, b0.w, b1.x, b1.y, b1.z, b1.w};
#pragma unroll
            for (int i = 0; i < 4; i++)
#pragma unroll
                for (int j = 0; j < 8; j++) acc[i][j] += av[i] * bv[j];
        }
        __syncthreads();
    }
    if (!vpath) {
#pragma unroll
        for (int i = 0; i < 4; i++) {
            int row = ty * 4 + i;
            float4 v0 = {acc[i][0], acc[i][1], acc[i][2], acc[i][3]};
            float4 v1 = {acc[i][4], acc[i][5], acc[i][6], acc[i][7]};
            *(float4*)&dstT[(i64)row * 128 + tx * 8] = v0;
            *(float4*)&dstT[(i64)row * 128 + tx * 8 + 4] = v1;
        }
    } else {
        int colbase = gidx(tx * 8, gAj, gBj);
#pragma unroll
        for (int i = 0; i < 4; i++) {
            int row = rowbase + ty * 4 + i;
            float4 v0 = {acc[i][0], acc[i][1], acc[i][2], acc[i][3]};
            float4 v1 = {acc[i][4], acc[i][5], acc[i][6], acc[i][7]};
            *(float4*)&Vw[(i64)row * H + colbase] = v0;
            *(float4*)&Vw[(i64)row * H + colbase + 4] = v1;
        }
    }
}

// etB: A_region = UI^T @ Tbuf[region]
__global__ __launch_bounds__(256) void etB_k(float* __restrict__ Abase,
                                             const float* __restrict__ Ubuf,
                                             const float* __restrict__ Tbuf, int r)
{
    __shared__ float As[32][68];
    __shared__ float Bs[32][132];
    int z = blockIdx.x, tid = threadIdx.x;
    int tx = tid & 15, ty = tid >> 4;
    int region = z >> 1, rt = z & 1;
    int mat = region >> 4, pp = region & 15, pri = pp >> 2, prj = pp & 3;
    int gAi = pos7(pri, r), gBi = pos7(7 - pri, r);
    int gAj = pos7(prj, r), gBj = pos7(7 - prj, r);
    const float* UI = Ubuf + (i64)(mat * 4 + pri) * 16384;
    const float* T = Tbuf + (i64)region * 16384;
    float* A = Abase + (i64)mat * HH;
    int outrowbase = (rt ? gBi : gAi) * 64;
    float acc[4][8] = {};
    for (int k0 = 0; k0 < 128; k0 += 32) {
        __syncthreads();
        for (int e = tid; e < 32 * 16; e += 256) {
            int ka = e >> 4, i4 = (e & 15) * 4;
            *(float4*)&As[ka][i4] = *(const float4*)&UI[(i64)(k0 + ka) * 128 + rt * 64 + i4];
        }
        for (int e = tid; e < 32 * 32; e += 256) {
            int ka = e >> 5, j4 = (e & 31) * 4;
            *(float4*)&Bs[ka][j4] = *(const float4*)&T[(i64)(k0 + ka) * 128 + j4];
        }
        __syncthreads();
#pragma unroll 4
        for (int kk = 0; kk < 32; kk++) {
            float4 a = *(const float4*)&As[kk][ty * 4];
            float av[4] = {a.x, a.y, a.z, a.w};
            float4 b0 = *(const float4*)&Bs[kk][tx * 8];
            float4 b1 = *(const float4*)&Bs[kk][tx * 8 + 4];
            float bv[8] = {b0.x, b0.y, b0.z, b0.w, b1.x, b1.y, b1.z, b1.w};
#pragma unroll
            for (int i = 0; i < 4; i++)
#pragma unroll
                for (int j = 0; j < 8; j++) acc[i][j] += av[i] * bv[j];
        }
    }
    int colbase = gidx(tx * 8, gAj, gBj);
#pragma unroll
    for (int i = 0; i < 4; i++) {
        int row = outrowbase + ty * 4 + i;
        float4 v0 = {acc[i][0], acc[i][1], acc[i][2], acc[i][3]};
        float4 v1 = {acc[i][4], acc[i][5], acc[i][6], acc[i][7]};
        *(float4*)&A[(i64)row * H + colbase] = v0;
        *(float4*)&A[(i64)row * H + colbase + 4] = v1;
    }
}

__global__ __launch_bounds__(512) void sort_k(const float* __restrict__ Afin,
                                              float* __restrict__ evals, int* __restrict__ rankbuf)
{
    __shared__ float d[512];
    int mat = blockIdx.x, i = threadIdx.x;
    float li = Afin[(i64)mat * HH + (i64)i * H + i];
    d[i] = li; __syncthreads();
    int cnt = 0;
    for (int j = 0; j < 512; j++) { float lj = d[j]; cnt += (lj < li) || (lj == li && j < i); }
    evals[mat * H + cnt] = li;
    if (mat < 4) rankbuf[mat * H + i] = cnt;
}
__global__ void perm_k(const float* __restrict__ Vfin, const int* __restrict__ rankbuf,
                       float* __restrict__ Vs)
{
    i64 e = (i64)blockIdx.x * 256 + threadIdx.x;
    if (e >= (i64)4 * HH) return;
    int mat = (int)(e / HH); i64 o = e % HH;
    int rrow = (int)(o >> 9), i = (int)(o & 511);
    Vs[(i64)mat * HH + (i64)rrow * H + rankbuf[mat * H + i]] = Vfin[e];
}

// ======================= small (3x3, 1x1) eigens =======================
__device__ void jacobi3(float A[3][3], float V[3][3], bool wantV) {
    if (wantV) for (int r = 0; r < 3; r++) for (int c = 0; c < 3; c++) V[r][c] = (r == c) ? 1.f : 0.f;
    const int PP[3] = {0, 0, 1}, QQ[3] = {1, 2, 2};
    for (int sw = 0; sw < 30; sw++)
        for (int e = 0; e < 3; e++) {
            int p = PP[e], q = QQ[e];
            float apq = A[p][q];
            if (fabsf(apq) < 1e-30f) continue;
            float tau = (A[q][q] - A[p][p]) / (2.f * apq);
            float t = copysignf(1.f, tau) / (fabsf(tau) + sqrtf(1.f + tau * tau));
            float c = 1.f / sqrtf(1.f + t * t), s = t * c;
            for (int k = 0; k < 3; k++) { float x = A[p][k], y = A[q][k]; A[p][k] = c * x - s * y; A[q][k] = s * x + c * y; }
            for (int k = 0; k < 3; k++) { float x = A[k][p], y = A[k][q]; A[k][p] = c * x - s * y; A[k][q] = s * x + c * y; }
            if (wantV) for (int k = 0; k < 3; k++) { float x = V[k][p], y = V[k][q]; V[k][p] = c * x - s * y; V[k][q] = s * x + c * y; }
        }
}

__global__ void small_eig_k(const float* Aom0, const float* S_A0,
                            const float* Abd0, const float* S_Ab0,
                            const float* Bom2, const float* S_B2,
                            const float* Bbd2, const float* S_B2b,
                            float* UA0, float* eA0, float* eAb0, float* eScal)
{
    if (threadIdx.x || blockIdx.x) return;
    float A[3][3], V[3][3];
    for (int r = 0; r < 3; r++) for (int c = 0; c < 3; c++) {
        A[r][c] = DEC * Aom0[r * 3 + c] + (1.f - DEC) * S_A0[r * 3 + c] / (float)NI;
        if (r == c) A[r][c] += DAMP;
    }
    jacobi3(A, V, true);
    int ord[3] = {0, 1, 2};
    for (int i = 0; i < 2; i++) for (int j = 0; j < 2 - i; j++)
        if (A[ord[j]][ord[j]] > A[ord[j + 1]][ord[j + 1]]) { int t = ord[j]; ord[j] = ord[j + 1]; ord[j + 1] = t; }
    for (int k = 0; k < 3; k++) { eA0[k] = A[ord[k]][ord[k]]; for (int r = 0; r < 3; r++) UA0[r * 3 + k] = V[r][ord[k]]; }

    for (int r = 0; r < 3; r++) for (int c = 0; c < 3; c++) {
        A[r][c] = DEC * Abd0[r * 3 + c] + (1.f - DEC) * S_Ab0[r * 3 + c] / (float)NB;
        if (r == c) A[r][c] += DAMP;
    }
    jacobi3(A, V, false);
    int ord2[3] = {0, 1, 2};
    for (int i = 0; i < 2; i++) for (int j = 0; j < 2 - i; j++)
        if (A[ord2[j]][ord2[j]] > A[ord2[j + 1]][ord2[j + 1]]) { int t = ord2[j]; ord2[j] = ord2[j + 1]; ord2[j + 1] = t; }
    for (int k = 0; k < 3; k++) eAb0[k] = A[ord2[k]][ord2[k]];

    eScal[0] = DEC * Bom2[0] + (1.f - DEC) * S_B2[0] / (float)NI + DAMP;
    eScal[1] = DEC * Bbd2[0] + (1.f - DEC) * S_B2b[0] / (float)NB + DAMP;
}

// ======================= preconditioning =======================
__global__ void div2_k(float* P, const float* eG, const float* eA,
                       const float* eGb, const float* eAb, int Mg, int Na)
{
    int e = blockIdx.x * 256 + threadIdx.x;
    if (e >= Mg * Na) return;
    int a = e / Na, b = e % Na;
    P[e] /= (eG[a] * eA[b] + eGb[a] * eAb[b]);
}
__global__ void div1_k(float* v, const float* eG, const float* eGb, int Mg)
{
    int e = blockIdx.x * 256 + threadIdx.x;
    if (e >= Mg) return;
    v[e] /= (eG[e] + eGb[e]);
}
__global__ void div2s_k(float* P, const float* eScal, const float* eA, const float* eAb, int Na)
{
    int e = blockIdx.x * 256 + threadIdx.x;
    if (e >= Na) return;
    P[e] /= (eScal[0] * eA[e] + eScal[1] * eAb[e]);
}
__global__ void scal2_k(const float* g, const float* eScal, float* out)
{
    if (threadIdx.x || blockIdx.x) return;
    out[0] = g[0] / (eScal[0] + eScal[1]);
}

// ======================= params concat helpers =======================
__device__ __forceinline__ float pick6(int e, const float* W0, const float* W1, const float* W2,
                                       const float* b0, const float* b1, const float* b2)
{
    if (e < OFF_W1) return W0[e];
    if (e < OFF_W2) return W1[e - OFF_W1];
    if (e < OFF_B0) return W2[e - OFF_W2];
    if (e < OFF_B1) return b0[e - OFF_B0];
    if (e < OFF_B2) return b1[e - OFF_B1];
    return b2[0];
}
__global__ void mom_k(const float* mw0, const float* mw1, const float* mw2,
                      const float* mb0, const float* mb1, const float* mb2,
                      const float* __restrict__ pcat, float* __restrict__ mcat)
{
    int e = blockIdx.x * 256 + threadIdx.x;
    if (e >= TOT) return;
    mcat[e] = 0.9f * pick6(e, mw0, mw1, mw2, mb0, mb1, mb2) + pcat[e];
}
__global__ void upd_k(const float* W0, const float* W1, const float* W2,
                      const float* b0, const float* b1, const float* b2,
                      const float* __restrict__ mcat, float alpha, const float* alphap,
                      float* __restrict__ out)
{
    int e = blockIdx.x * 256 + threadIdx.x;
    if (e >= TOT) return;
    float a = alphap ? alphap[0] : alpha;
    out[e] = pick6(e, W0, W1, W2, b0, b1, b2) - a * mcat[e];
}
__global__ void argmin_k(const float* lossI, const float* lossB, float* bestA)
{
    if (threadIdx.x || blockIdx.x) return;
    float best = 3.4e38f, ba = 0.01f;
    for (int k = 0; k < 5; k++) {
        float l = 0.5f * (lossI[k] / (float)NI) + 0.5f * (lossB[k] / (float)NB);
        float al = 0.01f * (1.0f / (float)(1 << k));
        if (l < best) { best = l; ba = al; }
    }
    bestA[0] = ba;
}

// ============ line-search mega kernel v2: fused t0, z = alpha ============
template<int LAP>
__global__ __launch_bounds__(256) void lsf2_k(
    const float* __restrict__ X,
    const float* __restrict__ W0, const float* __restrict__ b0,
    const float* __restrict__ W1, const float* __restrict__ b1,
    const float* __restrict__ W2, const float* __restrict__ b2,
    const float* __restrict__ mcat, int nrows, float* __restrict__ part)
{
    __shared__ float As[32][68];
    __shared__ float Bs[32][68];
    __shared__ float wq[32][8];
    __shared__ float Xs[64][4];
    __shared__ float red[64][17];
    int tid = threadIdx.x, tx = tid & 15, ty = tid >> 4;
    int n0 = blockIdx.x * 64, m0 = blockIdx.y * 64;
    float al = 0.01f * (1.0f / (float)(1 << blockIdx.z));
    if (tid < 192) { int n = tid / 3, d = tid - n * 3; Xs[n][d] = X[(i64)(n0 + n) * 3 + d]; }
    float a_t[4][4] = {}, a_g0[4][4] = {}, a_g1[4][4] = {}, a_g2[4][4] = {}, a_l[4][4] = {};
    __syncthreads();
    for (int k0 = 0; k0 < 512; k0 += 32) {
        {
            int n = tid >> 2, kq = (tid & 3) * 4;
            const float* p = &W1[(i64)(m0 + n) * 512 + k0 + kq];
            const float* pm = &mcat[OFF_W1 + (i64)(m0 + n) * 512 + k0 + kq];
            float4 v0 = *(const float4*)p, v1 = *(const float4*)(p + 16);
            float4 m0v = *(const float4*)pm, m1v = *(const float4*)(pm + 16);
            Bs[kq + 0][n] = v0.x - al * m0v.x; Bs[kq + 1][n] = v0.y - al * m0v.y;
            Bs[kq + 2][n] = v0.z - al * m0v.z; Bs[kq + 3][n] = v0.w - al * m0v.w;
            Bs[kq + 16][n] = v1.x - al * m1v.x; Bs[kq + 17][n] = v1.y - al * m1v.y;
            Bs[kq + 18][n] = v1.z - al * m1v.z; Bs[kq + 19][n] = v1.w - al * m1v.w;
        }
        if (tid < 32) {
            int j = k0 + tid;
            float w0 = W0[j * 3]     - al * mcat[j * 3];
            float w1 = W0[j * 3 + 1] - al * mcat[j * 3 + 1];
            float w2 = W0[j * 3 + 2] - al * mcat[j * 3 + 2];
            float bb = b0[j] - al * mcat[OFF_B0 + j];
            wq[tid][0] = w0; wq[tid][1] = w1; wq[tid][2] = w2; wq[tid][3] = bb;
            wq[tid][4] = w0 * w0 + w1 * w1 + w2 * w2;
        }
        __syncthreads();
        {
            int n = tid >> 2, a = tid & 3;
            float x0 = Xs[n][0], x1 = Xs[n][1], x2 = Xs[n][2];
#pragma unroll
            for (int i = 0; i < 8; i++) {
                int k = a + 4 * i;
                float s = x0 * wq[k][0] + x1 * wq[k][1] + x2 * wq[k][2] + wq[k][3];
                As[k][n] = tanhf(s);
            }
        }
        __syncthreads();
#pragma unroll
        for (int ks = 0; ks < 32; ks++) {
            float4 a = *(const float4*)&As[ks][ty * 4];
            float4 b = *(const float4*)&Bs[ks][tx * 4];
            float av[4] = {a.x, a.y, a.z, a.w};
            float bv[4] = {b.x, b.y, b.z, b.w};
            if (LAP) {
                float w0 = wq[ks][0], w1 = wq[ks][1], w2 = wq[ks][2], q0 = wq[ks][4];
                float gv0[4], gv1[4], gv2[4], lv[4];
#pragma unroll
                for (int i = 0; i < 4; i++) {
                    float t = av[i], phi = 1.f - t * t, u = -2.f * t * phi;
                    gv0[i] = phi * w0; gv1[i] = phi * w1; gv2[i] = phi * w2; lv[i] = u * q0;
                }
#pragma unroll
                for (int i = 0; i < 4; i++)
#pragma unroll
                    for (int j = 0; j < 4; j++) {
                        a_t[i][j]  += av[i]  * bv[j];
                        a_g0[i][j] += gv0[i] * bv[j];
                        a_g1[i][j] += gv1[i] * bv[j];
                        a_g2[i][j] += gv2[i] * bv[j];
                        a_l[i][j]  += lv[i]  * bv[j];
                    }
            } else {
#pragma unroll
                for (int i = 0; i < 4; i++)
#pragma unroll
                    for (int j = 0; j < 4; j++) a_t[i][j] += av[i] * bv[j];
            }
        }
        __syncthreads();
    }
    float rowpart[4];
#pragma unroll
    for (int i = 0; i < 4; i++) {
        rowpart[i] = 0.f;
#pragma unroll
        for (int j = 0; j < 4; j++) {
            int m = m0 + tx * 4 + j;
            float s = a_t[i][j] + (b1[m] - al * mcat[OFF_B1 + m]);
            float t1 = tanhf(s);
            float val;
            if (LAP) {
                float phi = 1.f - t1 * t1, u = -2.f * t1 * phi;
                float q = a_g0[i][j] * a_g0[i][j] + a_g1[i][j] * a_g1[i][j] + a_g2[i][j] * a_g2[i][j];
                val = phi * a_l[i][j] + u * q;
            } else val = t1;
            rowpart[i] += val * (W2[m] - al * mcat[OFF_W2 + m]);
        }
    }
#pragma unroll
    for (int i = 0; i < 4; i++) red[ty * 4 + i][tx] = rowpart[i];
    __syncthreads();
    if (tid < 64) {
        float s = 0.f;
#pragma unroll
        for (int x = 0; x < 16; x++) s += red[tid][x];
        if (!LAP && blockIdx.y == 0) s += (b2[0] - al * mcat[OFF_B2]);
        part[((i64)blockIdx.z * 8 + blockIdx.y) * nrows + n0 + tid] = s;
    }
}

__global__ __launch_bounds__(256) void lsred_k(const float* __restrict__ pI,
                                               const float* __restrict__ pB,
                                               const float* __restrict__ Xi,
                                               const float* __restrict__ Xb,
                                               float* __restrict__ lossI,
                                               float* __restrict__ lossB)
{
    __shared__ float red[256];
    int z = blockIdx.x, a = z >> 1, isB = z & 1;
    int rows = isB ? NB : NI;
    const float* src = isB ? (pB + (i64)a * 8 * NB) : (pI + (i64)a * 8 * NI);
    const float* X = isB ? Xb : Xi;
    float acc = 0.f;
    for (int n = threadIdx.x; n < rows; n += 256) {
        float s = 0.f;
#pragma unroll
        for (int t = 0; t < 8; t++) s += src[(i64)t * rows + n];
        const float* x = X + (i64)n * 3;
        float rhs = isB ? (cosf(x[0]) + cosf(x[1]) + cosf(x[2]))
                        : (sinf(x[0]) + sinf(x[1]) + sinf(x[2]));
        float r = s - rhs;
        acc += r * r;
    }
    red[threadIdx.x] = acc; __syncthreads();
    for (int off = 128; off; off >>= 1) {
        if (threadIdx.x < off) red[threadIdx.x] += red[threadIdx.x + off];
        __syncthreads();
    }
    if (threadIdx.x == 0) {
        if (isB) lossB[a] = red[0];
        else lossI[a] = red[0];
    }
}

// ======================= host helpers =======================
template<int MODE>
static inline void g64(hipStream_t st, const float* A, const float* B, float* C,
                       int M, int N, int K) {
    dim3 g((M + 63) / 64, (N + 63) / 64);
    bool fast = (M % 64 == 0) && (N % 64 == 0) && (K % 32 == 0);
    if (fast) gemm64_k<MODE, 0, 0, 1, 0><<<g, 256, 0, st>>>(A, B, nullptr, C, M, N, K, nullptr, nullptr);
    else      gemm64_k<MODE, 0, 0, 0, 0><<<g, 256, 0, st>>>(A, B, nullptr, C, M, N, K, nullptr, nullptr);
}
static inline void g64_bt(hipStream_t st, const float* A, const float* B, const float* bias,
                          float* C, int M, int N, int K) {
    dim3 g((M + 63) / 64, (N + 63) / 64);
    gemm64_k<0, 1, 1, 1, 0><<<g, 256, 0, st>>>(A, B, bias, C, M, N, K, nullptr, nullptr);
}
static inline void g64_aux1(hipStream_t st, const float* A, const float* B, float* C,
                            int M, int N, int K, const float* t0p, float* dst2) {
    dim3 g((M + 63) / 64, (N + 63) / 64);
    gemm64_k<1, 0, 0, 1, 1><<<g, 256, 0, st>>>(A, B, nullptr, C, M, N, K, t0p, dst2);
}
static inline void g64_aux2(hipStream_t st, const float* A, const float* B, float* C,
                            int M, int N, int K, const float* t0p) {
    dim3 g((M + 63) / 64, (N + 63) / 64);
    gemm64_k<1, 0, 0, 1, 2><<<g, 256, 0, st>>>(A, B, nullptr, C, M, N, K, t0p, nullptr);
}
static inline void g_sk(hipStream_t st, const float* A, const float* B, float* dst,
                        int M, int N, int K, float* skbuf) {
    int Ks = ((K / 8) + 31) / 32 * 32;
    if (Ks * 8 < K) Ks += 32;
    dim3 g((M + 63) / 64, (N + 63) / 64, 8);
    bool fast = (M % 64 == 0) && (N % 64 == 0) && (K == Ks * 8);
    if (fast) gemm_tn_sk_k<1><<<g, 256, 0, st>>>(A, B, skbuf, M, N, K, Ks);
    else      gemm_tn_sk_k<0><<<g, 256, 0, st>>>(A, B, skbuf, M, N, K, Ks);
    int cnt = M * N;
    sk_red_k<<<(cnt + 255) / 256, 256, 0, st>>>(dst, skbuf, cnt);
}

extern "C" void kernel_launch(void* const* d_in, const int* in_sizes, int n_in,
                              void* d_out, int out_size, void* d_ws, size_t ws_size,
                              hipStream_t stream)
{
    const float* Xi   = (const float*)d_in[0];
    const float* Xb   = (const float*)d_in[1];
    const float* W0   = (const float*)d_in[2];
    const float* b0   = (const float*)d_in[3];
    const float* Aom0 = (const float*)d_in[4];
    const float* Bom0 = (const float*)d_in[5];
    const float* Abd0 = (const float*)d_in[6];
    const float* Bbd0 = (const float*)d_in[7];
    const float* mw0  = (const float*)d_in[8];
    const float* mb0  = (const float*)d_in[9];
    const float* W1   = (const float*)d_in[10];
    const float* b1   = (const float*)d_in[11];
    const float* Aom1 = (const float*)d_in[12];
    const float* Bom1 = (const float*)d_in[13];
    const float* Abd1 = (const float*)d_in[14];
    const float* Bbd1 = (const float*)d_in[15];
    const float* mw1  = (const float*)d_in[16];
    const float* mb1  = (const float*)d_in[17];
    const float* W2   = (const float*)d_in[18];
    const float* b2   = (const float*)d_in[19];
    const float* Aom2 = (const float*)d_in[20];
    const float* Bom2 = (const float*)d_in[21];
    const float* Abd2 = (const float*)d_in[22];
    const float* Bbd2 = (const float*)d_in[23];
    const float* mw2  = (const float*)d_in[24];
    const float* mb2  = (const float*)d_in[25];

    float* w = (float*)d_ws;
    i64 off = 0;
    auto alloc = [&](i64 n) { float* p = w + off; off += n; return p; };

    const i64 M1 = 1048576;
    float* arena = alloc(15 * M1);
    float* t0c = arena + 0 * M1;
    float* t1c = arena + 1 * M1;
    float* l1c = arena + 2 * M1;
    float* ls1c = arena + 3 * M1;
    float* l2c = arena + 5 * M1;
    float* d1c = arena + 6 * M1;
    float* e1c = arena + 7 * M1;
    float* f1c = arena + 8 * M1;
    float* g1c = arena + 9 * M1;
    float* gs1c = arena + 12 * M1;
    float* skbuf = arena + 4 * M1;
    // eigen views (phase-disjoint: rlog [eig_sub->ubuild], Tbuf [etA->etB])
    float* Aeig = arena + 0 * M1;
    float* Veig = arena + 2 * M1;
    float* Ubuf = arena + 3 * M1;
    float* Vs   = arena + 3 * M1 + 524288;
    float* rlog = arena + 5 * M1;
    float* Tbuf = arena + 8 * M1;
    // precond / LS views
    float* P1 = arena + 8 * M1;
    float* P2 = arena + 8 * M1 + HH;
    float* pI  = arena + 9 * M1;
    float* pB  = arena + 10 * M1;

    float* ri = alloc(NI);
    float* rb = alloc(NB);
    float* zero_base = w + off;
    float* S8   = alloc(8 * (i64)HH);
    float* S_A0 = alloc(9);
    float* S_Ab0 = alloc(9);
    float* S_B2 = alloc(1);
    float* S_B2b = alloc(1);
    float* gW0 = alloc(1536);
    float* gW1 = alloc(HH);
    float* gW2 = alloc(H);
    float* gb0v = alloc(H);
    float* gb1v = alloc(H);
    float* gb2v = alloc(1);
    float* lossI = alloc(5);
    float* lossB = alloc(5);
    i64 zero_count = (w + off) - zero_base;
    float* UA0 = alloc(9);
    float* eA0 = alloc(3);
    float* eAb0 = alloc(3);
    float* eScal = alloc(2);
    float* evals = alloc(4096);
    int*   ranks = (int*)alloc(2048);
    float* pcat = alloc(TOT);
    float* mcat = alloc(TOT);
    float* bestA = alloc(1);
    float* wpart = alloc(3 * 16 * H);
    float* b0part = alloc(8 * 2048);
    if (ws_size < (size_t)off * sizeof(float)) return;

    hipStream_t st = stream;
    zero_k<<<(int)((zero_count + 255) / 256), 256, 0, st>>>(zero_base, zero_count);

    const int EW = (CH * H + 255) / 256;

    // ---------------- interior chunks ----------------
    for (int c = 0; c < 4; c++) {
        const float* Xc = Xi + (i64)c * CH * 3;
        float* ric = ri + (i64)c * CH;
        fwd0_k<1><<<EW, 256, 0, st>>>(Xc, W0, b0, CH, t0c, g1c, l1c);
        g64_bt(st, t0c, W1, b1, t1c, CH, H, H);
        g64<0>(st, g1c, W1, gs1c, 3 * CH, H, H);
        g64<0>(st, l1c, W1, ls1c, CH, H, H);
        lapbwd_k<<<CH, 256, 0, st>>>(t1c, ls1c, gs1c, W2, Xc, 1.f / NI, l2c, f1c, d1c, ric);
        g64_aux1(st, d1c, W1, ls1c, CH, H, H, t0c, e1c);        // bar_l1 + delta0
        {
            WJ wj = {};
            wj.src[0] = l2c; wj.wgt[0] = ric; wj.scale[0] = 1.f / NI; wj.dst[0] = gW2;
            wj.src[1] = f1c; wj.wgt[1] = nullptr; wj.scale[1] = 1.f; wj.dst[1] = gb1v;
            wcolp_k<<<dim3(2, 16, 2), 256, 0, st>>>(wj, CH, wpart);
            wcolr_k<<<dim3(2, 2), 256, 0, st>>>(wj, wpart);
        }
        {   // batched Gram: Bo1, Bo0, Ao1, Ao2
            SkBatch sb = {};
            sb.A[0] = d1c; sb.B[0] = d1c;
            sb.A[1] = e1c; sb.B[1] = e1c;
            sb.A[2] = t0c; sb.B[2] = t0c;
            sb.A[3] = t1c; sb.B[3] = t1c;
            sb.Ks = 1024;
            for (int z = 0; z < 8; z++) { sb.job_of_z[z] = z >> 1; sb.kb_of_z[z] = (z & 1) * 1024; }
            skb_k<<<dim3(8, 8, 8), 256, 0, st>>>(sb, skbuf);
            RedJ rj = {};
            rj.dst[0] = S8 + 2 * (i64)HH; rj.dst[1] = S8 + 0 * (i64)HH;
            rj.dst[2] = S8 + 1 * (i64)HH; rj.dst[3] = S8 + 3 * (i64)HH;
            rj.off[0] = 0; rj.off[1] = 2; rj.off[2] = 4; rj.off[3] = 6; rj.off[4] = 8;
            skred_k<<<dim3(1024, 4), 256, 0, st>>>(rj, skbuf);
        }
        {   // batched gW1
            SkBatch sb = {};
            sb.A[0] = f1c;  sb.B[0] = t0c;
            sb.A[1] = gs1c; sb.B[1] = g1c;
            sb.A[2] = d1c;  sb.B[2] = l1c;
            sb.Ks = 2048;
            int jo[5] = {0, 1, 1, 1, 2};
            int kb[5] = {0, 0, 2048, 4096, 0};
            for (int z = 0; z < 5; z++) { sb.job_of_z[z] = jo[z]; sb.kb_of_z[z] = kb[z]; }
            skb_k<<<dim3(8, 8, 5), 256, 0, st>>>(sb, skbuf);
            RedJ rj = {};
            rj.dst[0] = gW1;
            rj.off[0] = 0; rj.off[1] = 5;
            skred_k<<<dim3(1024, 1), 256, 0, st>>>(rj, skbuf);
        }
        g64<1>(st, f1c, W1, l2c, CH, H, H);                     // bar_t0
        g64<1>(st, gs1c, W1, g1c, 3 * CH, H, H);                // bar_g1
        bwd0p_k<<<dim3(2, 8), 256, 0, st>>>(Xc, CH, W0, t0c, l2c, ls1c, g1c, b0part);
        bwd0red_k<<<8, 256, 0, st>>>(b0part, gW0, gb0v);
    }

    // ---------------- boundary ----------------
    fwd0_k<0><<<(NB * H + 255) / 256, 256, 0, st>>>(Xb, W0, b0, NB, t0c, nullptr, nullptr);
    g64_bt(st, t0c, W1, b1, t1c, NB, H, H);
    bnd_fin_k<<<NB / 4, 256, 0, st>>>(t1c, W2, b2, Xb, NB, rb);
    dualred_k<<<2, 256, 0, st>>>(ri, rb, S_B2, gb2v, S_B2b);
    delta1_k<<<(NB * H + 255) / 256, 256, 0, st>>>(t1c, rb, W2, 1.f / NB, d1c, NB);
    {
        SkBatch sb = {};
        sb.A[0] = d1c; sb.B[0] = d1c;
        sb.A[1] = t0c; sb.B[1] = t0c;
        sb.A[2] = t1c; sb.B[2] = t1c;
        sb.Ks = 1024;
        for (int z = 0; z < 6; z++) { sb.job_of_z[z] = z >> 1; sb.kb_of_z[z] = (z & 1) * 1024; }
        skb_k<<<dim3(8, 8, 6), 256, 0, st>>>(sb, skbuf);
        RedJ rj = {};
        rj.dst[0] = S8 + 6 * (i64)HH; rj.dst[1] = S8 + 5 * (i64)HH; rj.dst[2] = S8 + 7 * (i64)HH;
        rj.off[0] = 0; rj.off[1] = 2; rj.off[2] = 4; rj.off[3] = 6;
        skred_k<<<dim3(1024, 3), 256, 0, st>>>(rj, skbuf);
    }
    g_sk(st, d1c, t0c, gW1, H, H, NB, skbuf);
    g64_aux2(st, d1c, W1, e1c, NB, H, H, t0c);
    {
        WJ wj = {};
        wj.src[0] = t1c; wj.wgt[0] = rb; wj.scale[0] = 1.f / NB; wj.dst[0] = gW2;
        wj.src[1] = d1c; wj.wgt[1] = nullptr; wj.scale[1] = 1.f; wj.dst[1] = gb1v;
        wj.src[2] = e1c; wj.wgt[2] = nullptr; wj.scale[2] = 1.f; wj.dst[2] = gb0v;
        wcolp_k<<<dim3(2, 16, 3), 256, 0, st>>>(wj, NB, wpart);
        wcolr_k<<<dim3(2, 3), 256, 0, st>>>(wj, wpart);
    }
    g_sk(st, e1c, e1c, S8 + 4 * (i64)HH, H, H, NB, skbuf);
    g_sk(st, e1c, Xb, gW0, H, 3, NB, skbuf);
    xtx3b_k<<<2, 256, 0, st>>>(Xi, Xb, S_A0, S_Ab0);

    // ---------------- factor build + eigensolve ----------------
    {
        P8 mom = {};
        mom.p[0] = Bom0; mom.p[1] = Aom1; mom.p[2] = Bom1; mom.p[3] = Aom2;
        mom.p[4] = Bbd0; mom.p[5] = Abd1; mom.p[6] = Bbd1; mom.p[7] = Abd2;
        fbuildb_k<<<dim3(1024, 8), 256, 0, st>>>(mom, S8, Aeig);
    }
    identv_k<<<(int)((4 * (i64)HH + 255) / 256), 256, 0, st>>>(Veig, 4 * (i64)HH);
    small_eig_k<<<1, 1, 0, st>>>(Aom0, S_A0, Abd0, S_Ab0, Bom2, S_B2, Bbd2, S_B2b,
                                 UA0, eA0, eAb0, eScal);

    for (int sw = 0; sw < SOUTER; sw++)
        for (int r = 0; r < 7; r++) {
            eig_sub_k<<<dim3(4, 8), 1024, 0, st>>>(Aeig, rlog, r);
            ubuild_k<<<dim3(8, 32), 256, 0, st>>>(rlog, Ubuf);
            etA_k<<<384, 256, 0, st>>>(Aeig, Veig, Ubuf, Tbuf, r);
            etB_k<<<256, 256, 0, st>>>(Aeig, Ubuf, Tbuf, r);
        }
    sort_k<<<8, 512, 0, st>>>(Aeig, evals, ranks);
    perm_k<<<(int)((4 * (i64)HH + 255) / 256), 256, 0, st>>>(Veig, ranks, Vs);

    // ---------------- preconditioning ----------------
    g64<2>(st, Vs + 0 * (i64)HH, gW0, P1, H, 3, H);
    g64<1>(st, P1, UA0, P2, H, 3, 3);
    div2_k<<<6, 256, 0, st>>>(P2, evals + 0 * H, eA0, evals + 4 * H, eAb0, H, 3);
    g64<1>(st, Vs + 0 * (i64)HH, P2, P1, H, 3, H);
    g64<0>(st, P1, UA0, pcat + 0, H, 3, 3);
    g64<2>(st, Vs + 0 * (i64)HH, gb0v, P2, H, 1, H);
    div1_k<<<2, 256, 0, st>>>(P2, evals + 0 * H, evals + 4 * H, H);
    g64<1>(st, Vs + 0 * (i64)HH, P2, pcat + OFF_B0, H, 1, H);

    g64<2>(st, Vs + 2 * (i64)HH, gW1, P1, H, H, H);
    g64<1>(st, P1, Vs + 1 * (i64)HH, P2, H, H, H);
    div2_k<<<1024, 256, 0, st>>>(P2, evals + 2 * H, evals + 1 * H, evals + 6 * H, evals + 5 * H, H, H);
    g64<1>(st, Vs + 2 * (i64)HH, P2, P1, H, H, H);
    g64<0>(st, P1, Vs + 1 * (i64)HH, pcat + OFF_W1, H, H, H);
    g64<2>(st, Vs + 2 * (i64)HH, gb1v, P2, H, 1, H);
    div1_k<<<2, 256, 0, st>>>(P2, evals + 2 * H, evals + 6 * H, H);
    g64<1>(st, Vs + 2 * (i64)HH, P2, pcat + OFF_B1, H, 1, H);

    g64<1>(st, gW2, Vs + 3 * (i64)HH, P2, 1, H, H);
    div2s_k<<<2, 256, 0, st>>>(P2, eScal, evals + 3 * H, evals + 7 * H, H);
    g64<0>(st, P2, Vs + 3 * (i64)HH, pcat + OFF_W2, 1, H, H);
    scal2_k<<<1, 1, 0, st>>>(gb2v, eScal, pcat + OFF_B2);

    // ---------------- momentum ----------------
    mom_k<<<(TOT + 255) / 256, 256, 0, st>>>(mw0, mw1, mw2, mb0, mb1, mb2, pcat, mcat);

    // ---------------- line search: 2 z-batched launches ----------------
    lsf2_k<1><<<dim3(NI / 64, 8, 5), 256, 0, st>>>(Xi, W0, b0, W1, b1, W2, b2, mcat, NI, pI);
    lsf2_k<0><<<dim3(NB / 64, 8, 5), 256, 0, st>>>(Xb, W0, b0, W1, b1, W2, b2, mcat, NB, pB);
    lsred_k<<<10, 256, 0, st>>>(pI, pB, Xi, Xb, lossI, lossB);
    argmin_k<<<1, 1, 0, st>>>(lossI, lossB, bestA);
    upd_k<<<(TOT + 255) / 256, 256, 0, st>>>(W0, W1, W2, b0, b1, b2, mcat, 0.f, bestA,
                                             (float*)d_out);
}